// Round 1
// baseline (1196.251 us; speedup 1.0000x reference)
//
#include <hip/hip_runtime.h>
#include <hip/hip_bf16.h>
#include <math.h>

#define F_IN 128
#define GH   64
#define HC1  128   // HEADS*C1

// ---------- helpers ----------
__device__ __forceinline__ unsigned fkey(float f) {
    unsigned u = __float_as_uint(f);
    return (u & 0x80000000u) ? ~u : (u | 0x80000000u);
}
__device__ __forceinline__ float funkey(unsigned u) {
    return (u & 0x80000000u) ? __uint_as_float(u & 0x7fffffffu) : __uint_as_float(~u);
}
__device__ __forceinline__ void edge_sd(const int* __restrict__ ei, int E, int e, int& s, int& d) {
    if (e < E) { s = ei[e]; d = ei[E + e]; } else { s = d = e - E; }
}

// ---------- GEMM: Y[n,m] = act(sum_k X[n,k]*W[k,m] + b[m]) ----------
template<int K, int M, bool RELU>
__global__ __launch_bounds__(256) void gemm_tile(
    const float* __restrict__ X, const float* __restrict__ W,
    const float* __restrict__ B, float* __restrict__ Y, int nrows)
{
    __shared__ float Wl[K * M];
    __shared__ float Xl[32 * K];
    const int t = threadIdx.x;
    for (int i = t; i < K * M / 4; i += 256)
        ((float4*)Wl)[i] = ((const float4*)W)[i];
    const int base = blockIdx.x * 32;
    for (int i = t; i < 32 * K / 4; i += 256) {
        int r = (i * 4) / K;
        int n = base + r;
        float4 v = make_float4(0.f, 0.f, 0.f, 0.f);
        if (n < nrows) v = ((const float4*)(X + (size_t)n * K))[i - r * (K / 4)];
        ((float4*)Xl)[i] = v;
    }
    __syncthreads();
    constexpr int TPC = 256 / M;       // threads sharing a column
    constexpr int RPT = 32 / TPC;      // rows per thread
    const int m = t % M;
    const int r0 = (t / M) * RPT;
    float acc[RPT];
#pragma unroll
    for (int i = 0; i < RPT; i++) acc[i] = 0.f;
#pragma unroll 4
    for (int k = 0; k < K; k++) {
        float wv = Wl[k * M + m];
#pragma unroll
        for (int i = 0; i < RPT; i++) acc[i] += Xl[(r0 + i) * K + k] * wv;
    }
    const float bb = B ? B[m] : 0.f;
#pragma unroll
    for (int i = 0; i < RPT; i++) {
        int n = base + r0 + i;
        if (n < nrows) {
            float v = acc[i] + bb;
            if (RELU) v = fmaxf(v, 0.f);
            Y[(size_t)n * M + m] = v;
        }
    }
}

// ---------- per-node attention dots, gat1 (4 heads x 32 ch) ----------
__global__ __launch_bounds__(256) void asad1_kernel(
    const float* __restrict__ xh, const float* __restrict__ asw, const float* __restrict__ adw,
    float* __restrict__ as_n, float* __restrict__ ad_n, int N)
{
    const int t = threadIdx.x;
    const int node = blockIdx.x * 2 + (t >> 7);
    const int c = t & 127;
    if (node >= N) return;
    float xv = xh[(size_t)node * 128 + c];
    float ps = xv * asw[c];
    float pd = xv * adw[c];
#pragma unroll
    for (int msk = 16; msk >= 1; msk >>= 1) {
        ps += __shfl_xor(ps, msk);
        pd += __shfl_xor(pd, msk);
    }
    if ((c & 31) == 0) {
        as_n[node * 4 + (c >> 5)] = ps;
        ad_n[node * 4 + (c >> 5)] = pd;
    }
}

// ---------- per-node attention dots, gat2 (1 head x 64 ch) ----------
__global__ __launch_bounds__(256) void asad2_kernel(
    const float* __restrict__ xh, const float* __restrict__ asw, const float* __restrict__ adw,
    float* __restrict__ as_n, float* __restrict__ ad_n, int N)
{
    const int t = threadIdx.x;
    const int node = blockIdx.x * 4 + (t >> 6);
    const int c = t & 63;
    if (node >= N) return;
    float xv = xh[(size_t)node * 64 + c];
    float ps = xv * asw[c];
    float pd = xv * adw[c];
#pragma unroll
    for (int msk = 32; msk >= 1; msk >>= 1) {
        ps += __shfl_xor(ps, msk);
        pd += __shfl_xor(pd, msk);
    }
    if (c == 0) { as_n[node] = ps; ad_n[node] = pd; }
}

// ---------- gat1 edge passes ----------
__global__ __launch_bounds__(256) void gat1_passA(
    const int* __restrict__ ei, int E, int ET, int N,
    const float* __restrict__ as_n, const float* __restrict__ ad_n,
    float* __restrict__ elog, unsigned* __restrict__ maxk)
{
    int e = blockIdx.x * 256 + threadIdx.x;
    if (e >= ET) return;
    int s, d; edge_sd(ei, E, e, s, d);
    if ((unsigned)s >= (unsigned)N || (unsigned)d >= (unsigned)N) return;
    float4 av = ((const float4*)as_n)[s];
    float4 bv = ((const float4*)ad_n)[d];
    float v[4] = {av.x + bv.x, av.y + bv.y, av.z + bv.z, av.w + bv.w};
#pragma unroll
    for (int h = 0; h < 4; h++) {
        float x = v[h];
        x = (x >= 0.f) ? x : 0.2f * x;
        v[h] = x;
        atomicMax(&maxk[d * 4 + h], fkey(x));
    }
    ((float4*)elog)[e] = make_float4(v[0], v[1], v[2], v[3]);
}

__global__ __launch_bounds__(256) void gat1_passB(
    const int* __restrict__ ei, int E, int ET, int N,
    const unsigned* __restrict__ maxk, float* __restrict__ elog, float* __restrict__ denom)
{
    int e = blockIdx.x * 256 + threadIdx.x;
    if (e >= ET) return;
    int s, d; edge_sd(ei, E, e, s, d);
    if ((unsigned)s >= (unsigned)N || (unsigned)d >= (unsigned)N) return;
    float4 lv = ((const float4*)elog)[e];
    float v[4] = {lv.x, lv.y, lv.z, lv.w};
    float ex[4];
#pragma unroll
    for (int h = 0; h < 4; h++) {
        float m = funkey(maxk[d * 4 + h]);
        ex[h] = expf(v[h] - m);
        atomicAdd(&denom[d * 4 + h], ex[h]);
    }
    ((float4*)elog)[e] = make_float4(ex[0], ex[1], ex[2], ex[3]);
}

__global__ __launch_bounds__(256) void gat1_passC(
    const int* __restrict__ ei, int E, int ET, int N,
    const float* __restrict__ elog, const float* __restrict__ denom,
    const float* __restrict__ xh, float* __restrict__ agg)
{
    int gid = (blockIdx.x * 256 + threadIdx.x) >> 5;
    int lane = threadIdx.x & 31;
    if (gid >= ET) return;
    int s, d; edge_sd(ei, E, gid, s, d);
    if ((unsigned)s >= (unsigned)N || (unsigned)d >= (unsigned)N) return;
    float al[4];
#pragma unroll
    for (int h = 0; h < 4; h++)
        al[h] = elog[gid * 4 + h] / (denom[d * 4 + h] + 1e-16f);
#pragma unroll
    for (int k = 0; k < 4; k++) {
        int c = lane + k * 32;
        atomicAdd(&agg[(size_t)d * 128 + c], al[k] * xh[(size_t)s * 128 + c]);
    }
}

// ---------- gat2 edge passes (1 head) ----------
__global__ __launch_bounds__(256) void gat2_passA(
    const int* __restrict__ ei, int E, int ET, int N,
    const float* __restrict__ as_n, const float* __restrict__ ad_n,
    float* __restrict__ elog, unsigned* __restrict__ maxk)
{
    int e = blockIdx.x * 256 + threadIdx.x;
    if (e >= ET) return;
    int s, d; edge_sd(ei, E, e, s, d);
    if ((unsigned)s >= (unsigned)N || (unsigned)d >= (unsigned)N) return;
    float v = as_n[s] + ad_n[d];
    v = (v >= 0.f) ? v : 0.2f * v;
    elog[e] = v;
    atomicMax(&maxk[d], fkey(v));
}

__global__ __launch_bounds__(256) void gat2_passB(
    const int* __restrict__ ei, int E, int ET, int N,
    const unsigned* __restrict__ maxk, float* __restrict__ elog, float* __restrict__ denom)
{
    int e = blockIdx.x * 256 + threadIdx.x;
    if (e >= ET) return;
    int s, d; edge_sd(ei, E, e, s, d);
    if ((unsigned)s >= (unsigned)N || (unsigned)d >= (unsigned)N) return;
    float m = funkey(maxk[d]);
    float ex = expf(elog[e] - m);
    elog[e] = ex;
    atomicAdd(&denom[d], ex);
}

__global__ __launch_bounds__(256) void gat2_passC(
    const int* __restrict__ ei, int E, int ET, int N,
    const float* __restrict__ elog, const float* __restrict__ denom,
    const float* __restrict__ xh, float* __restrict__ agg)
{
    int gid = (blockIdx.x * 256 + threadIdx.x) >> 5;
    int lane = threadIdx.x & 31;
    if (gid >= ET) return;
    int s, d; edge_sd(ei, E, gid, s, d);
    if ((unsigned)s >= (unsigned)N || (unsigned)d >= (unsigned)N) return;
    float al = elog[gid] / (denom[d] + 1e-16f);
    atomicAdd(&agg[(size_t)d * 64 + lane],      al * xh[(size_t)s * 64 + lane]);
    atomicAdd(&agg[(size_t)d * 64 + lane + 32], al * xh[(size_t)s * 64 + lane + 32]);
}

// ---------- elementwise: h = elu(agg + bias) in-place ----------
__global__ __launch_bounds__(256) void elu_bias128(float* __restrict__ a, const float* __restrict__ b, size_t total)
{
    size_t i = (size_t)blockIdx.x * 256 + threadIdx.x;
    if (i >= total) return;
    float v = a[i] + b[i & 127];
    a[i] = (v > 0.f) ? v : expm1f(v);
}

// ---------- elu(agg2+b2) fused with mean-pool accumulation ----------
__global__ __launch_bounds__(256) void pool_kernel(
    const float* __restrict__ agg, const float* __restrict__ b2,
    const int* __restrict__ batch, float* __restrict__ sums, float* __restrict__ cnts,
    int N, int G)
{
    size_t i = (size_t)blockIdx.x * 256 + threadIdx.x;
    if (i >= (size_t)N * 64) return;
    int n = (int)(i >> 6);
    int c = (int)(i & 63);
    int g = batch[n];
    if ((unsigned)g >= (unsigned)G) return;
    float v = agg[i] + b2[c];
    v = (v > 0.f) ? v : expm1f(v);
    atomicAdd(&sums[(size_t)g * 64 + c], v);
    if (c == 0) atomicAdd(&cnts[g], 1.0f);
}

// ---------- final MLP + 3 heads, one wave per graph ----------
__global__ __launch_bounds__(64) void mlp_head(
    const float* __restrict__ sums, const float* __restrict__ cnts,
    const float* __restrict__ Wm1, const float* __restrict__ bm1,
    const float* __restrict__ Wm2, const float* __restrict__ bm2,
    const float* __restrict__ Wc, const float* __restrict__ bc,
    const float* __restrict__ Wr, const float* __restrict__ br,
    const float* __restrict__ Wv, const float* __restrict__ bv,
    float* __restrict__ out, int G)
{
    int g = blockIdx.x;
    int t = threadIdx.x;
    __shared__ float hrow[64];
    __shared__ float zrow[64];
    float hv = sums[(size_t)g * 64 + t] / fmaxf(cnts[g], 1.0f);
    hrow[t] = hv;
    __syncthreads();
    float z1 = bm1[t];
#pragma unroll 8
    for (int k = 0; k < 64; k++) z1 += hrow[k] * Wm1[k * 64 + t];
    z1 = fmaxf(z1, 0.f);
    zrow[t] = z1;
    __syncthreads();
    float z2 = bm2[t];
#pragma unroll 8
    for (int k = 0; k < 64; k++) z2 += zrow[k] * Wm2[k * 64 + t];
    z2 = fmaxf(z2, 0.f);
    float pc = z2 * Wc[t], pr = z2 * Wr[t], pv = z2 * Wv[t];
#pragma unroll
    for (int m = 32; m >= 1; m >>= 1) {
        pc += __shfl_xor(pc, m);
        pr += __shfl_xor(pr, m);
        pv += __shfl_xor(pv, m);
    }
    if (t == 0) {
        out[g] = pc + bc[0];
        out[G + g] = pr + br[0];
        float s = pv + bv[0];
        out[2 * G + g] = (s > 20.f) ? s : log1pf(expf(s));
    }
}

extern "C" void kernel_launch(void* const* d_in, const int* in_sizes, int n_in,
                              void* d_out, int out_size, void* d_ws, size_t ws_size,
                              hipStream_t stream)
{
    const float* x     = (const float*)d_in[0];
    const int*   ei    = (const int*)d_in[1];
    const int*   batch = (const int*)d_in[2];
    const float* Wp  = (const float*)d_in[3];
    const float* bp  = (const float*)d_in[4];
    const float* W1  = (const float*)d_in[5];
    const float* as1 = (const float*)d_in[6];
    const float* ad1 = (const float*)d_in[7];
    const float* b1  = (const float*)d_in[8];
    const float* W2  = (const float*)d_in[9];
    const float* as2 = (const float*)d_in[10];
    const float* ad2 = (const float*)d_in[11];
    const float* b2  = (const float*)d_in[12];
    const float* Wm1 = (const float*)d_in[13];
    const float* bm1 = (const float*)d_in[14];
    const float* Wm2 = (const float*)d_in[15];
    const float* bm2 = (const float*)d_in[16];
    const float* Wc  = (const float*)d_in[17];
    const float* bc  = (const float*)d_in[18];
    const float* Wr  = (const float*)d_in[19];
    const float* br  = (const float*)d_in[20];
    const float* Wv  = (const float*)d_in[21];
    const float* bv  = (const float*)d_in[22];

    const int N  = in_sizes[0] / F_IN;
    const int E  = in_sizes[1] / 2;
    const int G  = out_size / 3;
    const int ET = E + N;

    float* ws = (float*)d_ws;
    size_t o = 0;
    float* bufA = ws + o; o += (size_t)N * 64;    // h0, later xh2
    float* bufB = ws + o; o += (size_t)N * 128;   // xh1, later agg2
    float* bufC = ws + o; o += (size_t)N * 128;   // agg1 -> h1
    float* elog = ws + o; o += (size_t)ET * 4;    // logits/exp, gat1 then gat2
    float* as1n = ws + o; o += (size_t)N * 4;
    float* ad1n = ws + o; o += (size_t)N * 4;
    // contiguous zero-init block:
    float* zstart = ws + o;
    unsigned* maxk1 = (unsigned*)(ws + o); o += (size_t)N * 4;
    float* denom1   = ws + o;              o += (size_t)N * 4;
    unsigned* maxk2 = (unsigned*)(ws + o); o += (size_t)N;
    float* denom2   = ws + o;              o += (size_t)N;
    float* sums     = ws + o;              o += (size_t)G * 64;
    float* cnts     = ws + o;              o += (size_t)G;
    size_t zlen = (size_t)(ws + o - zstart) * sizeof(float);
    float* as2n = ws + o; o += (size_t)N;
    float* ad2n = ws + o; o += (size_t)N;

    // zero scratch (ws is poisoned before every call)
    hipMemsetAsync(zstart, 0, zlen, stream);
    hipMemsetAsync(bufC, 0, (size_t)N * 128 * sizeof(float), stream);  // agg1

    const int gN32 = (N + 31) / 32;
    const int gE   = (ET + 255) / 256;
    const int gE32 = (ET + 7) / 8;   // 8 edge-groups (32 lanes each) per 256-thread block

    // node_proj: h0 = relu(x @ Wp + bp)
    gemm_tile<128, 64, true><<<gN32, 256, 0, stream>>>(x, Wp, bp, bufA, N);
    // gat1 transform: xh1 = h0 @ W1
    gemm_tile<64, 128, false><<<gN32, 256, 0, stream>>>(bufA, W1, nullptr, bufB, N);
    // attention dots
    asad1_kernel<<<(N + 1) / 2, 256, 0, stream>>>(bufB, as1, ad1, as1n, ad1n, N);
    // edge softmax + aggregate
    gat1_passA<<<gE, 256, 0, stream>>>(ei, E, ET, N, as1n, ad1n, elog, maxk1);
    gat1_passB<<<gE, 256, 0, stream>>>(ei, E, ET, N, maxk1, elog, denom1);
    gat1_passC<<<gE32, 256, 0, stream>>>(ei, E, ET, N, elog, denom1, bufB, bufC);
    // h1 = elu(agg1 + b1), in place in bufC
    elu_bias128<<<(int)(((size_t)N * 128 + 255) / 256), 256, 0, stream>>>(bufC, b1, (size_t)N * 128);
    // agg2 buffer (reuses bufB) must be zeroed now that xh1 is dead
    hipMemsetAsync(bufB, 0, (size_t)N * 64 * sizeof(float), stream);
    // gat2 transform: xh2 = h1 @ W2 (into bufA; h0 is dead)
    gemm_tile<128, 64, false><<<gN32, 256, 0, stream>>>(bufC, W2, nullptr, bufA, N);
    asad2_kernel<<<(N + 3) / 4, 256, 0, stream>>>(bufA, as2, ad2, as2n, ad2n, N);
    gat2_passA<<<gE, 256, 0, stream>>>(ei, E, ET, N, as2n, ad2n, elog, maxk2);
    gat2_passB<<<gE, 256, 0, stream>>>(ei, E, ET, N, maxk2, elog, denom2);
    gat2_passC<<<gE32, 256, 0, stream>>>(ei, E, ET, N, elog, denom2, bufA, bufB);
    // elu(agg2 + b2) fused with mean-pool accumulation
    pool_kernel<<<(int)(((size_t)N * 64 + 255) / 256), 256, 0, stream>>>(bufB, b2, batch, sums, cnts, N, G);
    // final MLP heads
    mlp_head<<<G, 64, 0, stream>>>(sums, cnts, Wm1, bm1, Wm2, bm2,
                                   Wc, bc, Wr, br, Wv, bv, (float*)d_out, G);
}

// Round 2
// 617.239 us; speedup vs baseline: 1.9381x; 1.9381x over previous
//
#include <hip/hip_runtime.h>
#include <hip/hip_bf16.h>
#include <math.h>

#define F_IN 128
#define GH   64

// ---------- helpers ----------
__device__ __forceinline__ void edge_sd(const int* __restrict__ ei, int E, int e, int& s, int& d) {
    if (e < E) { s = ei[e]; d = ei[E + e]; } else { s = d = e - E; }
}

// ---------- GEMM: Y[n,m] = act(sum_k X[n,k]*W[k,m] + b[m]) ----------
template<int K, int M, bool RELU>
__global__ __launch_bounds__(256) void gemm_tile(
    const float* __restrict__ X, const float* __restrict__ W,
    const float* __restrict__ B, float* __restrict__ Y, int nrows)
{
    __shared__ float Wl[K * M];
    __shared__ float Xl[32 * K];
    const int t = threadIdx.x;
    for (int i = t; i < K * M / 4; i += 256)
        ((float4*)Wl)[i] = ((const float4*)W)[i];
    const int base = blockIdx.x * 32;
    for (int i = t; i < 32 * K / 4; i += 256) {
        int r = (i * 4) / K;
        int n = base + r;
        float4 v = make_float4(0.f, 0.f, 0.f, 0.f);
        if (n < nrows) v = ((const float4*)(X + (size_t)n * K))[i - r * (K / 4)];
        ((float4*)Xl)[i] = v;
    }
    __syncthreads();
    constexpr int TPC = 256 / M;       // threads sharing a column
    constexpr int RPT = 32 / TPC;      // rows per thread
    const int m = t % M;
    const int r0 = (t / M) * RPT;
    float acc[RPT];
#pragma unroll
    for (int i = 0; i < RPT; i++) acc[i] = 0.f;
#pragma unroll 4
    for (int k = 0; k < K; k++) {
        float wv = Wl[k * M + m];
#pragma unroll
        for (int i = 0; i < RPT; i++) acc[i] += Xl[(r0 + i) * K + k] * wv;
    }
    const float bb = B ? B[m] : 0.f;
#pragma unroll
    for (int i = 0; i < RPT; i++) {
        int n = base + r0 + i;
        if (n < nrows) {
            float v = acc[i] + bb;
            if (RELU) v = fmaxf(v, 0.f);
            Y[(size_t)n * M + m] = v;
        }
    }
}

// ---------- per-node attention dots, gat1 (4 heads x 32 ch) ----------
__global__ __launch_bounds__(256) void asad1_kernel(
    const float* __restrict__ xh, const float* __restrict__ asw, const float* __restrict__ adw,
    float* __restrict__ as_n, float* __restrict__ ad_n, int N)
{
    const int t = threadIdx.x;
    const int node = blockIdx.x * 2 + (t >> 7);
    const int c = t & 127;
    if (node >= N) return;
    float xv = xh[(size_t)node * 128 + c];
    float ps = xv * asw[c];
    float pd = xv * adw[c];
#pragma unroll
    for (int msk = 16; msk >= 1; msk >>= 1) {
        ps += __shfl_xor(ps, msk);
        pd += __shfl_xor(pd, msk);
    }
    if ((c & 31) == 0) {
        as_n[node * 4 + (c >> 5)] = ps;
        ad_n[node * 4 + (c >> 5)] = pd;
    }
}

// ---------- per-node attention dots, gat2 (1 head x 64 ch) ----------
__global__ __launch_bounds__(256) void asad2_kernel(
    const float* __restrict__ xh, const float* __restrict__ asw, const float* __restrict__ adw,
    float* __restrict__ as_n, float* __restrict__ ad_n, int N)
{
    const int t = threadIdx.x;
    const int node = blockIdx.x * 4 + (t >> 6);
    const int c = t & 63;
    if (node >= N) return;
    float xv = xh[(size_t)node * 64 + c];
    float ps = xv * asw[c];
    float pd = xv * adw[c];
#pragma unroll
    for (int msk = 32; msk >= 1; msk >>= 1) {
        ps += __shfl_xor(ps, msk);
        pd += __shfl_xor(pd, msk);
    }
    if (c == 0) { as_n[node] = ps; ad_n[node] = pd; }
}

// ---------- CSR build ----------
__global__ __launch_bounds__(256) void hist_kernel(
    const int* __restrict__ ei, int E, int ET, int N, int* __restrict__ deg)
{
    int e = blockIdx.x * 256 + threadIdx.x;
    if (e >= ET) return;
    int s, d; edge_sd(ei, E, e, s, d);
    if ((unsigned)s >= (unsigned)N || (unsigned)d >= (unsigned)N) return;
    atomicAdd(&deg[d], 1);
}

__global__ __launch_bounds__(1024) void scan_kernel(
    const int* __restrict__ deg, int* __restrict__ row_start,
    int* __restrict__ cursor, int N)
{
    __shared__ int wsum[16];
    __shared__ int wbase[16];
    __shared__ int ctot;
    __shared__ int carry_s;
    const int t = threadIdx.x, lane = t & 63, w = t >> 6;
    if (t == 0) carry_s = 0;
    __syncthreads();
    for (int base = 0; base < N; base += 1024) {
        int idx = base + t;
        int v = (idx < N) ? deg[idx] : 0;
        int val = v;
#pragma unroll
        for (int off = 1; off < 64; off <<= 1) {
            int n = __shfl_up(val, off);
            if (lane >= off) val += n;
        }
        if (lane == 63) wsum[w] = val;
        __syncthreads();
        if (w == 0 && lane < 16) {
            int s = wsum[lane];
            int sv = s;
#pragma unroll
            for (int off = 1; off < 16; off <<= 1) {
                int n = __shfl_up(sv, off);
                if (lane >= off) sv += n;
            }
            wbase[lane] = sv - s;
            if (lane == 15) ctot = sv;
        }
        __syncthreads();
        int carry = carry_s;
        int excl = carry + wbase[w] + (val - v);
        if (idx < N) { row_start[idx] = excl; cursor[idx] = excl; }
        __syncthreads();
        if (t == 0) carry_s = carry + ctot;
        __syncthreads();
    }
    if (t == 0) row_start[N] = carry_s;
}

__global__ __launch_bounds__(256) void build_adj(
    const int* __restrict__ ei, int E, int ET, int N,
    int* __restrict__ cursor, int* __restrict__ adj)
{
    int e = blockIdx.x * 256 + threadIdx.x;
    if (e >= ET) return;
    int s, d; edge_sd(ei, E, e, s, d);
    if ((unsigned)s >= (unsigned)N || (unsigned)d >= (unsigned)N) return;
    int pos = atomicAdd(&cursor[d], 1);
    adj[pos] = s;
}

// ---------- fused GAT layer 1: online softmax + aggregate + bias + elu ----------
// one wave per dst node; 64 lanes cover 128 channels (2 per lane); 4 heads.
__global__ __launch_bounds__(256) void gat1_fused(
    const int* __restrict__ row_start, const int* __restrict__ adj,
    const float* __restrict__ as_n, const float* __restrict__ ad_n,
    const float* __restrict__ xh, const float* __restrict__ b1,
    float* __restrict__ out, int N)
{
    const int d = blockIdx.x * 4 + (threadIdx.x >> 6);
    if (d >= N) return;
    const int lane = threadIdx.x & 63;
    const int beg = row_start[d], end = row_start[d + 1];
    const float4 adv = ((const float4*)ad_n)[d];
    const float adh[4] = {adv.x, adv.y, adv.z, adv.w};
    float m[4] = {-1e30f, -1e30f, -1e30f, -1e30f};
    float l[4] = {0.f, 0.f, 0.f, 0.f};
    float acc0 = 0.f, acc1 = 0.f;
    const int h0 = lane >> 5;        // head of channel `lane`
    const int h1 = h0 + 2;           // head of channel `lane+64`
    for (int j = beg; j < end; j++) {
        int s = adj[j];
        float4 asv = ((const float4*)as_n)[s];
        float e[4] = {asv.x + adh[0], asv.y + adh[1], asv.z + adh[2], asv.w + adh[3]};
        float p[4], f[4];
#pragma unroll
        for (int h = 0; h < 4; h++) {
            float x = e[h];
            x = (x >= 0.f) ? x : 0.2f * x;
            float mn = fmaxf(m[h], x);
            f[h] = __expf(m[h] - mn);
            p[h] = __expf(x - mn);
            m[h] = mn;
            l[h] = l[h] * f[h] + p[h];
        }
        float xv0 = xh[(size_t)s * 128 + lane];
        float xv1 = xh[(size_t)s * 128 + 64 + lane];
        acc0 = acc0 * f[h0] + p[h0] * xv0;
        acc1 = acc1 * f[h1] + p[h1] * xv1;
    }
    float v0 = acc0 / (l[h0] + 1e-16f) + b1[lane];
    float v1 = acc1 / (l[h1] + 1e-16f) + b1[64 + lane];
    v0 = (v0 > 0.f) ? v0 : expm1f(v0);
    v1 = (v1 > 0.f) ? v1 : expm1f(v1);
    out[(size_t)d * 128 + lane]      = v0;
    out[(size_t)d * 128 + 64 + lane] = v1;
}

// ---------- fused GAT layer 2 (1 head, 64 ch) + elu + mean-pool accumulate ----------
__global__ __launch_bounds__(256) void gat2_fused(
    const int* __restrict__ row_start, const int* __restrict__ adj,
    const float* __restrict__ as_n, const float* __restrict__ ad_n,
    const float* __restrict__ xh, const float* __restrict__ b2,
    const int* __restrict__ batch, float* __restrict__ sums, float* __restrict__ cnts,
    int N, int G)
{
    const int d = blockIdx.x * 4 + (threadIdx.x >> 6);
    if (d >= N) return;
    const int lane = threadIdx.x & 63;
    const int beg = row_start[d], end = row_start[d + 1];
    const float ad = ad_n[d];
    float m = -1e30f, l = 0.f, acc = 0.f;
    for (int j = beg; j < end; j++) {
        int s = adj[j];
        float e = as_n[s] + ad;
        e = (e >= 0.f) ? e : 0.2f * e;
        float mn = fmaxf(m, e);
        float f = __expf(m - mn);
        float p = __expf(e - mn);
        m = mn;
        l = l * f + p;
        acc = acc * f + p * xh[(size_t)s * 64 + lane];
    }
    float v = acc / (l + 1e-16f) + b2[lane];
    v = (v > 0.f) ? v : expm1f(v);
    int g = batch[d];
    if ((unsigned)g >= (unsigned)G) return;
    atomicAdd(&sums[(size_t)g * 64 + lane], v);
    if (lane == 0) atomicAdd(&cnts[g], 1.0f);
}

// ---------- final MLP + 3 heads, one wave per graph ----------
__global__ __launch_bounds__(64) void mlp_head(
    const float* __restrict__ sums, const float* __restrict__ cnts,
    const float* __restrict__ Wm1, const float* __restrict__ bm1,
    const float* __restrict__ Wm2, const float* __restrict__ bm2,
    const float* __restrict__ Wc, const float* __restrict__ bc,
    const float* __restrict__ Wr, const float* __restrict__ br,
    const float* __restrict__ Wv, const float* __restrict__ bv,
    float* __restrict__ out, int G)
{
    int g = blockIdx.x;
    int t = threadIdx.x;
    __shared__ float hrow[64];
    __shared__ float zrow[64];
    float hv = sums[(size_t)g * 64 + t] / fmaxf(cnts[g], 1.0f);
    hrow[t] = hv;
    __syncthreads();
    float z1 = bm1[t];
#pragma unroll 8
    for (int k = 0; k < 64; k++) z1 += hrow[k] * Wm1[k * 64 + t];
    z1 = fmaxf(z1, 0.f);
    zrow[t] = z1;
    __syncthreads();
    float z2 = bm2[t];
#pragma unroll 8
    for (int k = 0; k < 64; k++) z2 += zrow[k] * Wm2[k * 64 + t];
    z2 = fmaxf(z2, 0.f);
    float pc = z2 * Wc[t], pr = z2 * Wr[t], pv = z2 * Wv[t];
#pragma unroll
    for (int m = 32; m >= 1; m >>= 1) {
        pc += __shfl_xor(pc, m);
        pr += __shfl_xor(pr, m);
        pv += __shfl_xor(pv, m);
    }
    if (t == 0) {
        out[g] = pc + bc[0];
        out[G + g] = pr + br[0];
        float s = pv + bv[0];
        out[2 * G + g] = (s > 20.f) ? s : log1pf(expf(s));
    }
}

extern "C" void kernel_launch(void* const* d_in, const int* in_sizes, int n_in,
                              void* d_out, int out_size, void* d_ws, size_t ws_size,
                              hipStream_t stream)
{
    const float* x     = (const float*)d_in[0];
    const int*   ei    = (const int*)d_in[1];
    const int*   batch = (const int*)d_in[2];
    const float* Wp  = (const float*)d_in[3];
    const float* bp  = (const float*)d_in[4];
    const float* W1  = (const float*)d_in[5];
    const float* as1 = (const float*)d_in[6];
    const float* ad1 = (const float*)d_in[7];
    const float* b1  = (const float*)d_in[8];
    const float* W2  = (const float*)d_in[9];
    const float* as2 = (const float*)d_in[10];
    const float* ad2 = (const float*)d_in[11];
    const float* b2  = (const float*)d_in[12];
    const float* Wm1 = (const float*)d_in[13];
    const float* bm1 = (const float*)d_in[14];
    const float* Wm2 = (const float*)d_in[15];
    const float* bm2 = (const float*)d_in[16];
    const float* Wc  = (const float*)d_in[17];
    const float* bc  = (const float*)d_in[18];
    const float* Wr  = (const float*)d_in[19];
    const float* br  = (const float*)d_in[20];
    const float* Wv  = (const float*)d_in[21];
    const float* bv  = (const float*)d_in[22];

    const int N  = in_sizes[0] / F_IN;
    const int E  = in_sizes[1] / 2;
    const int G  = out_size / 3;
    const int ET = E + N;

    float* ws = (float*)d_ws;
    size_t o = 0;
    float* bufA = ws + o; o += (size_t)N * 64;    // h0, later xh2
    float* bufB = ws + o; o += (size_t)N * 128;   // xh1
    float* bufC = ws + o; o += (size_t)N * 128;   // h1 (gat1 output)
    float* as1n = ws + o; o += (size_t)N * 4;
    float* ad1n = ws + o; o += (size_t)N * 4;
    float* as2n = ws + o; o += (size_t)N;
    float* ad2n = ws + o; o += (size_t)N;
    int* row_start = (int*)(ws + o); o += (size_t)N + 1;
    int* cursor    = (int*)(ws + o); o += (size_t)N;
    int* adj       = (int*)(ws + o); o += (size_t)ET;
    // contiguous zero-init block:
    float* zstart = ws + o;
    int*   deg  = (int*)(ws + o); o += (size_t)N;
    float* sums = ws + o;         o += (size_t)G * 64;
    float* cnts = ws + o;         o += (size_t)G;
    size_t zlen = (size_t)(ws + o - zstart) * sizeof(float);

    hipMemsetAsync(zstart, 0, zlen, stream);

    const int gN32 = (N + 31) / 32;
    const int gE   = (ET + 255) / 256;
    const int gN4  = (N + 3) / 4;

    // CSR build (reused by both GAT layers)
    hist_kernel<<<gE, 256, 0, stream>>>(ei, E, ET, N, deg);
    scan_kernel<<<1, 1024, 0, stream>>>(deg, row_start, cursor, N);
    build_adj<<<gE, 256, 0, stream>>>(ei, E, ET, N, cursor, adj);

    // node_proj: h0 = relu(x @ Wp + bp)
    gemm_tile<128, 64, true><<<gN32, 256, 0, stream>>>(x, Wp, bp, bufA, N);
    // gat1 transform: xh1 = h0 @ W1
    gemm_tile<64, 128, false><<<gN32, 256, 0, stream>>>(bufA, W1, nullptr, bufB, N);
    asad1_kernel<<<(N + 1) / 2, 256, 0, stream>>>(bufB, as1, ad1, as1n, ad1n, N);
    // fused edge softmax + aggregate + bias + elu  -> h1 in bufC
    gat1_fused<<<gN4, 256, 0, stream>>>(row_start, adj, as1n, ad1n, bufB, b1, bufC, N);
    // gat2 transform: xh2 = h1 @ W2 (into bufA; h0 dead)
    gemm_tile<128, 64, false><<<gN32, 256, 0, stream>>>(bufC, W2, nullptr, bufA, N);
    asad2_kernel<<<gN4, 256, 0, stream>>>(bufA, as2, ad2, as2n, ad2n, N);
    // fused edge softmax + aggregate + bias + elu + mean-pool accumulate
    gat2_fused<<<gN4, 256, 0, stream>>>(row_start, adj, as2n, ad2n, bufA, b2,
                                        batch, sums, cnts, N, G);
    // final MLP heads
    mlp_head<<<G, 64, 0, stream>>>(sums, cnts, Wm1, bm1, Wm2, bm2,
                                   Wc, bc, Wr, br, Wv, bv, (float*)d_out, G);
}

// Round 3
// 536.437 us; speedup vs baseline: 2.2300x; 1.1506x over previous
//
#include <hip/hip_runtime.h>
#include <hip/hip_bf16.h>
#include <math.h>

#define F_IN 128
#define GH   64

// ---------- helpers ----------
__device__ __forceinline__ void edge_sd(const int* __restrict__ ei, int E, int e, int& s, int& d) {
    if (e < E) { s = ei[e]; d = ei[E + e]; } else { s = d = e - E; }
}

// ---------- GEMM: Y[n,m] = act(sum_k X[n,k]*W[k,m] + b[m]) ----------
template<int K, int M, bool RELU>
__global__ __launch_bounds__(256) void gemm_tile(
    const float* __restrict__ X, const float* __restrict__ W,
    const float* __restrict__ B, float* __restrict__ Y, int nrows)
{
    __shared__ float Wl[K * M];
    __shared__ float Xl[32 * K];
    const int t = threadIdx.x;
    for (int i = t; i < K * M / 4; i += 256)
        ((float4*)Wl)[i] = ((const float4*)W)[i];
    const int base = blockIdx.x * 32;
    for (int i = t; i < 32 * K / 4; i += 256) {
        int r = (i * 4) / K;
        int n = base + r;
        float4 v = make_float4(0.f, 0.f, 0.f, 0.f);
        if (n < nrows) v = ((const float4*)(X + (size_t)n * K))[i - r * (K / 4)];
        ((float4*)Xl)[i] = v;
    }
    __syncthreads();
    constexpr int TPC = 256 / M;       // threads sharing a column
    constexpr int RPT = 32 / TPC;      // rows per thread
    const int m = t % M;
    const int r0 = (t / M) * RPT;
    float acc[RPT];
#pragma unroll
    for (int i = 0; i < RPT; i++) acc[i] = 0.f;
#pragma unroll 4
    for (int k = 0; k < K; k++) {
        float wv = Wl[k * M + m];
#pragma unroll
        for (int i = 0; i < RPT; i++) acc[i] += Xl[(r0 + i) * K + k] * wv;
    }
    const float bb = B ? B[m] : 0.f;
#pragma unroll
    for (int i = 0; i < RPT; i++) {
        int n = base + r0 + i;
        if (n < nrows) {
            float v = acc[i] + bb;
            if (RELU) v = fmaxf(v, 0.f);
            Y[(size_t)n * M + m] = v;
        }
    }
}

// ---------- per-node attention dots, gat1 (4 heads x 32 ch) ----------
__global__ __launch_bounds__(256) void asad1_kernel(
    const float* __restrict__ xh, const float* __restrict__ asw, const float* __restrict__ adw,
    float* __restrict__ as_n, float* __restrict__ ad_n, int N)
{
    const int t = threadIdx.x;
    const int node = blockIdx.x * 2 + (t >> 7);
    const int c = t & 127;
    if (node >= N) return;
    float xv = xh[(size_t)node * 128 + c];
    float ps = xv * asw[c];
    float pd = xv * adw[c];
#pragma unroll
    for (int msk = 16; msk >= 1; msk >>= 1) {
        ps += __shfl_xor(ps, msk);
        pd += __shfl_xor(pd, msk);
    }
    if ((c & 31) == 0) {
        as_n[node * 4 + (c >> 5)] = ps;
        ad_n[node * 4 + (c >> 5)] = pd;
    }
}

// ---------- per-node attention dots, gat2 (1 head x 64 ch) ----------
__global__ __launch_bounds__(256) void asad2_kernel(
    const float* __restrict__ xh, const float* __restrict__ asw, const float* __restrict__ adw,
    float* __restrict__ as_n, float* __restrict__ ad_n, int N)
{
    const int t = threadIdx.x;
    const int node = blockIdx.x * 4 + (t >> 6);
    const int c = t & 63;
    if (node >= N) return;
    float xv = xh[(size_t)node * 64 + c];
    float ps = xv * asw[c];
    float pd = xv * adw[c];
#pragma unroll
    for (int msk = 32; msk >= 1; msk >>= 1) {
        ps += __shfl_xor(ps, msk);
        pd += __shfl_xor(pd, msk);
    }
    if (c == 0) { as_n[node] = ps; ad_n[node] = pd; }
}

// ---------- CSR build ----------
__global__ __launch_bounds__(256) void hist_kernel(
    const int* __restrict__ ei, int E, int ET, int N, int* __restrict__ deg)
{
    int e = blockIdx.x * 256 + threadIdx.x;
    if (e >= ET) return;
    int s, d; edge_sd(ei, E, e, s, d);
    if ((unsigned)s >= (unsigned)N || (unsigned)d >= (unsigned)N) return;
    atomicAdd(&deg[d], 1);
}

__global__ __launch_bounds__(1024) void scan_kernel(
    const int* __restrict__ deg, int* __restrict__ row_start,
    int* __restrict__ cursor, int N)
{
    __shared__ int wsum[16];
    __shared__ int wbase[16];
    __shared__ int ctot;
    __shared__ int carry_s;
    const int t = threadIdx.x, lane = t & 63, w = t >> 6;
    if (t == 0) carry_s = 0;
    __syncthreads();
    for (int base = 0; base < N; base += 1024) {
        int idx = base + t;
        int v = (idx < N) ? deg[idx] : 0;
        int val = v;
#pragma unroll
        for (int off = 1; off < 64; off <<= 1) {
            int n = __shfl_up(val, off);
            if (lane >= off) val += n;
        }
        if (lane == 63) wsum[w] = val;
        __syncthreads();
        if (w == 0 && lane < 16) {
            int s = wsum[lane];
            int sv = s;
#pragma unroll
            for (int off = 1; off < 16; off <<= 1) {
                int n = __shfl_up(sv, off);
                if (lane >= off) sv += n;
            }
            wbase[lane] = sv - s;
            if (lane == 15) ctot = sv;
        }
        __syncthreads();
        int carry = carry_s;
        int excl = carry + wbase[w] + (val - v);
        if (idx < N) { row_start[idx] = excl; cursor[idx] = excl; }
        __syncthreads();
        if (t == 0) carry_s = carry + ctot;
        __syncthreads();
    }
    if (t == 0) row_start[N] = carry_s;
}

__global__ __launch_bounds__(256) void build_adj(
    const int* __restrict__ ei, int E, int ET, int N,
    int* __restrict__ cursor, int* __restrict__ adj)
{
    int e = blockIdx.x * 256 + threadIdx.x;
    if (e >= ET) return;
    int s, d; edge_sd(ei, E, e, s, d);
    if ((unsigned)s >= (unsigned)N || (unsigned)d >= (unsigned)N) return;
    int pos = atomicAdd(&cursor[d], 1);
    adj[pos] = s;
}

// ---------- fused GAT layer 1 ----------
// One wave per dst node. Pass 1: edge-parallel max per head. Pass 2 (per
// 64-edge chunk): edge-parallel p=exp(e-m) -> LDS, denominator partials in
// regs; then channel-parallel accumulate (float2 per lane = 128 ch).
__global__ __launch_bounds__(256) void gat1_fused(
    const int* __restrict__ row_start, const int* __restrict__ adj,
    const float* __restrict__ as_n, const float* __restrict__ ad_n,
    const float* __restrict__ xh, const float* __restrict__ b1,
    float* __restrict__ out, int N)
{
    __shared__ float s_alpha[4][64 * 4];
    __shared__ int   s_src[4][64];
    const int w = threadIdx.x >> 6;
    const int d = blockIdx.x * 4 + w;
    if (d >= N) return;
    const int lane = threadIdx.x & 63;
    const int beg = row_start[d], end = row_start[d + 1];
    const int deg = end - beg;
    const float4 adv = ((const float4*)ad_n)[d];
    const int h = lane >> 4;            // head of channels {2*lane, 2*lane+1}

    // pass 1: per-head max over all incoming edges
    float m[4] = {-1e30f, -1e30f, -1e30f, -1e30f};
    for (int j0 = 0; j0 < deg; j0 += 64) {
        int j = j0 + lane;
        if (j < deg) {
            int s = adj[beg + j];
            float4 asv = ((const float4*)as_n)[s];
            float e0 = asv.x + adv.x; e0 = (e0 >= 0.f) ? e0 : 0.2f * e0; m[0] = fmaxf(m[0], e0);
            float e1 = asv.y + adv.y; e1 = (e1 >= 0.f) ? e1 : 0.2f * e1; m[1] = fmaxf(m[1], e1);
            float e2 = asv.z + adv.z; e2 = (e2 >= 0.f) ? e2 : 0.2f * e2; m[2] = fmaxf(m[2], e2);
            float e3 = asv.w + adv.w; e3 = (e3 >= 0.f) ? e3 : 0.2f * e3; m[3] = fmaxf(m[3], e3);
        }
    }
#pragma unroll
    for (int msk = 32; msk >= 1; msk >>= 1) {
#pragma unroll
        for (int hh = 0; hh < 4; hh++) m[hh] = fmaxf(m[hh], __shfl_xor(m[hh], msk));
    }

    // pass 2: exp + LDS stage, then channel-parallel accumulate
    float l[4] = {0.f, 0.f, 0.f, 0.f};
    float accx = 0.f, accy = 0.f;
    for (int j0 = 0; j0 < deg; j0 += 64) {
        int j = j0 + lane;
        int chunk = min(64, deg - j0);
        if (j < deg) {
            int s = adj[beg + j];
            s_src[w][lane] = s;
            float4 asv = ((const float4*)as_n)[s];
            float p0, p1, p2, p3;
            {
                float e0 = asv.x + adv.x; e0 = (e0 >= 0.f) ? e0 : 0.2f * e0; p0 = __expf(e0 - m[0]); l[0] += p0;
                float e1 = asv.y + adv.y; e1 = (e1 >= 0.f) ? e1 : 0.2f * e1; p1 = __expf(e1 - m[1]); l[1] += p1;
                float e2 = asv.z + adv.z; e2 = (e2 >= 0.f) ? e2 : 0.2f * e2; p2 = __expf(e2 - m[2]); l[2] += p2;
                float e3 = asv.w + adv.w; e3 = (e3 >= 0.f) ? e3 : 0.2f * e3; p3 = __expf(e3 - m[3]); l[3] += p3;
            }
            ((float4*)&s_alpha[w][lane * 4])[0] = make_float4(p0, p1, p2, p3);
        }
        __threadfence_block();   // lgkmcnt(0): LDS writes visible to this wave's reads
        int j2 = 0;
        for (; j2 + 2 <= chunk; j2 += 2) {
            int sA = s_src[w][j2];
            int sB = s_src[w][j2 + 1];
            float aA = s_alpha[w][j2 * 4 + h];
            float aB = s_alpha[w][(j2 + 1) * 4 + h];
            float2 xA = ((const float2*)xh)[(size_t)sA * 64 + lane];
            float2 xB = ((const float2*)xh)[(size_t)sB * 64 + lane];
            accx += aA * xA.x + aB * xB.x;
            accy += aA * xA.y + aB * xB.y;
        }
        if (j2 < chunk) {
            int sA = s_src[w][j2];
            float aA = s_alpha[w][j2 * 4 + h];
            float2 xA = ((const float2*)xh)[(size_t)sA * 64 + lane];
            accx += aA * xA.x;
            accy += aA * xA.y;
        }
        __threadfence_block();   // reads done before next chunk overwrites
    }
#pragma unroll
    for (int msk = 32; msk >= 1; msk >>= 1) {
#pragma unroll
        for (int hh = 0; hh < 4; hh++) l[hh] += __shfl_xor(l[hh], msk);
    }
    const float inv = 1.0f / (l[h] + 1e-16f);
    float2 bb = ((const float2*)b1)[lane];
    float v0 = accx * inv + bb.x;
    float v1 = accy * inv + bb.y;
    v0 = (v0 > 0.f) ? v0 : expm1f(v0);
    v1 = (v1 > 0.f) ? v1 : expm1f(v1);
    ((float2*)out)[(size_t)d * 64 + lane] = make_float2(v0, v1);
}

// ---------- fused GAT layer 2 (1 head, 64 ch) + elu + mean-pool accumulate ----------
__global__ __launch_bounds__(256) void gat2_fused(
    const int* __restrict__ row_start, const int* __restrict__ adj,
    const float* __restrict__ as_n, const float* __restrict__ ad_n,
    const float* __restrict__ xh, const float* __restrict__ b2,
    const int* __restrict__ batch, float* __restrict__ sums, float* __restrict__ cnts,
    int N, int G)
{
    __shared__ float s_p[4][64];
    __shared__ int   s_src[4][64];
    const int w = threadIdx.x >> 6;
    const int d = blockIdx.x * 4 + w;
    if (d >= N) return;
    const int lane = threadIdx.x & 63;
    const int beg = row_start[d], end = row_start[d + 1];
    const int deg = end - beg;
    const float ad = ad_n[d];

    // pass 1: max
    float m = -1e30f;
    for (int j0 = 0; j0 < deg; j0 += 64) {
        int j = j0 + lane;
        if (j < deg) {
            int s = adj[beg + j];
            float e = as_n[s] + ad;
            e = (e >= 0.f) ? e : 0.2f * e;
            m = fmaxf(m, e);
        }
    }
#pragma unroll
    for (int msk = 32; msk >= 1; msk >>= 1) m = fmaxf(m, __shfl_xor(m, msk));

    // pass 2
    float l = 0.f, acc = 0.f;
    for (int j0 = 0; j0 < deg; j0 += 64) {
        int j = j0 + lane;
        int chunk = min(64, deg - j0);
        if (j < deg) {
            int s = adj[beg + j];
            s_src[w][lane] = s;
            float e = as_n[s] + ad;
            e = (e >= 0.f) ? e : 0.2f * e;
            float p = __expf(e - m);
            l += p;
            s_p[w][lane] = p;
        }
        __threadfence_block();
        int j2 = 0;
        for (; j2 + 2 <= chunk; j2 += 2) {
            int sA = s_src[w][j2];
            int sB = s_src[w][j2 + 1];
            float aA = s_p[w][j2];
            float aB = s_p[w][j2 + 1];
            float xA = xh[(size_t)sA * 64 + lane];
            float xB = xh[(size_t)sB * 64 + lane];
            acc += aA * xA + aB * xB;
        }
        if (j2 < chunk) {
            int sA = s_src[w][j2];
            acc += s_p[w][j2] * xh[(size_t)sA * 64 + lane];
        }
        __threadfence_block();
    }
#pragma unroll
    for (int msk = 32; msk >= 1; msk >>= 1) l += __shfl_xor(l, msk);

    float v = acc / (l + 1e-16f) + b2[lane];
    v = (v > 0.f) ? v : expm1f(v);
    int g = batch[d];
    if ((unsigned)g >= (unsigned)G) return;
    atomicAdd(&sums[(size_t)g * 64 + lane], v);
    if (lane == 0) atomicAdd(&cnts[g], 1.0f);
}

// ---------- final MLP + 3 heads, one wave per graph ----------
__global__ __launch_bounds__(64) void mlp_head(
    const float* __restrict__ sums, const float* __restrict__ cnts,
    const float* __restrict__ Wm1, const float* __restrict__ bm1,
    const float* __restrict__ Wm2, const float* __restrict__ bm2,
    const float* __restrict__ Wc, const float* __restrict__ bc,
    const float* __restrict__ Wr, const float* __restrict__ br,
    const float* __restrict__ Wv, const float* __restrict__ bv,
    float* __restrict__ out, int G)
{
    int g = blockIdx.x;
    int t = threadIdx.x;
    __shared__ float hrow[64];
    __shared__ float zrow[64];
    float hv = sums[(size_t)g * 64 + t] / fmaxf(cnts[g], 1.0f);
    hrow[t] = hv;
    __syncthreads();
    float z1 = bm1[t];
#pragma unroll 8
    for (int k = 0; k < 64; k++) z1 += hrow[k] * Wm1[k * 64 + t];
    z1 = fmaxf(z1, 0.f);
    zrow[t] = z1;
    __syncthreads();
    float z2 = bm2[t];
#pragma unroll 8
    for (int k = 0; k < 64; k++) z2 += zrow[k] * Wm2[k * 64 + t];
    z2 = fmaxf(z2, 0.f);
    float pc = z2 * Wc[t], pr = z2 * Wr[t], pv = z2 * Wv[t];
#pragma unroll
    for (int m = 32; m >= 1; m >>= 1) {
        pc += __shfl_xor(pc, m);
        pr += __shfl_xor(pr, m);
        pv += __shfl_xor(pv, m);
    }
    if (t == 0) {
        out[g] = pc + bc[0];
        out[G + g] = pr + br[0];
        float s = pv + bv[0];
        out[2 * G + g] = (s > 20.f) ? s : log1pf(expf(s));
    }
}

extern "C" void kernel_launch(void* const* d_in, const int* in_sizes, int n_in,
                              void* d_out, int out_size, void* d_ws, size_t ws_size,
                              hipStream_t stream)
{
    const float* x     = (const float*)d_in[0];
    const int*   ei    = (const int*)d_in[1];
    const int*   batch = (const int*)d_in[2];
    const float* Wp  = (const float*)d_in[3];
    const float* bp  = (const float*)d_in[4];
    const float* W1  = (const float*)d_in[5];
    const float* as1 = (const float*)d_in[6];
    const float* ad1 = (const float*)d_in[7];
    const float* b1  = (const float*)d_in[8];
    const float* W2  = (const float*)d_in[9];
    const float* as2 = (const float*)d_in[10];
    const float* ad2 = (const float*)d_in[11];
    const float* b2  = (const float*)d_in[12];
    const float* Wm1 = (const float*)d_in[13];
    const float* bm1 = (const float*)d_in[14];
    const float* Wm2 = (const float*)d_in[15];
    const float* bm2 = (const float*)d_in[16];
    const float* Wc  = (const float*)d_in[17];
    const float* bc  = (const float*)d_in[18];
    const float* Wr  = (const float*)d_in[19];
    const float* br  = (const float*)d_in[20];
    const float* Wv  = (const float*)d_in[21];
    const float* bv  = (const float*)d_in[22];

    const int N  = in_sizes[0] / F_IN;
    const int E  = in_sizes[1] / 2;
    const int G  = out_size / 3;
    const int ET = E + N;

    float* ws = (float*)d_ws;
    size_t o = 0;
    float* bufA = ws + o; o += (size_t)N * 64;    // h0, later xh2
    float* bufB = ws + o; o += (size_t)N * 128;   // xh1
    float* bufC = ws + o; o += (size_t)N * 128;   // h1 (gat1 output)
    float* as1n = ws + o; o += (size_t)N * 4;
    float* ad1n = ws + o; o += (size_t)N * 4;
    float* as2n = ws + o; o += (size_t)N;
    float* ad2n = ws + o; o += (size_t)N;
    int* row_start = (int*)(ws + o); o += (size_t)N + 1;
    int* cursor    = (int*)(ws + o); o += (size_t)N;
    int* adj       = (int*)(ws + o); o += (size_t)ET;
    // contiguous zero-init block:
    float* zstart = ws + o;
    int*   deg  = (int*)(ws + o); o += (size_t)N;
    float* sums = ws + o;         o += (size_t)G * 64;
    float* cnts = ws + o;         o += (size_t)G;
    size_t zlen = (size_t)(ws + o - zstart) * sizeof(float);

    hipMemsetAsync(zstart, 0, zlen, stream);

    const int gN32 = (N + 31) / 32;
    const int gE   = (ET + 255) / 256;
    const int gN4  = (N + 3) / 4;

    // CSR build (reused by both GAT layers)
    hist_kernel<<<gE, 256, 0, stream>>>(ei, E, ET, N, deg);
    scan_kernel<<<1, 1024, 0, stream>>>(deg, row_start, cursor, N);
    build_adj<<<gE, 256, 0, stream>>>(ei, E, ET, N, cursor, adj);

    // node_proj: h0 = relu(x @ Wp + bp)
    gemm_tile<128, 64, true><<<gN32, 256, 0, stream>>>(x, Wp, bp, bufA, N);
    // gat1 transform: xh1 = h0 @ W1
    gemm_tile<64, 128, false><<<gN32, 256, 0, stream>>>(bufA, W1, nullptr, bufB, N);
    asad1_kernel<<<(N + 1) / 2, 256, 0, stream>>>(bufB, as1, ad1, as1n, ad1n, N);
    // fused edge softmax + aggregate + bias + elu  -> h1 in bufC
    gat1_fused<<<gN4, 256, 0, stream>>>(row_start, adj, as1n, ad1n, bufB, b1, bufC, N);
    // gat2 transform: xh2 = h1 @ W2 (into bufA; h0 dead)
    gemm_tile<128, 64, false><<<gN32, 256, 0, stream>>>(bufC, W2, nullptr, bufA, N);
    asad2_kernel<<<gN4, 256, 0, stream>>>(bufA, as2, ad2, as2n, ad2n, N);
    // fused edge softmax + aggregate + bias + elu + mean-pool accumulate
    gat2_fused<<<gN4, 256, 0, stream>>>(row_start, adj, as2n, ad2n, bufA, b2,
                                        batch, sums, cnts, N, G);
    // final MLP heads
    mlp_head<<<G, 64, 0, stream>>>(sums, cnts, Wm1, bm1, Wm2, bm2,
                                   Wc, bc, Wr, br, Wv, bv, (float*)d_out, G);
}

// Round 5
// 519.084 us; speedup vs baseline: 2.3045x; 1.0334x over previous
//
#include <hip/hip_runtime.h>
#include <hip/hip_bf16.h>
#include <math.h>

#define F_IN 128
#define GH   64
#define CAP  128   // per-row LDS stash capacity (edges); overflow recomputes

// ---------- helpers ----------
__device__ __forceinline__ void edge_sd(const int* __restrict__ ei, int E, int e, int& s, int& d) {
    if (e < E) { s = ei[e]; d = ei[E + e]; } else { s = d = e - E; }
}
__device__ __forceinline__ float leaky(float x) { return (x >= 0.f) ? x : 0.2f * x; }

// ---------- GEMM: Y[n,m] = act(sum_k X[n,k]*W[k,m] + b[m]) ----------
template<int K, int M, bool RELU>
__global__ __launch_bounds__(256) void gemm_tile(
    const float* __restrict__ X, const float* __restrict__ W,
    const float* __restrict__ B, float* __restrict__ Y, int nrows)
{
    __shared__ float Wl[K * M];
    __shared__ float Xl[32 * K];
    const int t = threadIdx.x;
    for (int i = t; i < K * M / 4; i += 256)
        ((float4*)Wl)[i] = ((const float4*)W)[i];
    const int base = blockIdx.x * 32;
    for (int i = t; i < 32 * K / 4; i += 256) {
        int r = (i * 4) / K;
        int n = base + r;
        float4 v = make_float4(0.f, 0.f, 0.f, 0.f);
        if (n < nrows) v = ((const float4*)(X + (size_t)n * K))[i - r * (K / 4)];
        ((float4*)Xl)[i] = v;
    }
    __syncthreads();
    constexpr int TPC = 256 / M;       // threads sharing a column
    constexpr int RPT = 32 / TPC;      // rows per thread
    const int m = t % M;
    const int r0 = (t / M) * RPT;
    float acc[RPT];
#pragma unroll
    for (int i = 0; i < RPT; i++) acc[i] = 0.f;
#pragma unroll 4
    for (int k = 0; k < K; k++) {
        float wv = Wl[k * M + m];
#pragma unroll
        for (int i = 0; i < RPT; i++) acc[i] += Xl[(r0 + i) * K + k] * wv;
    }
    const float bb = B ? B[m] : 0.f;
#pragma unroll
    for (int i = 0; i < RPT; i++) {
        int n = base + r0 + i;
        if (n < nrows) {
            float v = acc[i] + bb;
            if (RELU) v = fmaxf(v, 0.f);
            Y[(size_t)n * M + m] = v;
        }
    }
}

// ---------- per-node attention dots, gat1 (4 heads x 32 ch) ----------
__global__ __launch_bounds__(256) void asad1_kernel(
    const float* __restrict__ xh, const float* __restrict__ asw, const float* __restrict__ adw,
    float* __restrict__ as_n, float* __restrict__ ad_n, int N)
{
    const int t = threadIdx.x;
    const int node = blockIdx.x * 2 + (t >> 7);
    const int c = t & 127;
    if (node >= N) return;
    float xv = xh[(size_t)node * 128 + c];
    float ps = xv * asw[c];
    float pd = xv * adw[c];
#pragma unroll
    for (int msk = 16; msk >= 1; msk >>= 1) {
        ps += __shfl_xor(ps, msk);
        pd += __shfl_xor(pd, msk);
    }
    if ((c & 31) == 0) {
        as_n[node * 4 + (c >> 5)] = ps;
        ad_n[node * 4 + (c >> 5)] = pd;
    }
}

// ---------- per-node attention dots, gat2 (1 head x 64 ch) ----------
__global__ __launch_bounds__(256) void asad2_kernel(
    const float* __restrict__ xh, const float* __restrict__ asw, const float* __restrict__ adw,
    float* __restrict__ as_n, float* __restrict__ ad_n, int N)
{
    const int t = threadIdx.x;
    const int node = blockIdx.x * 4 + (t >> 6);
    const int c = t & 63;
    if (node >= N) return;
    float xv = xh[(size_t)node * 64 + c];
    float ps = xv * asw[c];
    float pd = xv * adw[c];
#pragma unroll
    for (int msk = 32; msk >= 1; msk >>= 1) {
        ps += __shfl_xor(ps, msk);
        pd += __shfl_xor(pd, msk);
    }
    if (c == 0) { as_n[node] = ps; ad_n[node] = pd; }
}

// ---------- CSR build ----------
__global__ __launch_bounds__(256) void hist_kernel(
    const int* __restrict__ ei, int E, int ET, int N, int* __restrict__ deg)
{
    int e = blockIdx.x * 256 + threadIdx.x;
    if (e >= ET) return;
    int s, d; edge_sd(ei, E, e, s, d);
    if ((unsigned)s >= (unsigned)N || (unsigned)d >= (unsigned)N) return;
    atomicAdd(&deg[d], 1);
}

__global__ __launch_bounds__(1024) void scan_kernel(
    const int* __restrict__ deg, int* __restrict__ row_start,
    int* __restrict__ cursor, int N)
{
    __shared__ int wsum[16];
    __shared__ int wbase[16];
    __shared__ int ctot;
    __shared__ int carry_s;
    const int t = threadIdx.x, lane = t & 63, w = t >> 6;
    if (t == 0) carry_s = 0;
    __syncthreads();
    for (int base = 0; base < N; base += 1024) {
        int idx = base + t;
        int v = (idx < N) ? deg[idx] : 0;
        int val = v;
#pragma unroll
        for (int off = 1; off < 64; off <<= 1) {
            int n = __shfl_up(val, off);
            if (lane >= off) val += n;
        }
        if (lane == 63) wsum[w] = val;
        __syncthreads();
        if (w == 0 && lane < 16) {
            int s = wsum[lane];
            int sv = s;
#pragma unroll
            for (int off = 1; off < 16; off <<= 1) {
                int n = __shfl_up(sv, off);
                if (lane >= off) sv += n;
            }
            wbase[lane] = sv - s;
            if (lane == 15) ctot = sv;
        }
        __syncthreads();
        int carry = carry_s;
        int excl = carry + wbase[w] + (val - v);
        if (idx < N) { row_start[idx] = excl; cursor[idx] = excl; }
        __syncthreads();
        if (t == 0) carry_s = carry + ctot;
        __syncthreads();
    }
    if (t == 0) row_start[N] = carry_s;
}

__global__ __launch_bounds__(256) void build_adj(
    const int* __restrict__ ei, int E, int ET, int N,
    int* __restrict__ cursor, int* __restrict__ adj)
{
    int e = blockIdx.x * 256 + threadIdx.x;
    if (e >= ET) return;
    int s, d; edge_sd(ei, E, e, s, d);
    if ((unsigned)s >= (unsigned)N || (unsigned)d >= (unsigned)N) return;
    int pos = atomicAdd(&cursor[d], 1);
    adj[pos] = s;
}

// ---------- fused GAT layer 1 (4 heads x 32 ch, concat) ----------
// One wave per dst node. Pass 1: edge-parallel logits -> LDS stash + head max.
// Pass 2: probs in LDS + denom. Accumulate: two 32-lane halves process
// even/odd edges; each lane carries 4 channels (float4 = full 128-ch row/half).
__global__ __launch_bounds__(256) void gat1_fused(
    const int* __restrict__ row_start, const int* __restrict__ adj,
    const float* __restrict__ as_n, const float* __restrict__ ad_n,
    const float* __restrict__ xh, const float* __restrict__ b1,
    float* __restrict__ out, int N)
{
    __shared__ int   s_src[4][CAP];
    __shared__ float s_pl[4][CAP * 4];
    const int w = threadIdx.x >> 6;
    const int d = blockIdx.x * 4 + w;
    if (d >= N) return;
    const int lane = threadIdx.x & 63;
    const int li = lane & 31;
    const int half = lane >> 5;
    const int beg = row_start[d], end = row_start[d + 1];
    const int deg = end - beg;
    const float4 adv = ((const float4*)ad_n)[d];

    // pass 1: logits -> LDS, per-head max
    float m[4] = {-1e30f, -1e30f, -1e30f, -1e30f};
    for (int j0 = 0; j0 < deg; j0 += 64) {
        int j = j0 + lane;
        if (j < deg) {
            int s = adj[beg + j];
            float4 asv = ((const float4*)as_n)[s];
            float e0 = leaky(asv.x + adv.x);
            float e1 = leaky(asv.y + adv.y);
            float e2 = leaky(asv.z + adv.z);
            float e3 = leaky(asv.w + adv.w);
            m[0] = fmaxf(m[0], e0); m[1] = fmaxf(m[1], e1);
            m[2] = fmaxf(m[2], e2); m[3] = fmaxf(m[3], e3);
            if (j < CAP) {
                s_src[w][j] = s;
                ((float4*)&s_pl[w][j * 4])[0] = make_float4(e0, e1, e2, e3);
            }
        }
    }
#pragma unroll
    for (int msk = 32; msk >= 1; msk >>= 1) {
#pragma unroll
        for (int hh = 0; hh < 4; hh++) m[hh] = fmaxf(m[hh], __shfl_xor(m[hh], msk));
    }
    __threadfence_block();

    // pass 2: probs + denom
    float l[4] = {0.f, 0.f, 0.f, 0.f};
    for (int j0 = 0; j0 < deg; j0 += 64) {
        int j = j0 + lane;
        if (j < deg) {
            float e0, e1, e2, e3;
            if (j < CAP) {
                float4 ev = ((const float4*)&s_pl[w][j * 4])[0];
                e0 = ev.x; e1 = ev.y; e2 = ev.z; e3 = ev.w;
            } else {
                int s = adj[beg + j];
                float4 asv = ((const float4*)as_n)[s];
                e0 = leaky(asv.x + adv.x); e1 = leaky(asv.y + adv.y);
                e2 = leaky(asv.z + adv.z); e3 = leaky(asv.w + adv.w);
            }
            float p0 = __expf(e0 - m[0]), p1 = __expf(e1 - m[1]);
            float p2 = __expf(e2 - m[2]), p3 = __expf(e3 - m[3]);
            l[0] += p0; l[1] += p1; l[2] += p2; l[3] += p3;
            if (j < CAP)
                ((float4*)&s_pl[w][j * 4])[0] = make_float4(p0, p1, p2, p3);
        }
    }
#pragma unroll
    for (int msk = 32; msk >= 1; msk >>= 1) {
#pragma unroll
        for (int hh = 0; hh < 4; hh++) l[hh] += __shfl_xor(l[hh], msk);
    }
    __threadfence_block();

    // accumulate: half 0 -> even edges, half 1 -> odd edges; float4/lane
    const int h = li >> 3;           // head of channels 4*li .. 4*li+3
    float4 acc = make_float4(0.f, 0.f, 0.f, 0.f);
#pragma unroll 2
    for (int j = half; j < deg; j += 2) {
        int s; float a;
        if (j < CAP) {
            s = s_src[w][j];
            a = s_pl[w][j * 4 + h];
        } else {
            s = adj[beg + j];
            float4 asv = ((const float4*)as_n)[s];
            float ah[4] = {leaky(asv.x + adv.x), leaky(asv.y + adv.y),
                           leaky(asv.z + adv.z), leaky(asv.w + adv.w)};
            a = __expf(ah[h] - m[h]);
        }
        float4 xv = ((const float4*)xh)[(size_t)s * 32 + li];
        acc.x += a * xv.x; acc.y += a * xv.y; acc.z += a * xv.z; acc.w += a * xv.w;
    }
    acc.x += __shfl_xor(acc.x, 32);
    acc.y += __shfl_xor(acc.y, 32);
    acc.z += __shfl_xor(acc.z, 32);
    acc.w += __shfl_xor(acc.w, 32);

    const float inv = 1.0f / (l[h] + 1e-16f);
    float4 bb = ((const float4*)b1)[li];
    float v0 = acc.x * inv + bb.x;
    float v1 = acc.y * inv + bb.y;
    float v2 = acc.z * inv + bb.z;
    float v3 = acc.w * inv + bb.w;
    v0 = (v0 > 0.f) ? v0 : expm1f(v0);
    v1 = (v1 > 0.f) ? v1 : expm1f(v1);
    v2 = (v2 > 0.f) ? v2 : expm1f(v2);
    v3 = (v3 > 0.f) ? v3 : expm1f(v3);
    if (half == 0)
        ((float4*)out)[(size_t)d * 32 + li] = make_float4(v0, v1, v2, v3);
}

// ---------- fused GAT layer 2 (1 head, 64 ch) + elu + mean-pool accumulate ----------
__global__ __launch_bounds__(256) void gat2_fused(
    const int* __restrict__ row_start, const int* __restrict__ adj,
    const float* __restrict__ as_n, const float* __restrict__ ad_n,
    const float* __restrict__ xh, const float* __restrict__ b2,
    const int* __restrict__ batch, float* __restrict__ sums, float* __restrict__ cnts,
    int N, int G)
{
    __shared__ int   s_src[4][CAP];
    __shared__ float s_p[4][CAP];
    const int w = threadIdx.x >> 6;
    const int d = blockIdx.x * 4 + w;
    if (d >= N) return;
    const int lane = threadIdx.x & 63;
    const int li = lane & 31;
    const int half = lane >> 5;
    const int beg = row_start[d], end = row_start[d + 1];
    const int deg = end - beg;
    const float ad = ad_n[d];

    // pass 1: logits -> LDS, max
    float m = -1e30f;
    for (int j0 = 0; j0 < deg; j0 += 64) {
        int j = j0 + lane;
        if (j < deg) {
            int s = adj[beg + j];
            float e = leaky(as_n[s] + ad);
            m = fmaxf(m, e);
            if (j < CAP) { s_src[w][j] = s; s_p[w][j] = e; }
        }
    }
#pragma unroll
    for (int msk = 32; msk >= 1; msk >>= 1) m = fmaxf(m, __shfl_xor(m, msk));
    __threadfence_block();

    // pass 2: probs + denom
    float l = 0.f;
    for (int j0 = 0; j0 < deg; j0 += 64) {
        int j = j0 + lane;
        if (j < deg) {
            float e = (j < CAP) ? s_p[w][j] : leaky(as_n[adj[beg + j]] + ad);
            float p = __expf(e - m);
            l += p;
            if (j < CAP) s_p[w][j] = p;
        }
    }
#pragma unroll
    for (int msk = 32; msk >= 1; msk >>= 1) l += __shfl_xor(l, msk);
    __threadfence_block();

    // accumulate: halves on even/odd edges; float2/lane = full 64-ch row
    float2 acc = make_float2(0.f, 0.f);
#pragma unroll 2
    for (int j = half; j < deg; j += 2) {
        int s; float a;
        if (j < CAP) {
            s = s_src[w][j];
            a = s_p[w][j];
        } else {
            s = adj[beg + j];
            a = __expf(leaky(as_n[s] + ad) - m);
        }
        float2 xv = ((const float2*)xh)[(size_t)s * 32 + li];
        acc.x += a * xv.x; acc.y += a * xv.y;
    }
    acc.x += __shfl_xor(acc.x, 32);
    acc.y += __shfl_xor(acc.y, 32);

    const float inv = 1.0f / (l + 1e-16f);
    float2 bb = ((const float2*)b2)[li];
    float v0 = acc.x * inv + bb.x;
    float v1 = acc.y * inv + bb.y;
    v0 = (v0 > 0.f) ? v0 : expm1f(v0);
    v1 = (v1 > 0.f) ? v1 : expm1f(v1);
    int g = batch[d];
    if ((unsigned)g >= (unsigned)G) return;
    if (half == 0) {
        atomicAdd(&sums[(size_t)g * 64 + 2 * li],     v0);
        atomicAdd(&sums[(size_t)g * 64 + 2 * li + 1], v1);
        if (li == 0) atomicAdd(&cnts[g], 1.0f);
    }
}

// ---------- final MLP + 3 heads, one wave per graph ----------
__global__ __launch_bounds__(64) void mlp_head(
    const float* __restrict__ sums, const float* __restrict__ cnts,
    const float* __restrict__ Wm1, const float* __restrict__ bm1,
    const float* __restrict__ Wm2, const float* __restrict__ bm2,
    const float* __restrict__ Wc, const float* __restrict__ bc,
    const float* __restrict__ Wr, const float* __restrict__ br,
    const float* __restrict__ Wv, const float* __restrict__ bv,
    float* __restrict__ out, int G)
{
    int g = blockIdx.x;
    int t = threadIdx.x;
    __shared__ float hrow[64];
    __shared__ float zrow[64];
    float hv = sums[(size_t)g * 64 + t] / fmaxf(cnts[g], 1.0f);
    hrow[t] = hv;
    __syncthreads();
    float z1 = bm1[t];
#pragma unroll 8
    for (int k = 0; k < 64; k++) z1 += hrow[k] * Wm1[k * 64 + t];
    z1 = fmaxf(z1, 0.f);
    zrow[t] = z1;
    __syncthreads();
    float z2 = bm2[t];
#pragma unroll 8
    for (int k = 0; k < 64; k++) z2 += zrow[k] * Wm2[k * 64 + t];
    z2 = fmaxf(z2, 0.f);
    float pc = z2 * Wc[t], pr = z2 * Wr[t], pv = z2 * Wv[t];
#pragma unroll
    for (int m = 32; m >= 1; m >>= 1) {
        pc += __shfl_xor(pc, m);
        pr += __shfl_xor(pr, m);
        pv += __shfl_xor(pv, m);
    }
    if (t == 0) {
        out[g] = pc + bc[0];
        out[G + g] = pr + br[0];
        float s = pv + bv[0];
        out[2 * G + g] = (s > 20.f) ? s : log1pf(expf(s));
    }
}

extern "C" void kernel_launch(void* const* d_in, const int* in_sizes, int n_in,
                              void* d_out, int out_size, void* d_ws, size_t ws_size,
                              hipStream_t stream)
{
    const float* x     = (const float*)d_in[0];
    const int*   ei    = (const int*)d_in[1];
    const int*   batch = (const int*)d_in[2];
    const float* Wp  = (const float*)d_in[3];
    const float* bp  = (const float*)d_in[4];
    const float* W1  = (const float*)d_in[5];
    const float* as1 = (const float*)d_in[6];
    const float* ad1 = (const float*)d_in[7];
    const float* b1  = (const float*)d_in[8];
    const float* W2  = (const float*)d_in[9];
    const float* as2 = (const float*)d_in[10];
    const float* ad2 = (const float*)d_in[11];
    const float* b2  = (const float*)d_in[12];
    const float* Wm1 = (const float*)d_in[13];
    const float* bm1 = (const float*)d_in[14];
    const float* Wm2 = (const float*)d_in[15];
    const float* bm2 = (const float*)d_in[16];
    const float* Wc  = (const float*)d_in[17];
    const float* bc  = (const float*)d_in[18];
    const float* Wr  = (const float*)d_in[19];
    const float* br  = (const float*)d_in[20];
    const float* Wv  = (const float*)d_in[21];
    const float* bv  = (const float*)d_in[22];

    const int N  = in_sizes[0] / F_IN;
    const int E  = in_sizes[1] / 2;
    const int G  = out_size / 3;
    const int ET = E + N;

    float* ws = (float*)d_ws;
    size_t o = 0;
    float* bufA = ws + o; o += (size_t)N * 64;    // h0, later xh2
    float* bufB = ws + o; o += (size_t)N * 128;   // xh1
    float* bufC = ws + o; o += (size_t)N * 128;   // h1 (gat1 output)
    float* as1n = ws + o; o += (size_t)N * 4;
    float* ad1n = ws + o; o += (size_t)N * 4;
    float* as2n = ws + o; o += (size_t)N;
    float* ad2n = ws + o; o += (size_t)N;
    int* row_start = (int*)(ws + o); o += (size_t)N + 1;
    int* cursor    = (int*)(ws + o); o += (size_t)N;
    int* adj       = (int*)(ws + o); o += (size_t)ET;
    // contiguous zero-init block:
    float* zstart = ws + o;
    int*   deg  = (int*)(ws + o); o += (size_t)N;
    float* sums = ws + o;         o += (size_t)G * 64;
    float* cnts = ws + o;         o += (size_t)G;
    size_t zlen = (size_t)(ws + o - zstart) * sizeof(float);

    hipMemsetAsync(zstart, 0, zlen, stream);

    const int gN32 = (N + 31) / 32;
    const int gE   = (ET + 255) / 256;
    const int gN4  = (N + 3) / 4;

    // CSR build (reused by both GAT layers)
    hist_kernel<<<gE, 256, 0, stream>>>(ei, E, ET, N, deg);
    scan_kernel<<<1, 1024, 0, stream>>>(deg, row_start, cursor, N);
    build_adj<<<gE, 256, 0, stream>>>(ei, E, ET, N, cursor, adj);

    // node_proj: h0 = relu(x @ Wp + bp)
    gemm_tile<128, 64, true><<<gN32, 256, 0, stream>>>(x, Wp, bp, bufA, N);
    // gat1 transform: xh1 = h0 @ W1
    gemm_tile<64, 128, false><<<gN32, 256, 0, stream>>>(bufA, W1, nullptr, bufB, N);
    asad1_kernel<<<(N + 1) / 2, 256, 0, stream>>>(bufB, as1, ad1, as1n, ad1n, N);
    // fused edge softmax + aggregate + bias + elu  -> h1 in bufC
    gat1_fused<<<gN4, 256, 0, stream>>>(row_start, adj, as1n, ad1n, bufB, b1, bufC, N);
    // gat2 transform: xh2 = h1 @ W2 (into bufA; h0 dead)
    gemm_tile<128, 64, false><<<gN32, 256, 0, stream>>>(bufC, W2, nullptr, bufA, N);
    asad2_kernel<<<gN4, 256, 0, stream>>>(bufA, as2, ad2, as2n, ad2n, N);
    // fused edge softmax + aggregate + bias + elu + mean-pool accumulate
    gat2_fused<<<gN4, 256, 0, stream>>>(row_start, adj, as2n, ad2n, bufA, b2,
                                        batch, sums, cnts, N, G);
    // final MLP heads
    mlp_head<<<G, 64, 0, stream>>>(sums, cnts, Wm1, bm1, Wm2, bm2,
                                   Wc, bc, Wr, br, Wv, bv, (float*)d_out, G);
}

// Round 7
// 507.002 us; speedup vs baseline: 2.3595x; 1.0238x over previous
//
#include <hip/hip_runtime.h>
#include <hip/hip_bf16.h>
#include <math.h>

#define F_IN 128
#define GH   64
#define CAP  128   // per-row LDS stash capacity (edges); overflow recomputes

// ---------- helpers ----------
__device__ __forceinline__ void edge_sd(const int* __restrict__ ei, int E, int e, int& s, int& d) {
    if (e < E) { s = ei[e]; d = ei[E + e]; } else { s = d = e - E; }
}
__device__ __forceinline__ float leaky(float x) { return (x >= 0.f) ? x : 0.2f * x; }
__device__ __forceinline__ unsigned short f2bf(float f) {
    unsigned u = __float_as_uint(f);
    u += 0x7FFFu + ((u >> 16) & 1u);
    return (unsigned short)(u >> 16);
}
__device__ __forceinline__ float bflo(unsigned v) { return __uint_as_float(v << 16); }
__device__ __forceinline__ float bfhi(unsigned v) { return __uint_as_float(v & 0xFFFF0000u); }

// ---------- GEMM: act(X@W + b); OM=0 -> fp32 Y, OM=1 -> bf16 Yb ----------
template<int K, int M, bool RELU, int OM>
__global__ __launch_bounds__(256) void gemm_tile(
    const float* __restrict__ X, const float* __restrict__ W,
    const float* __restrict__ B, float* __restrict__ Y,
    unsigned short* __restrict__ Yb, int nrows)
{
    __shared__ float Wl[K * M];
    __shared__ float Xl[32 * K];
    const int t = threadIdx.x;
    for (int i = t; i < K * M / 4; i += 256)
        ((float4*)Wl)[i] = ((const float4*)W)[i];
    const int base = blockIdx.x * 32;
    for (int i = t; i < 32 * K / 4; i += 256) {
        int r = (i * 4) / K;
        int n = base + r;
        float4 v = make_float4(0.f, 0.f, 0.f, 0.f);
        if (n < nrows) v = ((const float4*)(X + (size_t)n * K))[i - r * (K / 4)];
        ((float4*)Xl)[i] = v;
    }
    __syncthreads();
    constexpr int TPC = 256 / M;
    constexpr int RPT = 32 / TPC;
    const int m = t % M;
    const int r0 = (t / M) * RPT;
    float acc[RPT];
#pragma unroll
    for (int i = 0; i < RPT; i++) acc[i] = 0.f;
#pragma unroll 4
    for (int k = 0; k < K; k++) {
        float wv = Wl[k * M + m];
#pragma unroll
        for (int i = 0; i < RPT; i++) acc[i] += Xl[(r0 + i) * K + k] * wv;
    }
    const float bb = B ? B[m] : 0.f;
#pragma unroll
    for (int i = 0; i < RPT; i++) {
        int n = base + r0 + i;
        if (n < nrows) {
            float v = acc[i] + bb;
            if (RELU) v = fmaxf(v, 0.f);
            if (OM == 0) Y[(size_t)n * M + m] = v;
            else         Yb[(size_t)n * M + m] = f2bf(v);
        }
    }
}

// ---------- attention dots from bf16 xh, gat1 (4 heads x 32 ch) ----------
// one wave per node; lane covers ch {2*lane, 2*lane+1}; head = lane>>4
__global__ __launch_bounds__(256) void asad1_kernel(
    const unsigned short* __restrict__ xhb, const float* __restrict__ asw,
    const float* __restrict__ adw, float* __restrict__ as_n, float* __restrict__ ad_n, int N)
{
    const int t = threadIdx.x;
    const int node = blockIdx.x * 4 + (t >> 6);
    const int lane = t & 63;
    if (node >= N) return;
    unsigned u = ((const unsigned*)xhb)[(size_t)node * 64 + lane];
    float x0 = bflo(u), x1 = bfhi(u);
    int c0 = 2 * lane;
    float ps = x0 * asw[c0] + x1 * asw[c0 + 1];
    float pd = x0 * adw[c0] + x1 * adw[c0 + 1];
#pragma unroll
    for (int msk = 8; msk >= 1; msk >>= 1) {
        ps += __shfl_xor(ps, msk);
        pd += __shfl_xor(pd, msk);
    }
    if ((lane & 15) == 0) {
        as_n[node * 4 + (lane >> 4)] = ps;
        ad_n[node * 4 + (lane >> 4)] = pd;
    }
}

// ---------- attention dots, gat2 (1 head x 64 ch), bf16 ----------
// 2 nodes per wave; 32 lanes per node, lane covers 2 ch
__global__ __launch_bounds__(256) void asad2_kernel(
    const unsigned short* __restrict__ xhb, const float* __restrict__ asw,
    const float* __restrict__ adw, float* __restrict__ as_n, float* __restrict__ ad_n, int N)
{
    const int t = threadIdx.x;
    const int node = blockIdx.x * 8 + (t >> 5);
    const int li = t & 31;
    if (node >= N) return;
    unsigned u = ((const unsigned*)xhb)[(size_t)node * 32 + li];
    float x0 = bflo(u), x1 = bfhi(u);
    int c0 = 2 * li;
    float ps = x0 * asw[c0] + x1 * asw[c0 + 1];
    float pd = x0 * adw[c0] + x1 * adw[c0 + 1];
#pragma unroll
    for (int msk = 16; msk >= 1; msk >>= 1) {
        ps += __shfl_xor(ps, msk);
        pd += __shfl_xor(pd, msk);
    }
    if (li == 0) { as_n[node] = ps; ad_n[node] = pd; }
}

// ---------- CSR build ----------
__global__ __launch_bounds__(256) void hist_kernel(
    const int* __restrict__ ei, int E, int ET, int N, int* __restrict__ deg)
{
    int e = blockIdx.x * 256 + threadIdx.x;
    if (e >= ET) return;
    int s, d; edge_sd(ei, E, e, s, d);
    if ((unsigned)s >= (unsigned)N || (unsigned)d >= (unsigned)N) return;
    atomicAdd(&deg[d], 1);
}

__global__ __launch_bounds__(1024) void scan_kernel(
    const int* __restrict__ deg, int* __restrict__ row_start,
    int* __restrict__ cursor, int N)
{
    __shared__ int wsum[16];
    __shared__ int wbase[16];
    __shared__ int ctot;
    __shared__ int carry_s;
    const int t = threadIdx.x, lane = t & 63, w = t >> 6;
    if (t == 0) carry_s = 0;
    __syncthreads();
    for (int base = 0; base < N; base += 1024) {
        int idx = base + t;
        int v = (idx < N) ? deg[idx] : 0;
        int val = v;
#pragma unroll
        for (int off = 1; off < 64; off <<= 1) {
            int n = __shfl_up(val, off);
            if (lane >= off) val += n;
        }
        if (lane == 63) wsum[w] = val;
        __syncthreads();
        if (w == 0 && lane < 16) {
            int s = wsum[lane];
            int sv = s;
#pragma unroll
            for (int off = 1; off < 16; off <<= 1) {
                int n = __shfl_up(sv, off);
                if (lane >= off) sv += n;
            }
            wbase[lane] = sv - s;
            if (lane == 15) ctot = sv;
        }
        __syncthreads();
        int carry = carry_s;
        int excl = carry + wbase[w] + (val - v);
        if (idx < N) { row_start[idx] = excl; cursor[idx] = excl; }
        __syncthreads();
        if (t == 0) carry_s = carry + ctot;
        __syncthreads();
    }
    if (t == 0) row_start[N] = carry_s;
}

__global__ __launch_bounds__(256) void build_adj(
    const int* __restrict__ ei, int E, int ET, int N,
    int* __restrict__ cursor, int* __restrict__ adj)
{
    int e = blockIdx.x * 256 + threadIdx.x;
    if (e >= ET) return;
    int s, d; edge_sd(ei, E, e, s, d);
    if ((unsigned)s >= (unsigned)N || (unsigned)d >= (unsigned)N) return;
    int pos = atomicAdd(&cursor[d], 1);
    adj[pos] = s;
}

// ---------- fused GAT layer 1 (4 heads x 32 ch, concat), bf16 gathers ----------
// One wave per dst. Pass1: logits -> LDS + head max. Pass2: probs + denom.
// Accumulate: 4 quarters of 16 lanes; quarter q takes edges q, q+4, ...;
// each lane loads bf16x8 (16B) = full 128-ch row per quarter.
__global__ __launch_bounds__(256) void gat1_fused(
    const int* __restrict__ row_start, const int* __restrict__ adj,
    const float* __restrict__ as_n, const float* __restrict__ ad_n,
    const unsigned short* __restrict__ xhb, const float* __restrict__ b1,
    float* __restrict__ out, int N)
{
    __shared__ int   s_src[4][CAP];
    __shared__ float s_pl[4][CAP * 4];
    const int w = threadIdx.x >> 6;
    const int d = blockIdx.x * 4 + w;
    if (d >= N) return;
    const int lane = threadIdx.x & 63;
    const int li = lane & 15;
    const int q  = lane >> 4;
    const int beg = row_start[d], end = row_start[d + 1];
    const int deg = end - beg;
    const float4 adv = ((const float4*)ad_n)[d];

    // pass 1: logits -> LDS, per-head max
    float m[4] = {-1e30f, -1e30f, -1e30f, -1e30f};
    for (int j0 = 0; j0 < deg; j0 += 64) {
        int j = j0 + lane;
        if (j < deg) {
            int s = adj[beg + j];
            float4 asv = ((const float4*)as_n)[s];
            float e0 = leaky(asv.x + adv.x);
            float e1 = leaky(asv.y + adv.y);
            float e2 = leaky(asv.z + adv.z);
            float e3 = leaky(asv.w + adv.w);
            m[0] = fmaxf(m[0], e0); m[1] = fmaxf(m[1], e1);
            m[2] = fmaxf(m[2], e2); m[3] = fmaxf(m[3], e3);
            if (j < CAP) {
                s_src[w][j] = s;
                ((float4*)&s_pl[w][j * 4])[0] = make_float4(e0, e1, e2, e3);
            }
        }
    }
#pragma unroll
    for (int msk = 32; msk >= 1; msk >>= 1) {
#pragma unroll
        for (int hh = 0; hh < 4; hh++) m[hh] = fmaxf(m[hh], __shfl_xor(m[hh], msk));
    }
    __threadfence_block();

    // pass 2: probs + denom
    float l[4] = {0.f, 0.f, 0.f, 0.f};
    for (int j0 = 0; j0 < deg; j0 += 64) {
        int j = j0 + lane;
        if (j < deg) {
            float e0, e1, e2, e3;
            if (j < CAP) {
                float4 ev = ((const float4*)&s_pl[w][j * 4])[0];
                e0 = ev.x; e1 = ev.y; e2 = ev.z; e3 = ev.w;
            } else {
                int s = adj[beg + j];
                float4 asv = ((const float4*)as_n)[s];
                e0 = leaky(asv.x + adv.x); e1 = leaky(asv.y + adv.y);
                e2 = leaky(asv.z + adv.z); e3 = leaky(asv.w + adv.w);
            }
            float p0 = __expf(e0 - m[0]), p1 = __expf(e1 - m[1]);
            float p2 = __expf(e2 - m[2]), p3 = __expf(e3 - m[3]);
            l[0] += p0; l[1] += p1; l[2] += p2; l[3] += p3;
            if (j < CAP)
                ((float4*)&s_pl[w][j * 4])[0] = make_float4(p0, p1, p2, p3);
        }
    }
#pragma unroll
    for (int msk = 32; msk >= 1; msk >>= 1) {
#pragma unroll
        for (int hh = 0; hh < 4; hh++) l[hh] += __shfl_xor(l[hh], msk);
    }
    __threadfence_block();

    // accumulate: quarter q -> edges q, q+4, ...; lane holds ch 8*li..8*li+7
    const int h = li >> 2;
    float acc[8] = {0.f, 0.f, 0.f, 0.f, 0.f, 0.f, 0.f, 0.f};
#pragma unroll 4
    for (int j = q; j < deg; j += 4) {
        int s; float a;
        if (j < CAP) {
            s = s_src[w][j];
            a = s_pl[w][j * 4 + h];
        } else {
            s = adj[beg + j];
            float4 asv = ((const float4*)as_n)[s];
            float ah[4] = {leaky(asv.x + adv.x), leaky(asv.y + adv.y),
                           leaky(asv.z + adv.z), leaky(asv.w + adv.w)};
            a = __expf(ah[h] - m[h]);
        }
        uint4 u = ((const uint4*)xhb)[(size_t)s * 16 + li];
        acc[0] += a * bflo(u.x); acc[1] += a * bfhi(u.x);
        acc[2] += a * bflo(u.y); acc[3] += a * bfhi(u.y);
        acc[4] += a * bflo(u.z); acc[5] += a * bfhi(u.z);
        acc[6] += a * bflo(u.w); acc[7] += a * bfhi(u.w);
    }
#pragma unroll
    for (int k = 0; k < 8; k++) {
        acc[k] += __shfl_xor(acc[k], 16);
        acc[k] += __shfl_xor(acc[k], 32);
    }
    if (q == 0) {
        const float inv = 1.0f / (l[h] + 1e-16f);
        float4 b0 = ((const float4*)b1)[2 * li];
        float4 b4 = ((const float4*)b1)[2 * li + 1];
        float v[8];
        v[0] = acc[0] * inv + b0.x; v[1] = acc[1] * inv + b0.y;
        v[2] = acc[2] * inv + b0.z; v[3] = acc[3] * inv + b0.w;
        v[4] = acc[4] * inv + b4.x; v[5] = acc[5] * inv + b4.y;
        v[6] = acc[6] * inv + b4.z; v[7] = acc[7] * inv + b4.w;
#pragma unroll
        for (int k = 0; k < 8; k++) v[k] = (v[k] > 0.f) ? v[k] : expm1f(v[k]);
        ((float4*)out)[(size_t)d * 32 + 2 * li]     = make_float4(v[0], v[1], v[2], v[3]);
        ((float4*)out)[(size_t)d * 32 + 2 * li + 1] = make_float4(v[4], v[5], v[6], v[7]);
    }
}

// ---------- fused GAT layer 2 (1 head, 64 ch) + elu + mean-pool, bf16 gathers ----------
__global__ __launch_bounds__(256) void gat2_fused(
    const int* __restrict__ row_start, const int* __restrict__ adj,
    const float* __restrict__ as_n, const float* __restrict__ ad_n,
    const unsigned short* __restrict__ xhb, const float* __restrict__ b2,
    const int* __restrict__ batch, float* __restrict__ sums, float* __restrict__ cnts,
    int N, int G)
{
    __shared__ int   s_src[4][CAP];
    __shared__ float s_p[4][CAP];
    const int w = threadIdx.x >> 6;
    const int d = blockIdx.x * 4 + w;
    if (d >= N) return;
    const int lane = threadIdx.x & 63;
    const int li = lane & 15;
    const int q  = lane >> 4;
    const int beg = row_start[d], end = row_start[d + 1];
    const int deg = end - beg;
    const float ad = ad_n[d];

    // pass 1: logits -> LDS, max
    float m = -1e30f;
    for (int j0 = 0; j0 < deg; j0 += 64) {
        int j = j0 + lane;
        if (j < deg) {
            int s = adj[beg + j];
            float e = leaky(as_n[s] + ad);
            m = fmaxf(m, e);
            if (j < CAP) { s_src[w][j] = s; s_p[w][j] = e; }
        }
    }
#pragma unroll
    for (int msk = 32; msk >= 1; msk >>= 1) m = fmaxf(m, __shfl_xor(m, msk));
    __threadfence_block();

    // pass 2: probs + denom
    float l = 0.f;
    for (int j0 = 0; j0 < deg; j0 += 64) {
        int j = j0 + lane;
        if (j < deg) {
            float e = (j < CAP) ? s_p[w][j] : leaky(as_n[adj[beg + j]] + ad);
            float p = __expf(e - m);
            l += p;
            if (j < CAP) s_p[w][j] = p;
        }
    }
#pragma unroll
    for (int msk = 32; msk >= 1; msk >>= 1) l += __shfl_xor(l, msk);
    __threadfence_block();

    // accumulate: quarter q -> edges q, q+4, ...; lane holds ch 4*li..4*li+3
    float acc[4] = {0.f, 0.f, 0.f, 0.f};
#pragma unroll 4
    for (int j = q; j < deg; j += 4) {
        int s; float a;
        if (j < CAP) {
            s = s_src[w][j];
            a = s_p[w][j];
        } else {
            s = adj[beg + j];
            a = __expf(leaky(as_n[s] + ad) - m);
        }
        uint2 u = ((const uint2*)xhb)[(size_t)s * 16 + li];
        acc[0] += a * bflo(u.x); acc[1] += a * bfhi(u.x);
        acc[2] += a * bflo(u.y); acc[3] += a * bfhi(u.y);
    }
#pragma unroll
    for (int k = 0; k < 4; k++) {
        acc[k] += __shfl_xor(acc[k], 16);
        acc[k] += __shfl_xor(acc[k], 32);
    }
    if (q == 0) {
        int g = batch[d];
        if ((unsigned)g >= (unsigned)G) return;
        const float inv = 1.0f / (l + 1e-16f);
        float4 bb = ((const float4*)b2)[li];
        float v0 = acc[0] * inv + bb.x;
        float v1 = acc[1] * inv + bb.y;
        float v2 = acc[2] * inv + bb.z;
        float v3 = acc[3] * inv + bb.w;
        v0 = (v0 > 0.f) ? v0 : expm1f(v0);
        v1 = (v1 > 0.f) ? v1 : expm1f(v1);
        v2 = (v2 > 0.f) ? v2 : expm1f(v2);
        v3 = (v3 > 0.f) ? v3 : expm1f(v3);
        atomicAdd(&sums[(size_t)g * 64 + 4 * li],     v0);
        atomicAdd(&sums[(size_t)g * 64 + 4 * li + 1], v1);
        atomicAdd(&sums[(size_t)g * 64 + 4 * li + 2], v2);
        atomicAdd(&sums[(size_t)g * 64 + 4 * li + 3], v3);
        if (li == 0) atomicAdd(&cnts[g], 1.0f);
    }
}

// ---------- final MLP + 3 heads, one wave per graph ----------
__global__ __launch_bounds__(64) void mlp_head(
    const float* __restrict__ sums, const float* __restrict__ cnts,
    const float* __restrict__ Wm1, const float* __restrict__ bm1,
    const float* __restrict__ Wm2, const float* __restrict__ bm2,
    const float* __restrict__ Wc, const float* __restrict__ bc,
    const float* __restrict__ Wr, const float* __restrict__ br,
    const float* __restrict__ Wv, const float* __restrict__ bv,
    float* __restrict__ out, int G)
{
    int g = blockIdx.x;
    int t = threadIdx.x;
    __shared__ float hrow[64];
    __shared__ float zrow[64];
    float hv = sums[(size_t)g * 64 + t] / fmaxf(cnts[g], 1.0f);
    hrow[t] = hv;
    __syncthreads();
    float z1 = bm1[t];
#pragma unroll 8
    for (int k = 0; k < 64; k++) z1 += hrow[k] * Wm1[k * 64 + t];
    z1 = fmaxf(z1, 0.f);
    zrow[t] = z1;
    __syncthreads();
    float z2 = bm2[t];
#pragma unroll 8
    for (int k = 0; k < 64; k++) z2 += zrow[k] * Wm2[k * 64 + t];
    z2 = fmaxf(z2, 0.f);
    float pc = z2 * Wc[t], pr = z2 * Wr[t], pv = z2 * Wv[t];
#pragma unroll
    for (int m = 32; m >= 1; m >>= 1) {
        pc += __shfl_xor(pc, m);
        pr += __shfl_xor(pr, m);
        pv += __shfl_xor(pv, m);
    }
    if (t == 0) {
        out[g] = pc + bc[0];
        out[G + g] = pr + br[0];
        float s = pv + bv[0];
        out[2 * G + g] = (s > 20.f) ? s : log1pf(expf(s));
    }
}

extern "C" void kernel_launch(void* const* d_in, const int* in_sizes, int n_in,
                              void* d_out, int out_size, void* d_ws, size_t ws_size,
                              hipStream_t stream)
{
    const float* x     = (const float*)d_in[0];
    const int*   ei    = (const int*)d_in[1];
    const int*   batch = (const int*)d_in[2];
    const float* Wp  = (const float*)d_in[3];
    const float* bp  = (const float*)d_in[4];
    const float* W1  = (const float*)d_in[5];
    const float* as1 = (const float*)d_in[6];
    const float* ad1 = (const float*)d_in[7];
    const float* b1  = (const float*)d_in[8];
    const float* W2  = (const float*)d_in[9];
    const float* as2 = (const float*)d_in[10];
    const float* ad2 = (const float*)d_in[11];
    const float* b2  = (const float*)d_in[12];
    const float* Wm1 = (const float*)d_in[13];
    const float* bm1 = (const float*)d_in[14];
    const float* Wm2 = (const float*)d_in[15];
    const float* bm2 = (const float*)d_in[16];
    const float* Wc  = (const float*)d_in[17];
    const float* bc  = (const float*)d_in[18];
    const float* Wr  = (const float*)d_in[19];
    const float* br  = (const float*)d_in[20];
    const float* Wv  = (const float*)d_in[21];
    const float* bv  = (const float*)d_in[22];

    const int N  = in_sizes[0] / F_IN;
    const int E  = in_sizes[1] / 2;
    const int G  = out_size / 3;
    const int ET = E + N;

    float* ws = (float*)d_ws;
    size_t o = 0;
    float* bufA = ws + o; o += (size_t)N * 64;    // h0 (fp32)
    float* bufC = ws + o; o += (size_t)N * 128;   // h1 (fp32, gat1 output)
    unsigned short* xhb1 = (unsigned short*)(ws + o); o += (size_t)N * 64;  // xh1 bf16 [N,128]
    unsigned short* xhb2 = (unsigned short*)(ws + o); o += (size_t)N * 32;  // xh2 bf16 [N,64]
    float* as1n = ws + o; o += (size_t)N * 4;
    float* ad1n = ws + o; o += (size_t)N * 4;
    float* as2n = ws + o; o += (size_t)N;
    float* ad2n = ws + o; o += (size_t)N;
    int* row_start = (int*)(ws + o); o += (size_t)N + 1;
    int* cursor    = (int*)(ws + o); o += (size_t)N;
    int* adj       = (int*)(ws + o); o += (size_t)ET;
    // contiguous zero-init block:
    float* zstart = ws + o;
    int*   deg  = (int*)(ws + o); o += (size_t)N;
    float* sums = ws + o;         o += (size_t)G * 64;
    float* cnts = ws + o;         o += (size_t)G;
    size_t zlen = (size_t)(ws + o - zstart) * sizeof(float);

    hipMemsetAsync(zstart, 0, zlen, stream);

    const int gN32 = (N + 31) / 32;
    const int gE   = (ET + 255) / 256;
    const int gN4  = (N + 3) / 4;

    // CSR build (reused by both GAT layers)
    hist_kernel<<<gE, 256, 0, stream>>>(ei, E, ET, N, deg);
    scan_kernel<<<1, 1024, 0, stream>>>(deg, row_start, cursor, N);
    build_adj<<<gE, 256, 0, stream>>>(ei, E, ET, N, cursor, adj);

    // node_proj: h0 = relu(x @ Wp + bp)  (fp32)
    gemm_tile<128, 64, true, 0><<<gN32, 256, 0, stream>>>(x, Wp, bp, bufA, nullptr, N);
    // gat1 transform: xh1 = h0 @ W1  (bf16 mirror only)
    gemm_tile<64, 128, false, 1><<<gN32, 256, 0, stream>>>(bufA, W1, nullptr, nullptr, xhb1, N);
    asad1_kernel<<<gN4, 256, 0, stream>>>(xhb1, as1, ad1, as1n, ad1n, N);
    // fused edge softmax + aggregate + bias + elu -> h1 (fp32) in bufC
    gat1_fused<<<gN4, 256, 0, stream>>>(row_start, adj, as1n, ad1n, xhb1, b1, bufC, N);
    // gat2 transform: xh2 = h1 @ W2  (bf16 mirror only)
    gemm_tile<128, 64, false, 1><<<gN32, 256, 0, stream>>>(bufC, W2, nullptr, nullptr, xhb2, N);
    asad2_kernel<<<(N + 7) / 8, 256, 0, stream>>>(xhb2, as2, ad2, as2n, ad2n, N);
    // fused edge softmax + aggregate + bias + elu + mean-pool accumulate
    gat2_fused<<<gN4, 256, 0, stream>>>(row_start, adj, as2n, ad2n, xhb2, b2,
                                        batch, sums, cnts, N, G);
    // final MLP heads
    mlp_head<<<G, 64, 0, stream>>>(sums, cnts, Wm1, bm1, Wm2, bm2,
                                   Wc, bc, Wr, br, Wv, bv, (float*)d_out, G);
}

// Round 8
// 441.140 us; speedup vs baseline: 2.7117x; 1.1493x over previous
//
#include <hip/hip_runtime.h>
#include <hip/hip_bf16.h>
#include <math.h>

#define F_IN 128
#define GH   64

// ---------- helpers ----------
__device__ __forceinline__ void edge_sd(const int* __restrict__ ei, int E, int e, int& s, int& d) {
    if (e < E) { s = ei[e]; d = ei[E + e]; } else { s = d = e - E; }
}
__device__ __forceinline__ float leaky(float x) { return (x >= 0.f) ? x : 0.2f * x; }
__device__ __forceinline__ unsigned short f2bf(float f) {
    unsigned u = __float_as_uint(f);
    u += 0x7FFFu + ((u >> 16) & 1u);
    return (unsigned short)(u >> 16);
}
__device__ __forceinline__ float bflo(unsigned v) { return __uint_as_float(v << 16); }
__device__ __forceinline__ float bfhi(unsigned v) { return __uint_as_float(v & 0xFFFF0000u); }

// ---------- GEMM: act(X@W + b); OM=0 -> fp32 Y, OM=1 -> bf16 Yb ----------
template<int K, int M, bool RELU, int OM>
__global__ __launch_bounds__(256) void gemm_tile(
    const float* __restrict__ X, const float* __restrict__ W,
    const float* __restrict__ B, float* __restrict__ Y,
    unsigned short* __restrict__ Yb, int nrows)
{
    __shared__ float Wl[K * M];
    __shared__ float Xl[32 * K];
    const int t = threadIdx.x;
    for (int i = t; i < K * M / 4; i += 256)
        ((float4*)Wl)[i] = ((const float4*)W)[i];
    const int base = blockIdx.x * 32;
    for (int i = t; i < 32 * K / 4; i += 256) {
        int r = (i * 4) / K;
        int n = base + r;
        float4 v = make_float4(0.f, 0.f, 0.f, 0.f);
        if (n < nrows) v = ((const float4*)(X + (size_t)n * K))[i - r * (K / 4)];
        ((float4*)Xl)[i] = v;
    }
    __syncthreads();
    constexpr int TPC = 256 / M;
    constexpr int RPT = 32 / TPC;
    const int m = t % M;
    const int r0 = (t / M) * RPT;
    float acc[RPT];
#pragma unroll
    for (int i = 0; i < RPT; i++) acc[i] = 0.f;
#pragma unroll 4
    for (int k = 0; k < K; k++) {
        float wv = Wl[k * M + m];
#pragma unroll
        for (int i = 0; i < RPT; i++) acc[i] += Xl[(r0 + i) * K + k] * wv;
    }
    const float bb = B ? B[m] : 0.f;
#pragma unroll
    for (int i = 0; i < RPT; i++) {
        int n = base + r0 + i;
        if (n < nrows) {
            float v = acc[i] + bb;
            if (RELU) v = fmaxf(v, 0.f);
            if (OM == 0) Y[(size_t)n * M + m] = v;
            else         Yb[(size_t)n * M + m] = f2bf(v);
        }
    }
}

// ---------- attention dots from bf16 xh, gat1 (4 heads x 32 ch) ----------
__global__ __launch_bounds__(256) void asad1_kernel(
    const unsigned short* __restrict__ xhb, const float* __restrict__ asw,
    const float* __restrict__ adw, float* __restrict__ as_n, float* __restrict__ ad_n, int N)
{
    const int t = threadIdx.x;
    const int node = blockIdx.x * 4 + (t >> 6);
    const int lane = t & 63;
    if (node >= N) return;
    unsigned u = ((const unsigned*)xhb)[(size_t)node * 64 + lane];
    float x0 = bflo(u), x1 = bfhi(u);
    int c0 = 2 * lane;
    float ps = x0 * asw[c0] + x1 * asw[c0 + 1];
    float pd = x0 * adw[c0] + x1 * adw[c0 + 1];
#pragma unroll
    for (int msk = 8; msk >= 1; msk >>= 1) {
        ps += __shfl_xor(ps, msk);
        pd += __shfl_xor(pd, msk);
    }
    if ((lane & 15) == 0) {
        as_n[node * 4 + (lane >> 4)] = ps;
        ad_n[node * 4 + (lane >> 4)] = pd;
    }
}

// ---------- attention dots, gat2 (1 head x 64 ch), bf16 ----------
__global__ __launch_bounds__(256) void asad2_kernel(
    const unsigned short* __restrict__ xhb, const float* __restrict__ asw,
    const float* __restrict__ adw, float* __restrict__ as_n, float* __restrict__ ad_n, int N)
{
    const int t = threadIdx.x;
    const int node = blockIdx.x * 8 + (t >> 5);
    const int li = t & 31;
    if (node >= N) return;
    unsigned u = ((const unsigned*)xhb)[(size_t)node * 32 + li];
    float x0 = bflo(u), x1 = bfhi(u);
    int c0 = 2 * li;
    float ps = x0 * asw[c0] + x1 * asw[c0 + 1];
    float pd = x0 * adw[c0] + x1 * adw[c0 + 1];
#pragma unroll
    for (int msk = 16; msk >= 1; msk >>= 1) {
        ps += __shfl_xor(ps, msk);
        pd += __shfl_xor(pd, msk);
    }
    if (li == 0) { as_n[node] = ps; ad_n[node] = pd; }
}

// ---------- CSR build ----------
__global__ __launch_bounds__(256) void hist_kernel(
    const int* __restrict__ ei, int E, int ET, int N, int* __restrict__ deg)
{
    int e = blockIdx.x * 256 + threadIdx.x;
    if (e >= ET) return;
    int s, d; edge_sd(ei, E, e, s, d);
    if ((unsigned)s >= (unsigned)N || (unsigned)d >= (unsigned)N) return;
    atomicAdd(&deg[d], 1);
}

__global__ __launch_bounds__(1024) void scan_kernel(
    const int* __restrict__ deg, int* __restrict__ row_start,
    int* __restrict__ cursor, int N)
{
    __shared__ int wsum[16];
    __shared__ int wbase[16];
    __shared__ int ctot;
    __shared__ int carry_s;
    const int t = threadIdx.x, lane = t & 63, w = t >> 6;
    if (t == 0) carry_s = 0;
    __syncthreads();
    for (int base = 0; base < N; base += 1024) {
        int idx = base + t;
        int v = (idx < N) ? deg[idx] : 0;
        int val = v;
#pragma unroll
        for (int off = 1; off < 64; off <<= 1) {
            int n = __shfl_up(val, off);
            if (lane >= off) val += n;
        }
        if (lane == 63) wsum[w] = val;
        __syncthreads();
        if (w == 0 && lane < 16) {
            int s = wsum[lane];
            int sv = s;
#pragma unroll
            for (int off = 1; off < 16; off <<= 1) {
                int n = __shfl_up(sv, off);
                if (lane >= off) sv += n;
            }
            wbase[lane] = sv - s;
            if (lane == 15) ctot = sv;
        }
        __syncthreads();
        int carry = carry_s;
        int excl = carry + wbase[w] + (val - v);
        if (idx < N) { row_start[idx] = excl; cursor[idx] = excl; }
        __syncthreads();
        if (t == 0) carry_s = carry + ctot;
        __syncthreads();
    }
    if (t == 0) row_start[N] = carry_s;
}

__global__ __launch_bounds__(256) void build_adj(
    const int* __restrict__ ei, int E, int ET, int N,
    int* __restrict__ cursor, int* __restrict__ adj)
{
    int e = blockIdx.x * 256 + threadIdx.x;
    if (e >= ET) return;
    int s, d; edge_sd(ei, E, e, s, d);
    if ((unsigned)s >= (unsigned)N || (unsigned)d >= (unsigned)N) return;
    int pos = atomicAdd(&cursor[d], 1);
    adj[pos] = s;
}

// ---------- fused GAT layer 1: SINGLE-PASS (no max), 4 heads x 32 ch ----------
// One wave per dst. 4 quarters of 16 lanes; quarter q handles edges q, q+4,...
// Per edge: p_h = exp(leaky(as+ad)) computed inline; denom accumulated in the
// same loop (quarters partition edges -> xor-reduce over quarters is exact).
__global__ __launch_bounds__(256) void gat1_fused(
    const int* __restrict__ row_start, const int* __restrict__ adj,
    const float* __restrict__ as_n, const float* __restrict__ ad_n,
    const unsigned short* __restrict__ xhb, const float* __restrict__ b1,
    float* __restrict__ out, int N)
{
    const int w = threadIdx.x >> 6;
    const int d = blockIdx.x * 4 + w;
    if (d >= N) return;
    const int lane = threadIdx.x & 63;
    const int li = lane & 15;
    const int q  = lane >> 4;
    const int beg = row_start[d];
    const int deg = row_start[d + 1] - beg;
    const float4 adv = ((const float4*)ad_n)[d];
    const int h = li >> 2;   // head of channels 8*li..8*li+7

    float acc[8] = {0.f, 0.f, 0.f, 0.f, 0.f, 0.f, 0.f, 0.f};
    float l[4] = {0.f, 0.f, 0.f, 0.f};
#pragma unroll 4
    for (int j = q; j < deg; j += 4) {
        int s = adj[beg + j];
        float4 asv = ((const float4*)as_n)[s];
        float p0 = __expf(leaky(asv.x + adv.x));
        float p1 = __expf(leaky(asv.y + adv.y));
        float p2 = __expf(leaky(asv.z + adv.z));
        float p3 = __expf(leaky(asv.w + adv.w));
        l[0] += p0; l[1] += p1; l[2] += p2; l[3] += p3;
        float a = (h == 0) ? p0 : (h == 1) ? p1 : (h == 2) ? p2 : p3;
        uint4 u = ((const uint4*)xhb)[(size_t)s * 16 + li];
        acc[0] += a * bflo(u.x); acc[1] += a * bfhi(u.x);
        acc[2] += a * bflo(u.y); acc[3] += a * bfhi(u.y);
        acc[4] += a * bflo(u.z); acc[5] += a * bfhi(u.z);
        acc[6] += a * bflo(u.w); acc[7] += a * bfhi(u.w);
    }
    // reduce across the 4 quarters (flip bits 4 and 5)
#pragma unroll
    for (int k = 0; k < 8; k++) {
        acc[k] += __shfl_xor(acc[k], 16);
        acc[k] += __shfl_xor(acc[k], 32);
    }
#pragma unroll
    for (int hh = 0; hh < 4; hh++) {
        l[hh] += __shfl_xor(l[hh], 16);
        l[hh] += __shfl_xor(l[hh], 32);
    }
    if (q == 0) {
        const float inv = 1.0f / (l[h] + 1e-16f);
        float4 b0 = ((const float4*)b1)[2 * li];
        float4 b4 = ((const float4*)b1)[2 * li + 1];
        float v[8];
        v[0] = acc[0] * inv + b0.x; v[1] = acc[1] * inv + b0.y;
        v[2] = acc[2] * inv + b0.z; v[3] = acc[3] * inv + b0.w;
        v[4] = acc[4] * inv + b4.x; v[5] = acc[5] * inv + b4.y;
        v[6] = acc[6] * inv + b4.z; v[7] = acc[7] * inv + b4.w;
#pragma unroll
        for (int k = 0; k < 8; k++) v[k] = (v[k] > 0.f) ? v[k] : expm1f(v[k]);
        ((float4*)out)[(size_t)d * 32 + 2 * li]     = make_float4(v[0], v[1], v[2], v[3]);
        ((float4*)out)[(size_t)d * 32 + 2 * li + 1] = make_float4(v[4], v[5], v[6], v[7]);
    }
}

// ---------- fused GAT layer 2: SINGLE-PASS + elu + mean-pool accumulate ----------
// Same quarter structure. Tail: shuffle-redistribute so lane c owns channel c
// (coalesced atomics), then block-combine the 4 waves when same graph.
__global__ __launch_bounds__(256) void gat2_fused(
    const int* __restrict__ row_start, const int* __restrict__ adj,
    const float* __restrict__ as_n, const float* __restrict__ ad_n,
    const unsigned short* __restrict__ xhb, const float* __restrict__ b2,
    const int* __restrict__ batch, float* __restrict__ sums, float* __restrict__ cnts,
    int N, int G)
{
    __shared__ float pbuf[4][64];
    __shared__ int   pg[4];
    const int w = threadIdx.x >> 6;
    const int d = blockIdx.x * 4 + w;
    const int lane = threadIdx.x & 63;
    const int li = lane & 15;
    const int q  = lane >> 4;
    const bool alive = (d < N);

    int deg = 0, beg = 0;
    float ad = 0.f;
    int g = -1;
    if (alive) {
        beg = row_start[d];
        deg = row_start[d + 1] - beg;
        ad = ad_n[d];
        int gb = batch[d];
        if ((unsigned)gb < (unsigned)G) g = gb;
    }

    float acc[4] = {0.f, 0.f, 0.f, 0.f};
    float l = 0.f;
#pragma unroll 4
    for (int j = q; j < deg; j += 4) {
        int s = adj[beg + j];
        float p = __expf(leaky(as_n[s] + ad));
        l += p;
        uint2 u = ((const uint2*)xhb)[(size_t)s * 16 + li];
        acc[0] += p * bflo(u.x); acc[1] += p * bfhi(u.x);
        acc[2] += p * bflo(u.y); acc[3] += p * bfhi(u.y);
    }
#pragma unroll
    for (int k = 0; k < 4; k++) {
        acc[k] += __shfl_xor(acc[k], 16);
        acc[k] += __shfl_xor(acc[k], 32);
    }
    l += __shfl_xor(l, 16);
    l += __shfl_xor(l, 32);

    // all lanes: finalize 4 channels (4*li..4*li+3)
    const float inv = 1.0f / (l + 1e-16f);
    float4 bb = ((const float4*)b2)[li];
    float v[4];
    v[0] = acc[0] * inv + bb.x;
    v[1] = acc[1] * inv + bb.y;
    v[2] = acc[2] * inv + bb.z;
    v[3] = acc[3] * inv + bb.w;
#pragma unroll
    for (int k = 0; k < 4; k++) v[k] = (v[k] > 0.f) ? v[k] : expm1f(v[k]);

    // redistribute: lane c takes component (c&3) from lane (c>>2)
    int src = lane >> 2;
    float w0 = __shfl(v[0], src), w1 = __shfl(v[1], src);
    float w2 = __shfl(v[2], src), w3 = __shfl(v[3], src);
    int sel = lane & 3;
    float val = (sel == 0) ? w0 : (sel == 1) ? w1 : (sel == 2) ? w2 : w3;

    if (lane == 0) pg[w] = g;
    pbuf[w][lane] = (g >= 0) ? val : 0.f;
    __syncthreads();
    int g0 = pg[0], g1 = pg[1], g2 = pg[2], g3 = pg[3];
    bool uni = (g0 >= 0) && (g1 == g0) && (g2 == g0) && (g3 == g0);
    if (uni) {
        if (w == 0) {
            float s4 = pbuf[0][lane] + pbuf[1][lane] + pbuf[2][lane] + pbuf[3][lane];
            atomicAdd(&sums[(size_t)g0 * 64 + lane], s4);
            if (lane == 0) atomicAdd(&cnts[g0], 4.0f);
        }
    } else if (g >= 0) {
        atomicAdd(&sums[(size_t)g * 64 + lane], val);
        if (lane == 0) atomicAdd(&cnts[g], 1.0f);
    }
}

// ---------- final MLP + 3 heads, one wave per graph ----------
__global__ __launch_bounds__(64) void mlp_head(
    const float* __restrict__ sums, const float* __restrict__ cnts,
    const float* __restrict__ Wm1, const float* __restrict__ bm1,
    const float* __restrict__ Wm2, const float* __restrict__ bm2,
    const float* __restrict__ Wc, const float* __restrict__ bc,
    const float* __restrict__ Wr, const float* __restrict__ br,
    const float* __restrict__ Wv, const float* __restrict__ bv,
    float* __restrict__ out, int G)
{
    int g = blockIdx.x;
    int t = threadIdx.x;
    __shared__ float hrow[64];
    __shared__ float zrow[64];
    float hv = sums[(size_t)g * 64 + t] / fmaxf(cnts[g], 1.0f);
    hrow[t] = hv;
    __syncthreads();
    float z1 = bm1[t];
#pragma unroll 8
    for (int k = 0; k < 64; k++) z1 += hrow[k] * Wm1[k * 64 + t];
    z1 = fmaxf(z1, 0.f);
    zrow[t] = z1;
    __syncthreads();
    float z2 = bm2[t];
#pragma unroll 8
    for (int k = 0; k < 64; k++) z2 += zrow[k] * Wm2[k * 64 + t];
    z2 = fmaxf(z2, 0.f);
    float pc = z2 * Wc[t], pr = z2 * Wr[t], pv = z2 * Wv[t];
#pragma unroll
    for (int m = 32; m >= 1; m >>= 1) {
        pc += __shfl_xor(pc, m);
        pr += __shfl_xor(pr, m);
        pv += __shfl_xor(pv, m);
    }
    if (t == 0) {
        out[g] = pc + bc[0];
        out[G + g] = pr + br[0];
        float s = pv + bv[0];
        out[2 * G + g] = (s > 20.f) ? s : log1pf(expf(s));
    }
}

extern "C" void kernel_launch(void* const* d_in, const int* in_sizes, int n_in,
                              void* d_out, int out_size, void* d_ws, size_t ws_size,
                              hipStream_t stream)
{
    const float* x     = (const float*)d_in[0];
    const int*   ei    = (const int*)d_in[1];
    const int*   batch = (const int*)d_in[2];
    const float* Wp  = (const float*)d_in[3];
    const float* bp  = (const float*)d_in[4];
    const float* W1  = (const float*)d_in[5];
    const float* as1 = (const float*)d_in[6];
    const float* ad1 = (const float*)d_in[7];
    const float* b1  = (const float*)d_in[8];
    const float* W2  = (const float*)d_in[9];
    const float* as2 = (const float*)d_in[10];
    const float* ad2 = (const float*)d_in[11];
    const float* b2  = (const float*)d_in[12];
    const float* Wm1 = (const float*)d_in[13];
    const float* bm1 = (const float*)d_in[14];
    const float* Wm2 = (const float*)d_in[15];
    const float* bm2 = (const float*)d_in[16];
    const float* Wc  = (const float*)d_in[17];
    const float* bc  = (const float*)d_in[18];
    const float* Wr  = (const float*)d_in[19];
    const float* br  = (const float*)d_in[20];
    const float* Wv  = (const float*)d_in[21];
    const float* bv  = (const float*)d_in[22];

    const int N  = in_sizes[0] / F_IN;
    const int E  = in_sizes[1] / 2;
    const int G  = out_size / 3;
    const int ET = E + N;

    float* ws = (float*)d_ws;
    size_t o = 0;
    float* bufA = ws + o; o += (size_t)N * 64;    // h0 (fp32)
    float* bufC = ws + o; o += (size_t)N * 128;   // h1 (fp32, gat1 output)
    unsigned short* xhb1 = (unsigned short*)(ws + o); o += (size_t)N * 64;  // xh1 bf16 [N,128]
    unsigned short* xhb2 = (unsigned short*)(ws + o); o += (size_t)N * 32;  // xh2 bf16 [N,64]
    float* as1n = ws + o; o += (size_t)N * 4;
    float* ad1n = ws + o; o += (size_t)N * 4;
    float* as2n = ws + o; o += (size_t)N;
    float* ad2n = ws + o; o += (size_t)N;
    int* row_start = (int*)(ws + o); o += (size_t)N + 1;
    int* cursor    = (int*)(ws + o); o += (size_t)N;
    int* adj       = (int*)(ws + o); o += (size_t)ET;
    // contiguous zero-init block:
    float* zstart = ws + o;
    int*   deg  = (int*)(ws + o); o += (size_t)N;
    float* sums = ws + o;         o += (size_t)G * 64;
    float* cnts = ws + o;         o += (size_t)G;
    size_t zlen = (size_t)(ws + o - zstart) * sizeof(float);

    hipMemsetAsync(zstart, 0, zlen, stream);

    const int gN32 = (N + 31) / 32;
    const int gE   = (ET + 255) / 256;
    const int gN4  = (N + 3) / 4;

    // CSR build (reused by both GAT layers)
    hist_kernel<<<gE, 256, 0, stream>>>(ei, E, ET, N, deg);
    scan_kernel<<<1, 1024, 0, stream>>>(deg, row_start, cursor, N);
    build_adj<<<gE, 256, 0, stream>>>(ei, E, ET, N, cursor, adj);

    // node_proj: h0 = relu(x @ Wp + bp)  (fp32)
    gemm_tile<128, 64, true, 0><<<gN32, 256, 0, stream>>>(x, Wp, bp, bufA, nullptr, N);
    // gat1 transform: xh1 = h0 @ W1  (bf16 mirror only)
    gemm_tile<64, 128, false, 1><<<gN32, 256, 0, stream>>>(bufA, W1, nullptr, nullptr, xhb1, N);
    asad1_kernel<<<gN4, 256, 0, stream>>>(xhb1, as1, ad1, as1n, ad1n, N);
    // fused single-pass edge softmax + aggregate + bias + elu -> h1 (fp32)
    gat1_fused<<<gN4, 256, 0, stream>>>(row_start, adj, as1n, ad1n, xhb1, b1, bufC, N);
    // gat2 transform: xh2 = h1 @ W2  (bf16 mirror only)
    gemm_tile<128, 64, false, 1><<<gN32, 256, 0, stream>>>(bufC, W2, nullptr, nullptr, xhb2, N);
    asad2_kernel<<<(N + 7) / 8, 256, 0, stream>>>(xhb2, as2, ad2, as2n, ad2n, N);
    // fused single-pass edge softmax + aggregate + bias + elu + mean-pool
    gat2_fused<<<gN4, 256, 0, stream>>>(row_start, adj, as2n, ad2n, xhb2, b2,
                                        batch, sums, cnts, N, G);
    // final MLP heads
    mlp_head<<<G, 64, 0, stream>>>(sums, cnts, Wm1, bm1, Wm2, bm2,
                                   Wc, bc, Wr, br, Wv, bv, (float*)d_out, G);
}

// Round 9
// 369.357 us; speedup vs baseline: 3.2387x; 1.1943x over previous
//
#include <hip/hip_runtime.h>
#include <hip/hip_bf16.h>
#include <math.h>

#define F_IN 128
#define GH   64

// ---------- helpers ----------
__device__ __forceinline__ void edge_sd(const int* __restrict__ ei, int E, int e, int& s, int& d) {
    if (e < E) { s = ei[e]; d = ei[E + e]; } else { s = d = e - E; }
}
__device__ __forceinline__ float leaky(float x) { return (x >= 0.f) ? x : 0.2f * x; }
__device__ __forceinline__ unsigned short f2bf(float f) {
    unsigned u = __float_as_uint(f);
    u += 0x7FFFu + ((u >> 16) & 1u);
    return (unsigned short)(u >> 16);
}
__device__ __forceinline__ float bflo(unsigned v) { return __uint_as_float(v << 16); }
__device__ __forceinline__ float bfhi(unsigned v) { return __uint_as_float(v & 0xFFFF0000u); }

// ---------- GEMM: act(X@W + b); OM=0 -> fp32 Y, OM=1 -> bf16 Yb ----------
template<int K, int M, bool RELU, int OM>
__global__ __launch_bounds__(256) void gemm_tile(
    const float* __restrict__ X, const float* __restrict__ W,
    const float* __restrict__ B, float* __restrict__ Y,
    unsigned short* __restrict__ Yb, int nrows)
{
    __shared__ float Wl[K * M];
    __shared__ float Xl[32 * K];
    const int t = threadIdx.x;
    for (int i = t; i < K * M / 4; i += 256)
        ((float4*)Wl)[i] = ((const float4*)W)[i];
    const int base = blockIdx.x * 32;
    for (int i = t; i < 32 * K / 4; i += 256) {
        int r = (i * 4) / K;
        int n = base + r;
        float4 v = make_float4(0.f, 0.f, 0.f, 0.f);
        if (n < nrows) v = ((const float4*)(X + (size_t)n * K))[i - r * (K / 4)];
        ((float4*)Xl)[i] = v;
    }
    __syncthreads();
    constexpr int TPC = 256 / M;
    constexpr int RPT = 32 / TPC;
    const int m = t % M;
    const int r0 = (t / M) * RPT;
    float acc[RPT];
#pragma unroll
    for (int i = 0; i < RPT; i++) acc[i] = 0.f;
#pragma unroll 4
    for (int k = 0; k < K; k++) {
        float wv = Wl[k * M + m];
#pragma unroll
        for (int i = 0; i < RPT; i++) acc[i] += Xl[(r0 + i) * K + k] * wv;
    }
    const float bb = B ? B[m] : 0.f;
#pragma unroll
    for (int i = 0; i < RPT; i++) {
        int n = base + r0 + i;
        if (n < nrows) {
            float v = acc[i] + bb;
            if (RELU) v = fmaxf(v, 0.f);
            if (OM == 0) Y[(size_t)n * M + m] = v;
            else         Yb[(size_t)n * M + m] = f2bf(v);
        }
    }
}

// ---------- attention dots from bf16 xh, gat1 (4 heads x 32 ch) ----------
__global__ __launch_bounds__(256) void asad1_kernel(
    const unsigned short* __restrict__ xhb, const float* __restrict__ asw,
    const float* __restrict__ adw, float* __restrict__ as_n, float* __restrict__ ad_n, int N)
{
    const int t = threadIdx.x;
    const int node = blockIdx.x * 4 + (t >> 6);
    const int lane = t & 63;
    if (node >= N) return;
    unsigned u = ((const unsigned*)xhb)[(size_t)node * 64 + lane];
    float x0 = bflo(u), x1 = bfhi(u);
    int c0 = 2 * lane;
    float ps = x0 * asw[c0] + x1 * asw[c0 + 1];
    float pd = x0 * adw[c0] + x1 * adw[c0 + 1];
#pragma unroll
    for (int msk = 8; msk >= 1; msk >>= 1) {
        ps += __shfl_xor(ps, msk);
        pd += __shfl_xor(pd, msk);
    }
    if ((lane & 15) == 0) {
        as_n[node * 4 + (lane >> 4)] = ps;
        ad_n[node * 4 + (lane >> 4)] = pd;
    }
}

// ---------- attention dots, gat2 (1 head x 64 ch), bf16 ----------
__global__ __launch_bounds__(256) void asad2_kernel(
    const unsigned short* __restrict__ xhb, const float* __restrict__ asw,
    const float* __restrict__ adw, float* __restrict__ as_n, float* __restrict__ ad_n, int N)
{
    const int t = threadIdx.x;
    const int node = blockIdx.x * 8 + (t >> 5);
    const int li = t & 31;
    if (node >= N) return;
    unsigned u = ((const unsigned*)xhb)[(size_t)node * 32 + li];
    float x0 = bflo(u), x1 = bfhi(u);
    int c0 = 2 * li;
    float ps = x0 * asw[c0] + x1 * asw[c0 + 1];
    float pd = x0 * adw[c0] + x1 * adw[c0 + 1];
#pragma unroll
    for (int msk = 16; msk >= 1; msk >>= 1) {
        ps += __shfl_xor(ps, msk);
        pd += __shfl_xor(pd, msk);
    }
    if (li == 0) { as_n[node] = ps; ad_n[node] = pd; }
}

// ---------- bucketed CSR build ----------
// bucket b = dst >> 8 (256 dst values per bucket; requires N <= 65536)

// K1: bucket histogram via LDS
__global__ __launch_bounds__(256) void bucket_hist(
    const int* __restrict__ ei, int E, int ET, int N, int* __restrict__ bcnt)
{
    __shared__ int h[256];
    h[threadIdx.x] = 0;
    __syncthreads();
    for (int e = blockIdx.x * 256 + threadIdx.x; e < ET; e += gridDim.x * 256) {
        int s, d; edge_sd(ei, E, e, s, d);
        if ((unsigned)s < (unsigned)N && (unsigned)d < (unsigned)N)
            atomicAdd(&h[d >> 8], 1);
    }
    __syncthreads();
    if (h[threadIdx.x]) atomicAdd(&bcnt[threadIdx.x], h[threadIdx.x]);
}

// K2: scan bucket counts -> bbase/bcur; also row_start[N] = total
__global__ __launch_bounds__(256) void bucket_scan(
    const int* __restrict__ bcnt, int* __restrict__ bbase, int* __restrict__ bcur,
    int* __restrict__ row_start, int B, int N)
{
    __shared__ int wsum[4];
    int t = threadIdx.x, lane = t & 63, w = t >> 6;
    int v = (t < B) ? bcnt[t] : 0;
    int incl = v;
#pragma unroll
    for (int off = 1; off < 64; off <<= 1) {
        int n = __shfl_up(incl, off);
        if (lane >= off) incl += n;
    }
    if (lane == 63) wsum[w] = incl;
    __syncthreads();
    int wb = 0;
#pragma unroll
    for (int i = 0; i < 4; i++) if (i < w) wb += wsum[i];
    int excl = wb + incl - v;
    if (t < B) { bbase[t] = excl; bcur[t] = excl; }
    if (t == 255) { bbase[B] = excl + v; row_start[N] = excl + v; }
}

// K3: stage (s,d) into bucket-contiguous regions (per-block reservation),
//     fused per-node degree histogram.
#define SCHUNK 4096
__global__ __launch_bounds__(256) void bucket_scatter(
    const int* __restrict__ ei, int E, int ET, int N,
    int* __restrict__ bcur, int* __restrict__ deg, uint2* __restrict__ staged)
{
    __shared__ int bc[256];
    __shared__ int bb[256];
    const int t = threadIdx.x;
    const int base = blockIdx.x * SCHUNK;
    bc[t] = 0;
    __syncthreads();
    const int cnt = min(SCHUNK, ET - base);
    int ss[16], dd[16], lr[16];
#pragma unroll
    for (int k = 0; k < 16; k++) {
        int i = t + k * 256;
        ss[k] = -1; dd[k] = 0; lr[k] = 0;
        if (i < cnt) {
            int s, d; edge_sd(ei, E, base + i, s, d);
            if ((unsigned)s < (unsigned)N && (unsigned)d < (unsigned)N) {
                ss[k] = s; dd[k] = d;
                lr[k] = atomicAdd(&bc[d >> 8], 1);
                atomicAdd(&deg[d], 1);
            }
        }
    }
    __syncthreads();
    bb[t] = bc[t] ? atomicAdd(&bcur[t], bc[t]) : 0;
    __syncthreads();
#pragma unroll
    for (int k = 0; k < 16; k++) {
        if (ss[k] >= 0)
            staged[bb[dd[k] >> 8] + lr[k]] = make_uint2((unsigned)ss[k], (unsigned)dd[k]);
    }
}

// K4: per-bucket block scan of deg -> row_start
__global__ __launch_bounds__(256) void row_scan(
    const int* __restrict__ deg, const int* __restrict__ bbase,
    int* __restrict__ row_start, int N)
{
    __shared__ int wsum[4];
    const int b = blockIdx.x, t = threadIdx.x;
    const int lane = t & 63, w = t >> 6;
    const int node = b * 256 + t;
    int v = (node < N) ? deg[node] : 0;
    int incl = v;
#pragma unroll
    for (int off = 1; off < 64; off <<= 1) {
        int n = __shfl_up(incl, off);
        if (lane >= off) incl += n;
    }
    if (lane == 63) wsum[w] = incl;
    __syncthreads();
    int wb = 0;
#pragma unroll
    for (int i = 0; i < 4; i++) if (i < w) wb += wsum[i];
    if (node < N) row_start[node] = bbase[b] + wb + incl - v;
}

// K5: per-bucket localized scatter with LDS cursors
__global__ __launch_bounds__(256) void bucket_final(
    const uint2* __restrict__ staged, const int* __restrict__ bbase,
    const int* __restrict__ row_start, int* __restrict__ adj, int N)
{
    __shared__ int cur[256];
    const int b = blockIdx.x, t = threadIdx.x;
    const int node = b * 256 + t;
    cur[t] = (node < N) ? row_start[node] : 0;
    __syncthreads();
    const int beg = bbase[b], end = bbase[b + 1];
    for (int i = beg + t; i < end; i += 256) {
        uint2 sd = staged[i];
        int pos = atomicAdd(&cur[sd.y & 255], 1);
        adj[pos] = (int)sd.x;
    }
}

// ---------- fused GAT layer 1: LDS-staged single-pass (4 heads x 32 ch) ----------
// One wave per dst. Phase A: 64 edges in parallel, exp once per edge/head,
// stash (byte-offset, p[4]) in wave-private LDS. Phase B: each lane owns
// channels {2*lane, 2*lane+1}, lean accumulate over the chunk.
__global__ __launch_bounds__(256) void gat1_fused(
    const int* __restrict__ row_start, const int* __restrict__ adj,
    const float* __restrict__ as_n, const float* __restrict__ ad_n,
    const unsigned short* __restrict__ xhb, const float* __restrict__ b1,
    float* __restrict__ out, int N)
{
    __shared__ unsigned s_ofs[4][64];
    __shared__ float    s_p[4][256];
    const int w = threadIdx.x >> 6;
    const int d = blockIdx.x * 4 + w;
    if (d >= N) return;
    const int lane = threadIdx.x & 63;
    const int h = lane >> 4;                 // head of ch {2*lane, 2*lane+1}
    const int beg = row_start[d];
    const int deg = row_start[d + 1] - beg;
    const float4 adv = ((const float4*)ad_n)[d];
    const char* xbase = (const char*)xhb;

    float l0 = 0.f, l1 = 0.f, l2 = 0.f, l3 = 0.f;
    float acc0 = 0.f, acc1 = 0.f;
    for (int j0 = 0; j0 < deg; j0 += 64) {
        const int chunk = min(64, deg - j0);
        if (lane < chunk) {
            int s = adj[beg + j0 + lane];
            float4 asv = ((const float4*)as_n)[s];
            float p0 = __expf(leaky(asv.x + adv.x));
            float p1 = __expf(leaky(asv.y + adv.y));
            float p2 = __expf(leaky(asv.z + adv.z));
            float p3 = __expf(leaky(asv.w + adv.w));
            l0 += p0; l1 += p1; l2 += p2; l3 += p3;
            s_ofs[w][lane] = (unsigned)s << 8;          // s * 256 bytes
            ((float4*)&s_p[w][lane * 4])[0] = make_float4(p0, p1, p2, p3);
        }
        __threadfence_block();
#pragma unroll 4
        for (int jj = 0; jj < chunk; jj++) {
            float a = s_p[w][jj * 4 + h];
            unsigned ofs = s_ofs[w][jj] + ((unsigned)lane << 2);
            unsigned u = *(const unsigned*)(xbase + ofs);
            acc0 += a * bflo(u);
            acc1 += a * bfhi(u);
        }
        __threadfence_block();
    }
#pragma unroll
    for (int msk = 32; msk >= 1; msk >>= 1) {
        l0 += __shfl_xor(l0, msk); l1 += __shfl_xor(l1, msk);
        l2 += __shfl_xor(l2, msk); l3 += __shfl_xor(l3, msk);
    }
    float lh = (h == 0) ? l0 : (h == 1) ? l1 : (h == 2) ? l2 : l3;
    const float inv = 1.0f / (lh + 1e-16f);
    float2 bb = ((const float2*)b1)[lane];
    float v0 = acc0 * inv + bb.x;
    float v1 = acc1 * inv + bb.y;
    v0 = (v0 > 0.f) ? v0 : expm1f(v0);
    v1 = (v1 > 0.f) ? v1 : expm1f(v1);
    ((float2*)out)[(size_t)d * 64 + lane] = make_float2(v0, v1);
}

// ---------- fused GAT layer 2: LDS-staged single-pass + elu + mean-pool ----------
__global__ __launch_bounds__(256) void gat2_fused(
    const int* __restrict__ row_start, const int* __restrict__ adj,
    const float* __restrict__ as_n, const float* __restrict__ ad_n,
    const unsigned short* __restrict__ xhb, const float* __restrict__ b2,
    const int* __restrict__ batch, float* __restrict__ sums, float* __restrict__ cnts,
    int N, int G)
{
    __shared__ unsigned s_ofs[4][64];
    __shared__ float    s_p[4][64];
    __shared__ float    pbuf[4][64];
    __shared__ int      pg[4];
    const int w = threadIdx.x >> 6;
    const int d = blockIdx.x * 4 + w;
    const int lane = threadIdx.x & 63;
    const bool alive = (d < N);
    int beg = 0, deg = 0; float ad = 0.f; int g = -1;
    if (alive) {
        beg = row_start[d];
        deg = row_start[d + 1] - beg;
        ad = ad_n[d];
        int gb = batch[d];
        if ((unsigned)gb < (unsigned)G) g = gb;
    }
    const char* xbase = (const char*)xhb;
    float l = 0.f, acc = 0.f;
    for (int j0 = 0; j0 < deg; j0 += 64) {
        const int chunk = min(64, deg - j0);
        if (lane < chunk) {
            int s = adj[beg + j0 + lane];
            float p = __expf(leaky(as_n[s] + ad));
            l += p;
            s_ofs[w][lane] = (unsigned)s << 7;          // s * 128 bytes
            s_p[w][lane] = p;
        }
        __threadfence_block();
#pragma unroll 4
        for (int jj = 0; jj < chunk; jj++) {
            float a = s_p[w][jj];
            unsigned ofs = s_ofs[w][jj] + ((unsigned)lane << 1);
            unsigned short uv = *(const unsigned short*)(xbase + ofs);
            acc += a * __uint_as_float((unsigned)uv << 16);
        }
        __threadfence_block();
    }
#pragma unroll
    for (int msk = 32; msk >= 1; msk >>= 1) l += __shfl_xor(l, msk);
    float v = acc / (l + 1e-16f) + b2[lane];
    v = (v > 0.f) ? v : expm1f(v);

    if (lane == 0) pg[w] = g;
    pbuf[w][lane] = (g >= 0) ? v : 0.f;
    __syncthreads();
    int g0 = pg[0], g1 = pg[1], g2 = pg[2], g3 = pg[3];
    bool uni = (g0 >= 0) && (g1 == g0) && (g2 == g0) && (g3 == g0);
    if (uni) {
        if (w == 0) {
            float s4 = pbuf[0][lane] + pbuf[1][lane] + pbuf[2][lane] + pbuf[3][lane];
            atomicAdd(&sums[(size_t)g0 * 64 + lane], s4);
            if (lane == 0) atomicAdd(&cnts[g0], 4.0f);
        }
    } else if (g >= 0) {
        atomicAdd(&sums[(size_t)g * 64 + lane], v);
        if (lane == 0) atomicAdd(&cnts[g], 1.0f);
    }
}

// ---------- final MLP + 3 heads, one wave per graph ----------
__global__ __launch_bounds__(64) void mlp_head(
    const float* __restrict__ sums, const float* __restrict__ cnts,
    const float* __restrict__ Wm1, const float* __restrict__ bm1,
    const float* __restrict__ Wm2, const float* __restrict__ bm2,
    const float* __restrict__ Wc, const float* __restrict__ bc,
    const float* __restrict__ Wr, const float* __restrict__ br,
    const float* __restrict__ Wv, const float* __restrict__ bv,
    float* __restrict__ out, int G)
{
    int g = blockIdx.x;
    int t = threadIdx.x;
    __shared__ float hrow[64];
    __shared__ float zrow[64];
    float hv = sums[(size_t)g * 64 + t] / fmaxf(cnts[g], 1.0f);
    hrow[t] = hv;
    __syncthreads();
    float z1 = bm1[t];
#pragma unroll 8
    for (int k = 0; k < 64; k++) z1 += hrow[k] * Wm1[k * 64 + t];
    z1 = fmaxf(z1, 0.f);
    zrow[t] = z1;
    __syncthreads();
    float z2 = bm2[t];
#pragma unroll 8
    for (int k = 0; k < 64; k++) z2 += zrow[k] * Wm2[k * 64 + t];
    z2 = fmaxf(z2, 0.f);
    float pc = z2 * Wc[t], pr = z2 * Wr[t], pv = z2 * Wv[t];
#pragma unroll
    for (int m = 32; m >= 1; m >>= 1) {
        pc += __shfl_xor(pc, m);
        pr += __shfl_xor(pr, m);
        pv += __shfl_xor(pv, m);
    }
    if (t == 0) {
        out[g] = pc + bc[0];
        out[G + g] = pr + br[0];
        float s = pv + bv[0];
        out[2 * G + g] = (s > 20.f) ? s : log1pf(expf(s));
    }
}

extern "C" void kernel_launch(void* const* d_in, const int* in_sizes, int n_in,
                              void* d_out, int out_size, void* d_ws, size_t ws_size,
                              hipStream_t stream)
{
    const float* x     = (const float*)d_in[0];
    const int*   ei    = (const int*)d_in[1];
    const int*   batch = (const int*)d_in[2];
    const float* Wp  = (const float*)d_in[3];
    const float* bp  = (const float*)d_in[4];
    const float* W1  = (const float*)d_in[5];
    const float* as1 = (const float*)d_in[6];
    const float* ad1 = (const float*)d_in[7];
    const float* b1  = (const float*)d_in[8];
    const float* W2  = (const float*)d_in[9];
    const float* as2 = (const float*)d_in[10];
    const float* ad2 = (const float*)d_in[11];
    const float* b2  = (const float*)d_in[12];
    const float* Wm1 = (const float*)d_in[13];
    const float* bm1 = (const float*)d_in[14];
    const float* Wm2 = (const float*)d_in[15];
    const float* bm2 = (const float*)d_in[16];
    const float* Wc  = (const float*)d_in[17];
    const float* bc  = (const float*)d_in[18];
    const float* Wr  = (const float*)d_in[19];
    const float* br  = (const float*)d_in[20];
    const float* Wv  = (const float*)d_in[21];
    const float* bv  = (const float*)d_in[22];

    const int N  = in_sizes[0] / F_IN;
    const int E  = in_sizes[1] / 2;
    const int G  = out_size / 3;
    const int ET = E + N;
    const int B  = (N + 255) >> 8;   // dst buckets of 256 nodes (N <= 65536)

    float* ws = (float*)d_ws;
    size_t o = 0;
    float* bufA = ws + o; o += (size_t)N * 64;    // h0 (fp32)
    float* bufC = ws + o; o += (size_t)N * 128;   // h1 (fp32, gat1 output)
    unsigned short* xhb1 = (unsigned short*)(ws + o); o += (size_t)N * 64;  // xh1 bf16 [N,128]
    unsigned short* xhb2 = (unsigned short*)(ws + o); o += (size_t)N * 32;  // xh2 bf16 [N,64]
    float* as1n = ws + o; o += (size_t)N * 4;
    float* ad1n = ws + o; o += (size_t)N * 4;
    float* as2n = ws + o; o += (size_t)N;
    float* ad2n = ws + o; o += (size_t)N;
    int* row_start = (int*)(ws + o); o += (size_t)N + 1;
    int* adj       = (int*)(ws + o); o += (size_t)ET;
    int* bbase     = (int*)(ws + o); o += 257;
    int* bcur      = (int*)(ws + o); o += 256;
    uint2* staged  = (uint2*)(ws + o); o += (size_t)ET * 2;
    // contiguous zero-init block:
    float* zstart = ws + o;
    int*   deg  = (int*)(ws + o); o += (size_t)N;
    int*   bcnt = (int*)(ws + o); o += 256;
    float* sums = ws + o;         o += (size_t)G * 64;
    float* cnts = ws + o;         o += (size_t)G;
    size_t zlen = (size_t)(ws + o - zstart) * sizeof(float);

    hipMemsetAsync(zstart, 0, zlen, stream);

    const int gN32 = (N + 31) / 32;
    const int gN4  = (N + 3) / 4;
    const int gSC  = (ET + SCHUNK - 1) / SCHUNK;

    // bucketed CSR build
    bucket_hist<<<512, 256, 0, stream>>>(ei, E, ET, N, bcnt);
    bucket_scan<<<1, 256, 0, stream>>>(bcnt, bbase, bcur, row_start, B, N);
    bucket_scatter<<<gSC, 256, 0, stream>>>(ei, E, ET, N, bcur, deg, staged);
    row_scan<<<B, 256, 0, stream>>>(deg, bbase, row_start, N);
    bucket_final<<<B, 256, 0, stream>>>(staged, bbase, row_start, adj, N);

    // node_proj: h0 = relu(x @ Wp + bp)  (fp32)
    gemm_tile<128, 64, true, 0><<<gN32, 256, 0, stream>>>(x, Wp, bp, bufA, nullptr, N);
    // gat1 transform: xh1 = h0 @ W1  (bf16 mirror only)
    gemm_tile<64, 128, false, 1><<<gN32, 256, 0, stream>>>(bufA, W1, nullptr, nullptr, xhb1, N);
    asad1_kernel<<<gN4, 256, 0, stream>>>(xhb1, as1, ad1, as1n, ad1n, N);
    // fused single-pass edge softmax + aggregate + bias + elu -> h1 (fp32)
    gat1_fused<<<gN4, 256, 0, stream>>>(row_start, adj, as1n, ad1n, xhb1, b1, bufC, N);
    // gat2 transform: xh2 = h1 @ W2  (bf16 mirror only)
    gemm_tile<128, 64, false, 1><<<gN32, 256, 0, stream>>>(bufC, W2, nullptr, nullptr, xhb2, N);
    asad2_kernel<<<(N + 7) / 8, 256, 0, stream>>>(xhb2, as2, ad2, as2n, ad2n, N);
    // fused single-pass edge softmax + aggregate + bias + elu + mean-pool
    gat2_fused<<<gN4, 256, 0, stream>>>(row_start, adj, as2n, ad2n, xhb2, b2,
                                        batch, sums, cnts, N, G);
    // final MLP heads
    mlp_head<<<G, 64, 0, stream>>>(sums, cnts, Wm1, bm1, Wm2, bm2,
                                   Wc, bc, Wr, br, Wv, bv, (float*)d_out, G);
}

// Round 11
// 331.631 us; speedup vs baseline: 3.6072x; 1.1138x over previous
//
#include <hip/hip_runtime.h>
#include <hip/hip_bf16.h>
#include <math.h>

#define F_IN 128
#define GH   64

typedef __attribute__((ext_vector_type(8))) short bf16x8;
typedef __attribute__((ext_vector_type(4))) float f32x4;

// ---------- helpers ----------
__device__ __forceinline__ void edge_sd(const int* __restrict__ ei, int E, int e, int& s, int& d) {
    if (e < E) { s = ei[e]; d = ei[E + e]; } else { s = d = e - E; }
}
__device__ __forceinline__ float leaky(float x) { return (x >= 0.f) ? x : 0.2f * x; }
__device__ __forceinline__ unsigned short f2bf(float f) {
    unsigned u = __float_as_uint(f);
    u += 0x7FFFu + ((u >> 16) & 1u);
    return (unsigned short)(u >> 16);
}
__device__ __forceinline__ float bflo(unsigned v) { return __uint_as_float(v << 16); }
__device__ __forceinline__ float bfhi(unsigned v) { return __uint_as_float(v & 0xFFFF0000u); }

// ---------- MFMA GEMM: Y[n,m] = act(X[n,:K] @ W[K,M] + b) ----------
// block = 64 rows (4 waves x 16-row tile), full M width. A-tile + W^T staged
// in LDS as bf16, +8 elem row pad (2-way bank conflict = free).
// Fragment layouts (m89/m92-verified): A/B lane l elem i <-> k=(l>>4)*8+i,
// A row / B col = l&15. C/D: col=l&15, row=(l>>4)*4+reg.
template<int K, int M, bool RELU, int AIN, int OM>
__global__ __launch_bounds__(256) void gemm_mfma(
    const float* __restrict__ Xf, const unsigned short* __restrict__ Xb,
    const float* __restrict__ W, const float* __restrict__ Bias,
    float* __restrict__ Yf, unsigned short* __restrict__ Yb, int nrows)
{
    constexpr int KP = K + 8;
    __shared__ unsigned short Als[64 * KP];
    __shared__ unsigned short Wls[M * KP];
    const int t = threadIdx.x;
    const int base = blockIdx.x * 64;

    // stage W transposed: Wls[m][k] = bf16(W[k][m]); coalesced float4 reads
    for (int i = t; i < K * M / 4; i += 256) {
        int k  = i / (M / 4);
        int m0 = (i % (M / 4)) * 4;
        float4 wv = ((const float4*)W)[i];
        Wls[(m0 + 0) * KP + k] = f2bf(wv.x);
        Wls[(m0 + 1) * KP + k] = f2bf(wv.y);
        Wls[(m0 + 2) * KP + k] = f2bf(wv.z);
        Wls[(m0 + 3) * KP + k] = f2bf(wv.w);
    }
    // stage A rows (zero-fill OOB)
    if (AIN == 0) {
        for (int i = t; i < 64 * K / 4; i += 256) {
            int r  = i / (K / 4);
            int c4 = (i % (K / 4)) * 4;
            int n = base + r;
            float4 v = make_float4(0.f, 0.f, 0.f, 0.f);
            if (n < nrows) v = ((const float4*)(Xf + (size_t)n * K))[c4 >> 2];
            ushort4 pk = make_ushort4(f2bf(v.x), f2bf(v.y), f2bf(v.z), f2bf(v.w));
            *(ushort4*)&Als[r * KP + c4] = pk;
        }
    } else {
        for (int i = t; i < 64 * K / 8; i += 256) {
            int r  = i / (K / 8);
            int c8 = (i % (K / 8)) * 8;
            int n = base + r;
            uint4 v = make_uint4(0, 0, 0, 0);
            if (n < nrows) v = ((const uint4*)(Xb + (size_t)n * K))[c8 >> 3];
            *(uint4*)&Als[r * KP + c8] = v;
        }
    }
    __syncthreads();

    const int w = t >> 6, l = t & 63;
    const int lr = l & 15, lg = l >> 4;
    constexpr int CT = M / 16;
    f32x4 acc[CT];
#pragma unroll
    for (int ct = 0; ct < CT; ct++) acc[ct] = (f32x4){0.f, 0.f, 0.f, 0.f};

    const unsigned short* arow = &Als[(w * 16 + lr) * KP + lg * 8];
#pragma unroll
    for (int ks = 0; ks < K / 32; ks++) {
        bf16x8 a = *(const bf16x8*)(arow + ks * 32);
#pragma unroll
        for (int ct = 0; ct < CT; ct++) {
            bf16x8 b = *(const bf16x8*)&Wls[(ct * 16 + lr) * KP + ks * 32 + lg * 8];
            acc[ct] = __builtin_amdgcn_mfma_f32_16x16x32_bf16(a, b, acc[ct], 0, 0, 0);
        }
    }

#pragma unroll
    for (int ct = 0; ct < CT; ct++) {
        int col = ct * 16 + lr;
        float bb = Bias ? Bias[col] : 0.f;
#pragma unroll
        for (int r = 0; r < 4; r++) {
            int gr = base + w * 16 + lg * 4 + r;
            if (gr < nrows) {
                float v = acc[ct][r] + bb;
                if (RELU) v = fmaxf(v, 0.f);
                if (OM == 0) Yf[(size_t)gr * M + col] = v;
                else         Yb[(size_t)gr * M + col] = f2bf(v);
            }
        }
    }
}

// ---------- attention dots from bf16 xh, gat1 (4 heads x 32 ch) ----------
__global__ __launch_bounds__(256) void asad1_kernel(
    const unsigned short* __restrict__ xhb, const float* __restrict__ asw,
    const float* __restrict__ adw, float* __restrict__ as_n, float* __restrict__ ad_n, int N)
{
    const int t = threadIdx.x;
    const int node = blockIdx.x * 4 + (t >> 6);
    const int lane = t & 63;
    if (node >= N) return;
    unsigned u = ((const unsigned*)xhb)[(size_t)node * 64 + lane];
    float x0 = bflo(u), x1 = bfhi(u);
    int c0 = 2 * lane;
    float ps = x0 * asw[c0] + x1 * asw[c0 + 1];
    float pd = x0 * adw[c0] + x1 * adw[c0 + 1];
#pragma unroll
    for (int msk = 8; msk >= 1; msk >>= 1) {
        ps += __shfl_xor(ps, msk);
        pd += __shfl_xor(pd, msk);
    }
    if ((lane & 15) == 0) {
        as_n[node * 4 + (lane >> 4)] = ps;
        ad_n[node * 4 + (lane >> 4)] = pd;
    }
}

// ---------- attention dots, gat2 (1 head x 64 ch), bf16 ----------
__global__ __launch_bounds__(256) void asad2_kernel(
    const unsigned short* __restrict__ xhb, const float* __restrict__ asw,
    const float* __restrict__ adw, float* __restrict__ as_n, float* __restrict__ ad_n, int N)
{
    const int t = threadIdx.x;
    const int node = blockIdx.x * 8 + (t >> 5);
    const int li = t & 31;
    if (node >= N) return;
    unsigned u = ((const unsigned*)xhb)[(size_t)node * 32 + li];
    float x0 = bflo(u), x1 = bfhi(u);
    int c0 = 2 * li;
    float ps = x0 * asw[c0] + x1 * asw[c0 + 1];
    float pd = x0 * adw[c0] + x1 * adw[c0 + 1];
#pragma unroll
    for (int msk = 16; msk >= 1; msk >>= 1) {
        ps += __shfl_xor(ps, msk);
        pd += __shfl_xor(pd, msk);
    }
    if (li == 0) { as_n[node] = ps; ad_n[node] = pd; }
}

// ---------- bucketed CSR build (bucket = dst >> 8) ----------
__global__ __launch_bounds__(256) void bucket_hist(
    const int* __restrict__ ei, int E, int ET, int N, int* __restrict__ bcnt)
{
    __shared__ int h[256];
    h[threadIdx.x] = 0;
    __syncthreads();
    for (int e = blockIdx.x * 256 + threadIdx.x; e < ET; e += gridDim.x * 256) {
        int s, d; edge_sd(ei, E, e, s, d);
        if ((unsigned)s < (unsigned)N && (unsigned)d < (unsigned)N)
            atomicAdd(&h[d >> 8], 1);
    }
    __syncthreads();
    if (h[threadIdx.x]) atomicAdd(&bcnt[threadIdx.x], h[threadIdx.x]);
}

__global__ __launch_bounds__(256) void bucket_scan(
    const int* __restrict__ bcnt, int* __restrict__ bbase, int* __restrict__ bcur,
    int* __restrict__ row_start, int B, int N)
{
    __shared__ int wsum[4];
    int t = threadIdx.x, lane = t & 63, w = t >> 6;
    int v = (t < B) ? bcnt[t] : 0;
    int incl = v;
#pragma unroll
    for (int off = 1; off < 64; off <<= 1) {
        int n = __shfl_up(incl, off);
        if (lane >= off) incl += n;
    }
    if (lane == 63) wsum[w] = incl;
    __syncthreads();
    int wb = 0;
#pragma unroll
    for (int i = 0; i < 4; i++) if (i < w) wb += wsum[i];
    int excl = wb + incl - v;
    if (t < B) { bbase[t] = excl; bcur[t] = excl; }
    if (t == 255) { bbase[B] = excl + v; row_start[N] = excl + v; }
}

#define SCHUNK 4096
__global__ __launch_bounds__(256) void bucket_scatter(
    const int* __restrict__ ei, int E, int ET, int N,
    int* __restrict__ bcur, int* __restrict__ deg, uint2* __restrict__ staged)
{
    __shared__ int bc[256];
    __shared__ int bb[256];
    const int t = threadIdx.x;
    const int base = blockIdx.x * SCHUNK;
    bc[t] = 0;
    __syncthreads();
    const int cnt = min(SCHUNK, ET - base);
    int ss[16], dd[16], lr[16];
#pragma unroll
    for (int k = 0; k < 16; k++) {
        int i = t + k * 256;
        ss[k] = -1; dd[k] = 0; lr[k] = 0;
        if (i < cnt) {
            int s, d; edge_sd(ei, E, base + i, s, d);
            if ((unsigned)s < (unsigned)N && (unsigned)d < (unsigned)N) {
                ss[k] = s; dd[k] = d;
                lr[k] = atomicAdd(&bc[d >> 8], 1);
                atomicAdd(&deg[d], 1);
            }
        }
    }
    __syncthreads();
    bb[t] = bc[t] ? atomicAdd(&bcur[t], bc[t]) : 0;
    __syncthreads();
#pragma unroll
    for (int k = 0; k < 16; k++) {
        if (ss[k] >= 0)
            staged[bb[dd[k] >> 8] + lr[k]] = make_uint2((unsigned)ss[k], (unsigned)dd[k]);
    }
}

__global__ __launch_bounds__(256) void row_scan(
    const int* __restrict__ deg, const int* __restrict__ bbase,
    int* __restrict__ row_start, int N)
{
    __shared__ int wsum[4];
    const int b = blockIdx.x, t = threadIdx.x;
    const int lane = t & 63, w = t >> 6;
    const int node = b * 256 + t;
    int v = (node < N) ? deg[node] : 0;
    int incl = v;
#pragma unroll
    for (int off = 1; off < 64; off <<= 1) {
        int n = __shfl_up(incl, off);
        if (lane >= off) incl += n;
    }
    if (lane == 63) wsum[w] = incl;
    __syncthreads();
    int wb = 0;
#pragma unroll
    for (int i = 0; i < 4; i++) if (i < w) wb += wsum[i];
    if (node < N) row_start[node] = bbase[b] + wb + incl - v;
}

__global__ __launch_bounds__(256) void bucket_final(
    const uint2* __restrict__ staged, const int* __restrict__ bbase,
    const int* __restrict__ row_start, int* __restrict__ adj, int N)
{
    __shared__ int cur[256];
    const int b = blockIdx.x, t = threadIdx.x;
    const int node = b * 256 + t;
    cur[t] = (node < N) ? row_start[node] : 0;
    __syncthreads();
    const int beg = bbase[b], end = bbase[b + 1];
    for (int i = beg + t; i < end; i += 256) {
        uint2 sd = staged[i];
        int pos = atomicAdd(&cur[sd.y & 255], 1);
        adj[pos] = (int)sd.x;
    }
}

// ---------- fused GAT layer 1: LDS-staged single-pass -> bf16 h1 ----------
__global__ __launch_bounds__(256) void gat1_fused(
    const int* __restrict__ row_start, const int* __restrict__ adj,
    const float* __restrict__ as_n, const float* __restrict__ ad_n,
    const unsigned short* __restrict__ xhb, const float* __restrict__ b1,
    unsigned short* __restrict__ outb, int N)
{
    __shared__ unsigned s_ofs[4][64];
    __shared__ float    s_p[4][256];
    const int w = threadIdx.x >> 6;
    const int d = blockIdx.x * 4 + w;
    if (d >= N) return;
    const int lane = threadIdx.x & 63;
    const int h = lane >> 4;                 // head of ch {2*lane, 2*lane+1}
    const int beg = row_start[d];
    const int deg = row_start[d + 1] - beg;
    const float4 adv = ((const float4*)ad_n)[d];
    const char* xbase = (const char*)xhb;

    float l0 = 0.f, l1 = 0.f, l2 = 0.f, l3 = 0.f;
    float acc0 = 0.f, acc1 = 0.f;
    for (int j0 = 0; j0 < deg; j0 += 64) {
        const int chunk = min(64, deg - j0);
        if (lane < chunk) {
            int s = adj[beg + j0 + lane];
            float4 asv = ((const float4*)as_n)[s];
            float p0 = __expf(leaky(asv.x + adv.x));
            float p1 = __expf(leaky(asv.y + adv.y));
            float p2 = __expf(leaky(asv.z + adv.z));
            float p3 = __expf(leaky(asv.w + adv.w));
            l0 += p0; l1 += p1; l2 += p2; l3 += p3;
            s_ofs[w][lane] = (unsigned)s << 8;          // s * 256 bytes
            ((float4*)&s_p[w][lane * 4])[0] = make_float4(p0, p1, p2, p3);
        }
        __threadfence_block();
#pragma unroll 4
        for (int jj = 0; jj < chunk; jj++) {
            float a = s_p[w][jj * 4 + h];
            unsigned ofs = s_ofs[w][jj] + ((unsigned)lane << 2);
            unsigned u = *(const unsigned*)(xbase + ofs);
            acc0 += a * bflo(u);
            acc1 += a * bfhi(u);
        }
        __threadfence_block();
    }
#pragma unroll
    for (int msk = 32; msk >= 1; msk >>= 1) {
        l0 += __shfl_xor(l0, msk); l1 += __shfl_xor(l1, msk);
        l2 += __shfl_xor(l2, msk); l3 += __shfl_xor(l3, msk);
    }
    float lh = (h == 0) ? l0 : (h == 1) ? l1 : (h == 2) ? l2 : l3;
    const float inv = 1.0f / (lh + 1e-16f);
    float2 bb = ((const float2*)b1)[lane];
    float v0 = acc0 * inv + bb.x;
    float v1 = acc1 * inv + bb.y;
    v0 = (v0 > 0.f) ? v0 : expm1f(v0);
    v1 = (v1 > 0.f) ? v1 : expm1f(v1);
    unsigned pk = (unsigned)f2bf(v0) | ((unsigned)f2bf(v1) << 16);
    ((unsigned*)outb)[(size_t)d * 64 + lane] = pk;
}

// ---------- fused GAT layer 2: LDS-staged single-pass + elu + mean-pool ----------
__global__ __launch_bounds__(256) void gat2_fused(
    const int* __restrict__ row_start, const int* __restrict__ adj,
    const float* __restrict__ as_n, const float* __restrict__ ad_n,
    const unsigned short* __restrict__ xhb, const float* __restrict__ b2,
    const int* __restrict__ batch, float* __restrict__ sums, float* __restrict__ cnts,
    int N, int G)
{
    __shared__ unsigned s_ofs[4][64];
    __shared__ float    s_p[4][64];
    __shared__ float    pbuf[4][64];
    __shared__ int      pg[4];
    const int w = threadIdx.x >> 6;
    const int d = blockIdx.x * 4 + w;
    const int lane = threadIdx.x & 63;
    const bool alive = (d < N);
    int beg = 0, deg = 0; float ad = 0.f; int g = -1;
    if (alive) {
        beg = row_start[d];
        deg = row_start[d + 1] - beg;
        ad = ad_n[d];
        int gb = batch[d];
        if ((unsigned)gb < (unsigned)G) g = gb;
    }
    const char* xbase = (const char*)xhb;
    float l = 0.f, acc = 0.f;
    for (int j0 = 0; j0 < deg; j0 += 64) {
        const int chunk = min(64, deg - j0);
        if (lane < chunk) {
            int s = adj[beg + j0 + lane];
            float p = __expf(leaky(as_n[s] + ad));
            l += p;
            s_ofs[w][lane] = (unsigned)s << 7;          // s * 128 bytes
            s_p[w][lane] = p;
        }
        __threadfence_block();
#pragma unroll 4
        for (int jj = 0; jj < chunk; jj++) {
            float a = s_p[w][jj];
            unsigned ofs = s_ofs[w][jj] + ((unsigned)lane << 1);
            unsigned short uv = *(const unsigned short*)(xbase + ofs);
            acc += a * __uint_as_float((unsigned)uv << 16);
        }
        __threadfence_block();
    }
#pragma unroll
    for (int msk = 32; msk >= 1; msk >>= 1) l += __shfl_xor(l, msk);
    float v = acc / (l + 1e-16f) + b2[lane];
    v = (v > 0.f) ? v : expm1f(v);

    if (lane == 0) pg[w] = g;
    pbuf[w][lane] = (g >= 0) ? v : 0.f;
    __syncthreads();
    int g0 = pg[0], g1 = pg[1], g2 = pg[2], g3 = pg[3];
    bool uni = (g0 >= 0) && (g1 == g0) && (g2 == g0) && (g3 == g0);
    if (uni) {
        if (w == 0) {
            float s4 = pbuf[0][lane] + pbuf[1][lane] + pbuf[2][lane] + pbuf[3][lane];
            atomicAdd(&sums[(size_t)g0 * 64 + lane], s4);
            if (lane == 0) atomicAdd(&cnts[g0], 4.0f);
        }
    } else if (g >= 0) {
        atomicAdd(&sums[(size_t)g * 64 + lane], v);
        if (lane == 0) atomicAdd(&cnts[g], 1.0f);
    }
}

// ---------- final MLP + 3 heads, one wave per graph ----------
__global__ __launch_bounds__(64) void mlp_head(
    const float* __restrict__ sums, const float* __restrict__ cnts,
    const float* __restrict__ Wm1, const float* __restrict__ bm1,
    const float* __restrict__ Wm2, const float* __restrict__ bm2,
    const float* __restrict__ Wc, const float* __restrict__ bc,
    const float* __restrict__ Wr, const float* __restrict__ br,
    const float* __restrict__ Wv, const float* __restrict__ bv,
    float* __restrict__ out, int G)
{
    int g = blockIdx.x;
    int t = threadIdx.x;
    __shared__ float hrow[64];
    __shared__ float zrow[64];
    float hv = sums[(size_t)g * 64 + t] / fmaxf(cnts[g], 1.0f);
    hrow[t] = hv;
    __syncthreads();
    float z1 = bm1[t];
#pragma unroll 8
    for (int k = 0; k < 64; k++) z1 += hrow[k] * Wm1[k * 64 + t];
    z1 = fmaxf(z1, 0.f);
    zrow[t] = z1;
    __syncthreads();
    float z2 = bm2[t];
#pragma unroll 8
    for (int k = 0; k < 64; k++) z2 += zrow[k] * Wm2[k * 64 + t];
    z2 = fmaxf(z2, 0.f);
    float pc = z2 * Wc[t], pr = z2 * Wr[t], pv = z2 * Wv[t];
#pragma unroll
    for (int m = 32; m >= 1; m >>= 1) {
        pc += __shfl_xor(pc, m);
        pr += __shfl_xor(pr, m);
        pv += __shfl_xor(pv, m);
    }
    if (t == 0) {
        out[g] = pc + bc[0];
        out[G + g] = pr + br[0];
        float s = pv + bv[0];
        out[2 * G + g] = (s > 20.f) ? s : log1pf(expf(s));
    }
}

extern "C" void kernel_launch(void* const* d_in, const int* in_sizes, int n_in,
                              void* d_out, int out_size, void* d_ws, size_t ws_size,
                              hipStream_t stream)
{
    const float* x     = (const float*)d_in[0];
    const int*   ei    = (const int*)d_in[1];
    const int*   batch = (const int*)d_in[2];
    const float* Wp  = (const float*)d_in[3];
    const float* bp  = (const float*)d_in[4];
    const float* W1  = (const float*)d_in[5];
    const float* as1 = (const float*)d_in[6];
    const float* ad1 = (const float*)d_in[7];
    const float* b1  = (const float*)d_in[8];
    const float* W2  = (const float*)d_in[9];
    const float* as2 = (const float*)d_in[10];
    const float* ad2 = (const float*)d_in[11];
    const float* b2  = (const float*)d_in[12];
    const float* Wm1 = (const float*)d_in[13];
    const float* bm1 = (const float*)d_in[14];
    const float* Wm2 = (const float*)d_in[15];
    const float* bm2 = (const float*)d_in[16];
    const float* Wc  = (const float*)d_in[17];
    const float* bc  = (const float*)d_in[18];
    const float* Wr  = (const float*)d_in[19];
    const float* br  = (const float*)d_in[20];
    const float* Wv  = (const float*)d_in[21];
    const float* bv  = (const float*)d_in[22];

    const int N  = in_sizes[0] / F_IN;
    const int E  = in_sizes[1] / 2;
    const int G  = out_size / 3;
    const int ET = E + N;
    const int B  = (N + 255) >> 8;   // dst buckets of 256 nodes (N <= 65536)

    float* ws = (float*)d_ws;
    size_t o = 0;
    unsigned short* h0b  = (unsigned short*)(ws + o); o += (size_t)N * 32;  // h0 bf16 [N,64]
    unsigned short* h1b  = (unsigned short*)(ws + o); o += (size_t)N * 64;  // h1 bf16 [N,128]
    unsigned short* xhb1 = (unsigned short*)(ws + o); o += (size_t)N * 64;  // xh1 bf16 [N,128]
    unsigned short* xhb2 = (unsigned short*)(ws + o); o += (size_t)N * 32;  // xh2 bf16 [N,64]
    float* as1n = ws + o; o += (size_t)N * 4;
    float* ad1n = ws + o; o += (size_t)N * 4;
    float* as2n = ws + o; o += (size_t)N;
    float* ad2n = ws + o; o += (size_t)N;
    int* row_start = (int*)(ws + o); o += (size_t)N + 1;
    int* adj       = (int*)(ws + o); o += (size_t)ET;
    int* bbase     = (int*)(ws + o); o += 257;
    int* bcur      = (int*)(ws + o); o += 256;
    uint2* staged  = (uint2*)(ws + o); o += (size_t)ET * 2;
    // contiguous zero-init block:
    float* zstart = ws + o;
    int*   deg  = (int*)(ws + o); o += (size_t)N;
    int*   bcnt = (int*)(ws + o); o += 256;
    float* sums = ws + o;         o += (size_t)G * 64;
    float* cnts = ws + o;         o += (size_t)G;
    size_t zlen = (size_t)(ws + o - zstart) * sizeof(float);

    hipMemsetAsync(zstart, 0, zlen, stream);

    const int gN64 = (N + 63) / 64;
    const int gN4  = (N + 3) / 4;
    const int gSC  = (ET + SCHUNK - 1) / SCHUNK;

    // bucketed CSR build
    bucket_hist<<<512, 256, 0, stream>>>(ei, E, ET, N, bcnt);
    bucket_scan<<<1, 256, 0, stream>>>(bcnt, bbase, bcur, row_start, B, N);
    bucket_scatter<<<gSC, 256, 0, stream>>>(ei, E, ET, N, bcur, deg, staged);
    row_scan<<<B, 256, 0, stream>>>(deg, bbase, row_start, N);
    bucket_final<<<B, 256, 0, stream>>>(staged, bbase, row_start, adj, N);

    // node_proj: h0 = relu(x @ Wp + bp) -> bf16
    gemm_mfma<128, 64, true, 0, 1><<<gN64, 256, 0, stream>>>(x, nullptr, Wp, bp, nullptr, h0b, N);
    // gat1 transform: xh1 = h0 @ W1 -> bf16
    gemm_mfma<64, 128, false, 1, 1><<<gN64, 256, 0, stream>>>(nullptr, h0b, W1, nullptr, nullptr, xhb1, N);
    asad1_kernel<<<gN4, 256, 0, stream>>>(xhb1, as1, ad1, as1n, ad1n, N);
    // fused single-pass edge softmax + aggregate + bias + elu -> h1 (bf16)
    gat1_fused<<<gN4, 256, 0, stream>>>(row_start, adj, as1n, ad1n, xhb1, b1, h1b, N);
    // gat2 transform: xh2 = h1 @ W2 -> bf16
    gemm_mfma<128, 64, false, 1, 1><<<gN64, 256, 0, stream>>>(nullptr, h1b, W2, nullptr, nullptr, xhb2, N);
    asad2_kernel<<<(N + 7) / 8, 256, 0, stream>>>(xhb2, as2, ad2, as2n, ad2n, N);
    // fused single-pass edge softmax + aggregate + bias + elu + mean-pool
    gat2_fused<<<gN4, 256, 0, stream>>>(row_start, adj, as2n, ad2n, xhb2, b2,
                                        batch, sums, cnts, N, G);
    // final MLP heads
    mlp_head<<<G, 64, 0, stream>>>(sums, cnts, Wm1, bm1, Wm2, bm2,
                                   Wc, bc, Wr, br, Wv, bv, (float*)d_out, G);
}

// Round 12
// 321.181 us; speedup vs baseline: 3.7245x; 1.0325x over previous
//
#include <hip/hip_runtime.h>
#include <hip/hip_bf16.h>
#include <math.h>

#define F_IN 128
#define GH   64

typedef __attribute__((ext_vector_type(8))) short bf16x8;
typedef __attribute__((ext_vector_type(4))) float f32x4;

// ---------- helpers ----------
__device__ __forceinline__ void edge_sd(const int* __restrict__ ei, int E, int e, int& s, int& d) {
    if (e < E) { s = ei[e]; d = ei[E + e]; } else { s = d = e - E; }
}
__device__ __forceinline__ float leaky(float x) { return (x >= 0.f) ? x : 0.2f * x; }
__device__ __forceinline__ unsigned short f2bf(float f) {
    unsigned u = __float_as_uint(f);
    u += 0x7FFFu + ((u >> 16) & 1u);
    return (unsigned short)(u >> 16);
}
__device__ __forceinline__ float bflo(unsigned v) { return __uint_as_float(v << 16); }
__device__ __forceinline__ float bfhi(unsigned v) { return __uint_as_float(v & 0xFFFF0000u); }

// ---------- MFMA GEMM: Y[n,m] = act(X[n,:K] @ W[K,M] + b), bf16 out ----------
// DOTS=0: none. DOTS=1: fused 4-head attention dots (M=128).
// DOTS=2: fused 1-head dots (M=64). Dots computed from fp32 acc in epilogue.
// Fragment layouts (m89/m92-verified): A/B lane l elem i <-> k=(l>>4)*8+i,
// A row / B col = l&15. C/D: col=l&15, row=(l>>4)*4+reg.
template<int K, int M, bool RELU, int AIN, int DOTS>
__global__ __launch_bounds__(256) void gemm_mfma(
    const float* __restrict__ Xf, const unsigned short* __restrict__ Xb,
    const float* __restrict__ W, const float* __restrict__ Bias,
    unsigned short* __restrict__ Yb,
    const float* __restrict__ asw, const float* __restrict__ adw,
    float* __restrict__ as_n, float* __restrict__ ad_n, int nrows)
{
    constexpr int KP = K + 8;
    __shared__ unsigned short Als[64 * KP];
    __shared__ unsigned short Wls[M * KP];
    const int t = threadIdx.x;
    const int base = blockIdx.x * 64;

    // stage W transposed: Wls[m][k] = bf16(W[k][m]); coalesced float4 reads
    for (int i = t; i < K * M / 4; i += 256) {
        int k  = i / (M / 4);
        int m0 = (i % (M / 4)) * 4;
        float4 wv = ((const float4*)W)[i];
        Wls[(m0 + 0) * KP + k] = f2bf(wv.x);
        Wls[(m0 + 1) * KP + k] = f2bf(wv.y);
        Wls[(m0 + 2) * KP + k] = f2bf(wv.z);
        Wls[(m0 + 3) * KP + k] = f2bf(wv.w);
    }
    // stage A rows (zero-fill OOB)
    if (AIN == 0) {
        for (int i = t; i < 64 * K / 4; i += 256) {
            int r  = i / (K / 4);
            int c4 = (i % (K / 4)) * 4;
            int n = base + r;
            float4 v = make_float4(0.f, 0.f, 0.f, 0.f);
            if (n < nrows) v = ((const float4*)(Xf + (size_t)n * K))[c4 >> 2];
            ushort4 pk = make_ushort4(f2bf(v.x), f2bf(v.y), f2bf(v.z), f2bf(v.w));
            *(ushort4*)&Als[r * KP + c4] = pk;
        }
    } else {
        for (int i = t; i < 64 * K / 8; i += 256) {
            int r  = i / (K / 8);
            int c8 = (i % (K / 8)) * 8;
            int n = base + r;
            uint4 v = make_uint4(0, 0, 0, 0);
            if (n < nrows) v = ((const uint4*)(Xb + (size_t)n * K))[c8 >> 3];
            *(uint4*)&Als[r * KP + c8] = v;
        }
    }
    __syncthreads();

    const int w = t >> 6, l = t & 63;
    const int lr = l & 15, lg = l >> 4;
    constexpr int CT = M / 16;
    f32x4 acc[CT];
#pragma unroll
    for (int ct = 0; ct < CT; ct++) acc[ct] = (f32x4){0.f, 0.f, 0.f, 0.f};

    const unsigned short* arow = &Als[(w * 16 + lr) * KP + lg * 8];
#pragma unroll
    for (int ks = 0; ks < K / 32; ks++) {
        bf16x8 a = *(const bf16x8*)(arow + ks * 32);
#pragma unroll
        for (int ct = 0; ct < CT; ct++) {
            bf16x8 b = *(const bf16x8*)&Wls[(ct * 16 + lr) * KP + ks * 32 + lg * 8];
            acc[ct] = __builtin_amdgcn_mfma_f32_16x16x32_bf16(a, b, acc[ct], 0, 0, 0);
        }
    }

    // store bf16 output
#pragma unroll
    for (int ct = 0; ct < CT; ct++) {
        int col = ct * 16 + lr;
        float bb = Bias ? Bias[col] : 0.f;
#pragma unroll
        for (int r = 0; r < 4; r++) {
            int gr = base + w * 16 + lg * 4 + r;
            if (gr < nrows) {
                float v = acc[ct][r] + bb;
                if (RELU) v = fmaxf(v, 0.f);
                Yb[(size_t)gr * M + col] = f2bf(v);
            }
        }
    }

    // fused attention dots (no bias/act on these GEMMs)
    if (DOTS == 1) {
        float hs[4][4], hd[4][4];   // [r][head]
#pragma unroll
        for (int r = 0; r < 4; r++)
#pragma unroll
            for (int h = 0; h < 4; h++) { hs[r][h] = 0.f; hd[r][h] = 0.f; }
#pragma unroll
        for (int ct = 0; ct < CT; ct++) {
            int col = ct * 16 + lr;
            float aw = asw[col], dw = adw[col];
            int h = ct >> 1;
#pragma unroll
            for (int r = 0; r < 4; r++) {
                hs[r][h] += acc[ct][r] * aw;
                hd[r][h] += acc[ct][r] * dw;
            }
        }
#pragma unroll
        for (int msk = 8; msk >= 1; msk >>= 1) {
#pragma unroll
            for (int r = 0; r < 4; r++)
#pragma unroll
                for (int h = 0; h < 4; h++) {
                    hs[r][h] += __shfl_xor(hs[r][h], msk);
                    hd[r][h] += __shfl_xor(hd[r][h], msk);
                }
        }
        if (lr == 0) {
#pragma unroll
            for (int r = 0; r < 4; r++) {
                int gr = base + w * 16 + lg * 4 + r;
                if (gr < nrows) {
                    ((float4*)as_n)[gr] = make_float4(hs[r][0], hs[r][1], hs[r][2], hs[r][3]);
                    ((float4*)ad_n)[gr] = make_float4(hd[r][0], hd[r][1], hd[r][2], hd[r][3]);
                }
            }
        }
    } else if (DOTS == 2) {
        float ps[4], pd[4];
#pragma unroll
        for (int r = 0; r < 4; r++) { ps[r] = 0.f; pd[r] = 0.f; }
#pragma unroll
        for (int ct = 0; ct < CT; ct++) {
            int col = ct * 16 + lr;
            float aw = asw[col], dw = adw[col];
#pragma unroll
            for (int r = 0; r < 4; r++) {
                ps[r] += acc[ct][r] * aw;
                pd[r] += acc[ct][r] * dw;
            }
        }
#pragma unroll
        for (int msk = 8; msk >= 1; msk >>= 1) {
#pragma unroll
            for (int r = 0; r < 4; r++) {
                ps[r] += __shfl_xor(ps[r], msk);
                pd[r] += __shfl_xor(pd[r], msk);
            }
        }
        if (lr == 0) {
#pragma unroll
            for (int r = 0; r < 4; r++) {
                int gr = base + w * 16 + lg * 4 + r;
                if (gr < nrows) { as_n[gr] = ps[r]; ad_n[gr] = pd[r]; }
            }
        }
    }
}

// ---------- bucketed CSR build (bucket = dst >> 8) ----------
__global__ __launch_bounds__(256) void bucket_hist(
    const int* __restrict__ ei, int E, int ET, int N, int* __restrict__ bcnt)
{
    __shared__ int h[256];
    h[threadIdx.x] = 0;
    __syncthreads();
    for (int e = blockIdx.x * 256 + threadIdx.x; e < ET; e += gridDim.x * 256) {
        int s, d; edge_sd(ei, E, e, s, d);
        if ((unsigned)s < (unsigned)N && (unsigned)d < (unsigned)N)
            atomicAdd(&h[d >> 8], 1);
    }
    __syncthreads();
    if (h[threadIdx.x]) atomicAdd(&bcnt[threadIdx.x], h[threadIdx.x]);
}

__global__ __launch_bounds__(256) void bucket_scan(
    const int* __restrict__ bcnt, int* __restrict__ bbase, int* __restrict__ bcur,
    int* __restrict__ row_start, int B, int N)
{
    __shared__ int wsum[4];
    int t = threadIdx.x, lane = t & 63, w = t >> 6;
    int v = (t < B) ? bcnt[t] : 0;
    int incl = v;
#pragma unroll
    for (int off = 1; off < 64; off <<= 1) {
        int n = __shfl_up(incl, off);
        if (lane >= off) incl += n;
    }
    if (lane == 63) wsum[w] = incl;
    __syncthreads();
    int wb = 0;
#pragma unroll
    for (int i = 0; i < 4; i++) if (i < w) wb += wsum[i];
    int excl = wb + incl - v;
    if (t < B) { bbase[t] = excl; bcur[t] = excl; }
    if (t == 255) { bbase[B] = excl + v; row_start[N] = excl + v; }
}

#define SCHUNK 4096
__global__ __launch_bounds__(256) void bucket_scatter(
    const int* __restrict__ ei, int E, int ET, int N,
    int* __restrict__ bcur, int* __restrict__ deg, uint2* __restrict__ staged)
{
    __shared__ int bc[256];
    __shared__ int bb[256];
    const int t = threadIdx.x;
    const int base = blockIdx.x * SCHUNK;
    bc[t] = 0;
    __syncthreads();
    const int cnt = min(SCHUNK, ET - base);
    int ss[16], dd[16], lr[16];
#pragma unroll
    for (int k = 0; k < 16; k++) {
        int i = t + k * 256;
        ss[k] = -1; dd[k] = 0; lr[k] = 0;
        if (i < cnt) {
            int s, d; edge_sd(ei, E, base + i, s, d);
            if ((unsigned)s < (unsigned)N && (unsigned)d < (unsigned)N) {
                ss[k] = s; dd[k] = d;
                lr[k] = atomicAdd(&bc[d >> 8], 1);
                atomicAdd(&deg[d], 1);
            }
        }
    }
    __syncthreads();
    bb[t] = bc[t] ? atomicAdd(&bcur[t], bc[t]) : 0;
    __syncthreads();
#pragma unroll
    for (int k = 0; k < 16; k++) {
        if (ss[k] >= 0)
            staged[bb[dd[k] >> 8] + lr[k]] = make_uint2((unsigned)ss[k], (unsigned)dd[k]);
    }
}

__global__ __launch_bounds__(256) void row_scan(
    const int* __restrict__ deg, const int* __restrict__ bbase,
    int* __restrict__ row_start, int N)
{
    __shared__ int wsum[4];
    const int b = blockIdx.x, t = threadIdx.x;
    const int lane = t & 63, w = t >> 6;
    const int node = b * 256 + t;
    int v = (node < N) ? deg[node] : 0;
    int incl = v;
#pragma unroll
    for (int off = 1; off < 64; off <<= 1) {
        int n = __shfl_up(incl, off);
        if (lane >= off) incl += n;
    }
    if (lane == 63) wsum[w] = incl;
    __syncthreads();
    int wb = 0;
#pragma unroll
    for (int i = 0; i < 4; i++) if (i < w) wb += wsum[i];
    if (node < N) row_start[node] = bbase[b] + wb + incl - v;
}

__global__ __launch_bounds__(256) void bucket_final(
    const uint2* __restrict__ staged, const int* __restrict__ bbase,
    const int* __restrict__ row_start, int* __restrict__ adj, int N)
{
    __shared__ int cur[256];
    const int b = blockIdx.x, t = threadIdx.x;
    const int node = b * 256 + t;
    cur[t] = (node < N) ? row_start[node] : 0;
    __syncthreads();
    const int beg = bbase[b], end = bbase[b + 1];
    for (int i = beg + t; i < end; i += 256) {
        uint2 sd = staged[i];
        int pos = atomicAdd(&cur[sd.y & 255], 1);
        adj[pos] = (int)sd.x;
    }
}

// ---------- fused GAT layer 1: single-pass, half-wave 2-edge accumulate ----------
// Phase A: 64 edges parallel, exp once per edge/head -> LDS.
// Phase B: halves take even/odd edges; lane li loads uint2 = ch 4li..4li+3.
__global__ __launch_bounds__(256) void gat1_fused(
    const int* __restrict__ row_start, const int* __restrict__ adj,
    const float* __restrict__ as_n, const float* __restrict__ ad_n,
    const unsigned short* __restrict__ xhb, const float* __restrict__ b1,
    unsigned short* __restrict__ outb, int N)
{
    __shared__ unsigned s_ofs[4][64];
    __shared__ float    s_p[4][256];
    const int w = threadIdx.x >> 6;
    const int d = blockIdx.x * 4 + w;
    if (d >= N) return;
    const int lane = threadIdx.x & 63;
    const int li = lane & 31;
    const int half = lane >> 5;
    const int h = li >> 3;               // head of ch 4li..4li+3
    const int beg = row_start[d];
    const int deg = row_start[d + 1] - beg;
    const float4 adv = ((const float4*)ad_n)[d];
    const char* xbase = (const char*)xhb;

    float l0 = 0.f, l1 = 0.f, l2 = 0.f, l3 = 0.f;
    float a0 = 0.f, a1 = 0.f, a2 = 0.f, a3 = 0.f;
    for (int j0 = 0; j0 < deg; j0 += 64) {
        const int chunk = min(64, deg - j0);
        if (lane < chunk) {
            int s = adj[beg + j0 + lane];
            float4 asv = ((const float4*)as_n)[s];
            float p0 = __expf(leaky(asv.x + adv.x));
            float p1 = __expf(leaky(asv.y + adv.y));
            float p2 = __expf(leaky(asv.z + adv.z));
            float p3 = __expf(leaky(asv.w + adv.w));
            l0 += p0; l1 += p1; l2 += p2; l3 += p3;
            s_ofs[w][lane] = (unsigned)s << 8;          // s * 256 bytes
            ((float4*)&s_p[w][lane * 4])[0] = make_float4(p0, p1, p2, p3);
        }
        __threadfence_block();
#pragma unroll 4
        for (int jj = half; jj < chunk; jj += 2) {
            float a = s_p[w][jj * 4 + h];
            unsigned ofs = s_ofs[w][jj] + ((unsigned)li << 3);
            uint2 u = *(const uint2*)(xbase + ofs);
            a0 += a * bflo(u.x); a1 += a * bfhi(u.x);
            a2 += a * bflo(u.y); a3 += a * bfhi(u.y);
        }
        __threadfence_block();
    }
    // combine halves (even/odd edge partition)
    a0 += __shfl_xor(a0, 32); a1 += __shfl_xor(a1, 32);
    a2 += __shfl_xor(a2, 32); a3 += __shfl_xor(a3, 32);
#pragma unroll
    for (int msk = 32; msk >= 1; msk >>= 1) {
        l0 += __shfl_xor(l0, msk); l1 += __shfl_xor(l1, msk);
        l2 += __shfl_xor(l2, msk); l3 += __shfl_xor(l3, msk);
    }
    if (half == 0) {
        float lh = (h == 0) ? l0 : (h == 1) ? l1 : (h == 2) ? l2 : l3;
        const float inv = 1.0f / (lh + 1e-16f);
        float4 bb = ((const float4*)b1)[li];
        float v0 = a0 * inv + bb.x;
        float v1 = a1 * inv + bb.y;
        float v2 = a2 * inv + bb.z;
        float v3 = a3 * inv + bb.w;
        v0 = (v0 > 0.f) ? v0 : expm1f(v0);
        v1 = (v1 > 0.f) ? v1 : expm1f(v1);
        v2 = (v2 > 0.f) ? v2 : expm1f(v2);
        v3 = (v3 > 0.f) ? v3 : expm1f(v3);
        unsigned pk01 = (unsigned)f2bf(v0) | ((unsigned)f2bf(v1) << 16);
        unsigned pk23 = (unsigned)f2bf(v2) | ((unsigned)f2bf(v3) << 16);
        ((uint2*)((char*)outb + (size_t)d * 256))[li] = make_uint2(pk01, pk23);
    }
}

// ---------- fused GAT layer 2: single-pass + elu + mean-pool, 2-edge ILP ----------
__global__ __launch_bounds__(256) void gat2_fused(
    const int* __restrict__ row_start, const int* __restrict__ adj,
    const float* __restrict__ as_n, const float* __restrict__ ad_n,
    const unsigned short* __restrict__ xhb, const float* __restrict__ b2,
    const int* __restrict__ batch, float* __restrict__ sums, float* __restrict__ cnts,
    int N, int G)
{
    __shared__ unsigned s_ofs[4][64];
    __shared__ float    s_p[4][64];
    __shared__ float    pbuf[4][64];
    __shared__ int      pg[4];
    const int w = threadIdx.x >> 6;
    const int d = blockIdx.x * 4 + w;
    const int lane = threadIdx.x & 63;
    const int li = lane & 31;
    const int half = lane >> 5;
    const bool alive = (d < N);
    int beg = 0, deg = 0; float ad = 0.f; int g = -1;
    if (alive) {
        beg = row_start[d];
        deg = row_start[d + 1] - beg;
        ad = ad_n[d];
        int gb = batch[d];
        if ((unsigned)gb < (unsigned)G) g = gb;
    }
    const char* xbase = (const char*)xhb;
    float l = 0.f, a0 = 0.f, a1 = 0.f;
    for (int j0 = 0; j0 < deg; j0 += 64) {
        const int chunk = min(64, deg - j0);
        if (lane < chunk) {
            int s = adj[beg + j0 + lane];
            float p = __expf(leaky(as_n[s] + ad));
            l += p;
            s_ofs[w][lane] = (unsigned)s << 7;          // s * 128 bytes
            s_p[w][lane] = p;
        }
        __threadfence_block();
#pragma unroll 4
        for (int jj = half; jj < chunk; jj += 2) {
            float a = s_p[w][jj];
            unsigned ofs = s_ofs[w][jj] + ((unsigned)li << 2);
            unsigned u = *(const unsigned*)(xbase + ofs);
            a0 += a * bflo(u);
            a1 += a * bfhi(u);
        }
        __threadfence_block();
    }
    a0 += __shfl_xor(a0, 32);
    a1 += __shfl_xor(a1, 32);
#pragma unroll
    for (int msk = 32; msk >= 1; msk >>= 1) l += __shfl_xor(l, msk);

    if (lane == 0) pg[w] = g;
    if (half == 0) {
        const float inv = 1.0f / (l + 1e-16f);
        float2 bb = ((const float2*)b2)[li];
        float v0 = a0 * inv + bb.x;
        float v1 = a1 * inv + bb.y;
        v0 = (v0 > 0.f) ? v0 : expm1f(v0);
        v1 = (v1 > 0.f) ? v1 : expm1f(v1);
        ((float2*)&pbuf[w][2 * li])[0] = make_float2((g >= 0) ? v0 : 0.f,
                                                    (g >= 0) ? v1 : 0.f);
    }
    __syncthreads();
    int g0 = pg[0], g1 = pg[1], g2 = pg[2], g3 = pg[3];
    bool uni = (g0 >= 0) && (g1 == g0) && (g2 == g0) && (g3 == g0);
    if (uni) {
        if (w == 0) {
            float s4 = pbuf[0][lane] + pbuf[1][lane] + pbuf[2][lane] + pbuf[3][lane];
            atomicAdd(&sums[(size_t)g0 * 64 + lane], s4);
            if (lane == 0) atomicAdd(&cnts[g0], 4.0f);
        }
    } else if (g >= 0) {
        atomicAdd(&sums[(size_t)g * 64 + lane], pbuf[w][lane]);
        if (lane == 0) atomicAdd(&cnts[g], 1.0f);
    }
}

// ---------- final MLP + 3 heads, one wave per graph ----------
__global__ __launch_bounds__(64) void mlp_head(
    const float* __restrict__ sums, const float* __restrict__ cnts,
    const float* __restrict__ Wm1, const float* __restrict__ bm1,
    const float* __restrict__ Wm2, const float* __restrict__ bm2,
    const float* __restrict__ Wc, const float* __restrict__ bc,
    const float* __restrict__ Wr, const float* __restrict__ br,
    const float* __restrict__ Wv, const float* __restrict__ bv,
    float* __restrict__ out, int G)
{
    int g = blockIdx.x;
    int t = threadIdx.x;
    __shared__ float hrow[64];
    __shared__ float zrow[64];
    float hv = sums[(size_t)g * 64 + t] / fmaxf(cnts[g], 1.0f);
    hrow[t] = hv;
    __syncthreads();
    float z1 = bm1[t];
#pragma unroll 8
    for (int k = 0; k < 64; k++) z1 += hrow[k] * Wm1[k * 64 + t];
    z1 = fmaxf(z1, 0.f);
    zrow[t] = z1;
    __syncthreads();
    float z2 = bm2[t];
#pragma unroll 8
    for (int k = 0; k < 64; k++) z2 += zrow[k] * Wm2[k * 64 + t];
    z2 = fmaxf(z2, 0.f);
    float pc = z2 * Wc[t], pr = z2 * Wr[t], pv = z2 * Wv[t];
#pragma unroll
    for (int m = 32; m >= 1; m >>= 1) {
        pc += __shfl_xor(pc, m);
        pr += __shfl_xor(pr, m);
        pv += __shfl_xor(pv, m);
    }
    if (t == 0) {
        out[g] = pc + bc[0];
        out[G + g] = pr + br[0];
        float s = pv + bv[0];
        out[2 * G + g] = (s > 20.f) ? s : log1pf(expf(s));
    }
}

extern "C" void kernel_launch(void* const* d_in, const int* in_sizes, int n_in,
                              void* d_out, int out_size, void* d_ws, size_t ws_size,
                              hipStream_t stream)
{
    const float* x     = (const float*)d_in[0];
    const int*   ei    = (const int*)d_in[1];
    const int*   batch = (const int*)d_in[2];
    const float* Wp  = (const float*)d_in[3];
    const float* bp  = (const float*)d_in[4];
    const float* W1  = (const float*)d_in[5];
    const float* as1 = (const float*)d_in[6];
    const float* ad1 = (const float*)d_in[7];
    const float* b1  = (const float*)d_in[8];
    const float* W2  = (const float*)d_in[9];
    const float* as2 = (const float*)d_in[10];
    const float* ad2 = (const float*)d_in[11];
    const float* b2  = (const float*)d_in[12];
    const float* Wm1 = (const float*)d_in[13];
    const float* bm1 = (const float*)d_in[14];
    const float* Wm2 = (const float*)d_in[15];
    const float* bm2 = (const float*)d_in[16];
    const float* Wc  = (const float*)d_in[17];
    const float* bc  = (const float*)d_in[18];
    const float* Wr  = (const float*)d_in[19];
    const float* br  = (const float*)d_in[20];
    const float* Wv  = (const float*)d_in[21];
    const float* bv  = (const float*)d_in[22];

    const int N  = in_sizes[0] / F_IN;
    const int E  = in_sizes[1] / 2;
    const int G  = out_size / 3;
    const int ET = E + N;
    const int B  = (N + 255) >> 8;   // dst buckets of 256 nodes (N <= 65536)

    float* ws = (float*)d_ws;
    size_t o = 0;
    unsigned short* h0b  = (unsigned short*)(ws + o); o += (size_t)N * 32;  // h0 bf16 [N,64]
    unsigned short* h1b  = (unsigned short*)(ws + o); o += (size_t)N * 64;  // h1 bf16 [N,128]
    unsigned short* xhb1 = (unsigned short*)(ws + o); o += (size_t)N * 64;  // xh1 bf16 [N,128]
    unsigned short* xhb2 = (unsigned short*)(ws + o); o += (size_t)N * 32;  // xh2 bf16 [N,64]
    float* as1n = ws + o; o += (size_t)N * 4;
    float* ad1n = ws + o; o += (size_t)N * 4;
    float* as2n = ws + o; o += (size_t)N;
    float* ad2n = ws + o; o += (size_t)N;
    int* row_start = (int*)(ws + o); o += (size_t)N + 1;
    int* adj       = (int*)(ws + o); o += (size_t)ET;
    int* bbase     = (int*)(ws + o); o += 257;
    int* bcur      = (int*)(ws + o); o += 256;
    uint2* staged  = (uint2*)(ws + o); o += (size_t)ET * 2;
    // contiguous zero-init block:
    float* zstart = ws + o;
    int*   deg  = (int*)(ws + o); o += (size_t)N;
    int*   bcnt = (int*)(ws + o); o += 256;
    float* sums = ws + o;         o += (size_t)G * 64;
    float* cnts = ws + o;         o += (size_t)G;
    size_t zlen = (size_t)(ws + o - zstart) * sizeof(float);

    hipMemsetAsync(zstart, 0, zlen, stream);

    const int gN64 = (N + 63) / 64;
    const int gN4  = (N + 3) / 4;
    const int gSC  = (ET + SCHUNK - 1) / SCHUNK;

    // bucketed CSR build
    bucket_hist<<<512, 256, 0, stream>>>(ei, E, ET, N, bcnt);
    bucket_scan<<<1, 256, 0, stream>>>(bcnt, bbase, bcur, row_start, B, N);
    bucket_scatter<<<gSC, 256, 0, stream>>>(ei, E, ET, N, bcur, deg, staged);
    row_scan<<<B, 256, 0, stream>>>(deg, bbase, row_start, N);
    bucket_final<<<B, 256, 0, stream>>>(staged, bbase, row_start, adj, N);

    // node_proj: h0 = relu(x @ Wp + bp) -> bf16
    gemm_mfma<128, 64, true, 0, 0><<<gN64, 256, 0, stream>>>(
        x, nullptr, Wp, bp, h0b, nullptr, nullptr, nullptr, nullptr, N);
    // gat1 transform: xh1 = h0 @ W1 -> bf16, fused 4-head attention dots
    gemm_mfma<64, 128, false, 1, 1><<<gN64, 256, 0, stream>>>(
        nullptr, h0b, W1, nullptr, xhb1, as1, ad1, as1n, ad1n, N);
    // fused single-pass edge softmax + aggregate + bias + elu -> h1 (bf16)
    gat1_fused<<<gN4, 256, 0, stream>>>(row_start, adj, as1n, ad1n, xhb1, b1, h1b, N);
    // gat2 transform: xh2 = h1 @ W2 -> bf16, fused 1-head dots
    gemm_mfma<128, 64, false, 1, 2><<<gN64, 256, 0, stream>>>(
        nullptr, h1b, W2, nullptr, xhb2, as2, ad2, as2n, ad2n, N);
    // fused single-pass edge softmax + aggregate + bias + elu + mean-pool
    gat2_fused<<<gN4, 256, 0, stream>>>(row_start, adj, as2n, ad2n, xhb2, b2,
                                        batch, sums, cnts, N, G);
    // final MLP heads
    mlp_head<<<G, 64, 0, stream>>>(sums, cnts, Wm1, bm1, Wm2, bm2,
                                   Wc, bc, Wr, br, Wv, bv, (float*)d_out, G);
}

// Round 13
// 293.623 us; speedup vs baseline: 4.0741x; 1.0939x over previous
//
#include <hip/hip_runtime.h>
#include <hip/hip_bf16.h>
#include <math.h>

#define F_IN 128
#define GH   64

typedef __attribute__((ext_vector_type(8))) short bf16x8;
typedef __attribute__((ext_vector_type(4))) float f32x4;

// ---------- helpers ----------
__device__ __forceinline__ void edge_sd(const int* __restrict__ ei, int E, int e, int& s, int& d) {
    if (e < E) { s = ei[e]; d = ei[E + e]; } else { s = d = e - E; }
}
__device__ __forceinline__ float leaky(float x) { return (x >= 0.f) ? x : 0.2f * x; }
__device__ __forceinline__ unsigned short f2bf(float f) {
    unsigned u = __float_as_uint(f);
    u += 0x7FFFu + ((u >> 16) & 1u);
    return (unsigned short)(u >> 16);
}
__device__ __forceinline__ float bflo(unsigned v) { return __uint_as_float(v << 16); }
__device__ __forceinline__ float bfhi(unsigned v) { return __uint_as_float(v & 0xFFFF0000u); }

// ---------- MFMA GEMM: Y[n,m] = act(X[n,:K] @ W[K,M] + b), bf16 out ----------
// DOTS=0: none. DOTS=1: fused 4-head attention dots (M=128).
// DOTS=2: fused 1-head dots (M=64). Dots computed from fp32 acc in epilogue.
template<int K, int M, bool RELU, int AIN, int DOTS>
__global__ __launch_bounds__(256) void gemm_mfma(
    const float* __restrict__ Xf, const unsigned short* __restrict__ Xb,
    const float* __restrict__ W, const float* __restrict__ Bias,
    unsigned short* __restrict__ Yb,
    const float* __restrict__ asw, const float* __restrict__ adw,
    float* __restrict__ as_n, float* __restrict__ ad_n, int nrows)
{
    constexpr int KP = K + 8;
    __shared__ unsigned short Als[64 * KP];
    __shared__ unsigned short Wls[M * KP];
    const int t = threadIdx.x;
    const int base = blockIdx.x * 64;

    for (int i = t; i < K * M / 4; i += 256) {
        int k  = i / (M / 4);
        int m0 = (i % (M / 4)) * 4;
        float4 wv = ((const float4*)W)[i];
        Wls[(m0 + 0) * KP + k] = f2bf(wv.x);
        Wls[(m0 + 1) * KP + k] = f2bf(wv.y);
        Wls[(m0 + 2) * KP + k] = f2bf(wv.z);
        Wls[(m0 + 3) * KP + k] = f2bf(wv.w);
    }
    if (AIN == 0) {
        for (int i = t; i < 64 * K / 4; i += 256) {
            int r  = i / (K / 4);
            int c4 = (i % (K / 4)) * 4;
            int n = base + r;
            float4 v = make_float4(0.f, 0.f, 0.f, 0.f);
            if (n < nrows) v = ((const float4*)(Xf + (size_t)n * K))[c4 >> 2];
            ushort4 pk = make_ushort4(f2bf(v.x), f2bf(v.y), f2bf(v.z), f2bf(v.w));
            *(ushort4*)&Als[r * KP + c4] = pk;
        }
    } else {
        for (int i = t; i < 64 * K / 8; i += 256) {
            int r  = i / (K / 8);
            int c8 = (i % (K / 8)) * 8;
            int n = base + r;
            uint4 v = make_uint4(0, 0, 0, 0);
            if (n < nrows) v = ((const uint4*)(Xb + (size_t)n * K))[c8 >> 3];
            *(uint4*)&Als[r * KP + c8] = v;
        }
    }
    __syncthreads();

    const int w = t >> 6, l = t & 63;
    const int lr = l & 15, lg = l >> 4;
    constexpr int CT = M / 16;
    f32x4 acc[CT];
#pragma unroll
    for (int ct = 0; ct < CT; ct++) acc[ct] = (f32x4){0.f, 0.f, 0.f, 0.f};

    const unsigned short* arow = &Als[(w * 16 + lr) * KP + lg * 8];
#pragma unroll
    for (int ks = 0; ks < K / 32; ks++) {
        bf16x8 a = *(const bf16x8*)(arow + ks * 32);
#pragma unroll
        for (int ct = 0; ct < CT; ct++) {
            bf16x8 b = *(const bf16x8*)&Wls[(ct * 16 + lr) * KP + ks * 32 + lg * 8];
            acc[ct] = __builtin_amdgcn_mfma_f32_16x16x32_bf16(a, b, acc[ct], 0, 0, 0);
        }
    }

#pragma unroll
    for (int ct = 0; ct < CT; ct++) {
        int col = ct * 16 + lr;
        float bb = Bias ? Bias[col] : 0.f;
#pragma unroll
        for (int r = 0; r < 4; r++) {
            int gr = base + w * 16 + lg * 4 + r;
            if (gr < nrows) {
                float v = acc[ct][r] + bb;
                if (RELU) v = fmaxf(v, 0.f);
                Yb[(size_t)gr * M + col] = f2bf(v);
            }
        }
    }

    if (DOTS == 1) {
        float hs[4][4], hd[4][4];
#pragma unroll
        for (int r = 0; r < 4; r++)
#pragma unroll
            for (int h = 0; h < 4; h++) { hs[r][h] = 0.f; hd[r][h] = 0.f; }
#pragma unroll
        for (int ct = 0; ct < CT; ct++) {
            int col = ct * 16 + lr;
            float aw = asw[col], dw = adw[col];
            int h = ct >> 1;
#pragma unroll
            for (int r = 0; r < 4; r++) {
                hs[r][h] += acc[ct][r] * aw;
                hd[r][h] += acc[ct][r] * dw;
            }
        }
#pragma unroll
        for (int msk = 8; msk >= 1; msk >>= 1) {
#pragma unroll
            for (int r = 0; r < 4; r++)
#pragma unroll
                for (int h = 0; h < 4; h++) {
                    hs[r][h] += __shfl_xor(hs[r][h], msk);
                    hd[r][h] += __shfl_xor(hd[r][h], msk);
                }
        }
        if (lr == 0) {
#pragma unroll
            for (int r = 0; r < 4; r++) {
                int gr = base + w * 16 + lg * 4 + r;
                if (gr < nrows) {
                    ((float4*)as_n)[gr] = make_float4(hs[r][0], hs[r][1], hs[r][2], hs[r][3]);
                    ((float4*)ad_n)[gr] = make_float4(hd[r][0], hd[r][1], hd[r][2], hd[r][3]);
                }
            }
        }
    } else if (DOTS == 2) {
        float ps[4], pd[4];
#pragma unroll
        for (int r = 0; r < 4; r++) { ps[r] = 0.f; pd[r] = 0.f; }
#pragma unroll
        for (int ct = 0; ct < CT; ct++) {
            int col = ct * 16 + lr;
            float aw = asw[col], dw = adw[col];
#pragma unroll
            for (int r = 0; r < 4; r++) {
                ps[r] += acc[ct][r] * aw;
                pd[r] += acc[ct][r] * dw;
            }
        }
#pragma unroll
        for (int msk = 8; msk >= 1; msk >>= 1) {
#pragma unroll
            for (int r = 0; r < 4; r++) {
                ps[r] += __shfl_xor(ps[r], msk);
                pd[r] += __shfl_xor(pd[r], msk);
            }
        }
        if (lr == 0) {
#pragma unroll
            for (int r = 0; r < 4; r++) {
                int gr = base + w * 16 + lg * 4 + r;
                if (gr < nrows) { as_n[gr] = ps[r]; ad_n[gr] = pd[r]; }
            }
        }
    }
}

// ---------- bucketed CSR build (bucket = dst >> 8; requires N <= 65536) ----------
__global__ __launch_bounds__(256) void bucket_hist(
    const int* __restrict__ ei, int E, int ET, int N, int* __restrict__ bcnt)
{
    __shared__ int h[256];
    h[threadIdx.x] = 0;
    __syncthreads();
    for (int e = blockIdx.x * 256 + threadIdx.x; e < ET; e += gridDim.x * 256) {
        int s, d; edge_sd(ei, E, e, s, d);
        if ((unsigned)s < (unsigned)N && (unsigned)d < (unsigned)N)
            atomicAdd(&h[d >> 8], 1);
    }
    __syncthreads();
    if (h[threadIdx.x]) atomicAdd(&bcnt[threadIdx.x], h[threadIdx.x]);
}

__global__ __launch_bounds__(256) void bucket_scan(
    const int* __restrict__ bcnt, int* __restrict__ bbase, int* __restrict__ bcur,
    int* __restrict__ row_start, int B, int N)
{
    __shared__ int wsum[4];
    int t = threadIdx.x, lane = t & 63, w = t >> 6;
    int v = (t < B) ? bcnt[t] : 0;
    int incl = v;
#pragma unroll
    for (int off = 1; off < 64; off <<= 1) {
        int n = __shfl_up(incl, off);
        if (lane >= off) incl += n;
    }
    if (lane == 63) wsum[w] = incl;
    __syncthreads();
    int wb = 0;
#pragma unroll
    for (int i = 0; i < 4; i++) if (i < w) wb += wsum[i];
    int excl = wb + incl - v;
    if (t < B) { bbase[t] = excl; bcur[t] = excl; }
    if (t == 255) { bbase[B] = excl + v; row_start[N] = excl + v; }
}

// stage edges bucket-contiguously: two streaming passes (count -> place into
// LDS sorted by bucket), packed uint32 = bucket(8)|d&255(8)|s(16), then
// coalesced run writes. No register arrays, no global deg.
#define SCHUNK 2048
__global__ __launch_bounds__(256) void bucket_scatter(
    const int* __restrict__ ei, int E, int ET, int N,
    int* __restrict__ bcur, unsigned* __restrict__ staged)
{
    __shared__ int bc[256];       // count, then local cursor
    __shared__ int lbase[256];    // local exclusive prefix
    __shared__ int bb[256];       // global run base
    __shared__ unsigned sorted[SCHUNK];
    __shared__ int wsum[4];
    const int t = threadIdx.x;
    const int lane = t & 63, wv = t >> 6;
    const int base = blockIdx.x * SCHUNK;
    const int cnt = min(SCHUNK, ET - base);
    bc[t] = 0;
    __syncthreads();
    // pass 1: per-bucket counts
    for (int i = t; i < cnt; i += 256) {
        int s, d; edge_sd(ei, E, base + i, s, d);
        if ((unsigned)s < (unsigned)N && (unsigned)d < (unsigned)N)
            atomicAdd(&bc[d >> 8], 1);
    }
    __syncthreads();
    // block scan -> lbase; reserve global runs
    int v = bc[t];
    int incl = v;
#pragma unroll
    for (int off = 1; off < 64; off <<= 1) {
        int n = __shfl_up(incl, off);
        if (lane >= off) incl += n;
    }
    if (lane == 63) wsum[wv] = incl;
    __syncthreads();
    int wb = 0;
#pragma unroll
    for (int i = 0; i < 4; i++) if (i < wv) wb += wsum[i];
    int excl = wb + incl - v;
    lbase[t] = excl;
    bb[t] = v ? atomicAdd(&bcur[t], v) : 0;
    __syncthreads();
    bc[t] = excl;                 // local cursor
    __syncthreads();
    // pass 2: place into LDS sorted by bucket
    for (int i = t; i < cnt; i += 256) {
        int s, d; edge_sd(ei, E, base + i, s, d);
        if ((unsigned)s < (unsigned)N && (unsigned)d < (unsigned)N) {
            int b = d >> 8;
            int r = atomicAdd(&bc[b], 1);
            sorted[r] = ((unsigned)b << 24) | ((unsigned)(d & 255) << 16) | (unsigned)s;
        }
    }
    __syncthreads();
    const int total = bc[255];    // cursor after last bucket = valid count
    // coalesced run writes
    for (int i = t; i < total; i += 256) {
        unsigned wd = sorted[i];
        int b = wd >> 24;
        staged[bb[b] + (i - lbase[b])] = wd;
    }
}

// per-bucket: histogram d&255 -> row_start (block scan), then adj scatter
__global__ __launch_bounds__(256) void bucket_build(
    const unsigned* __restrict__ staged, const int* __restrict__ bbase,
    int* __restrict__ row_start, int* __restrict__ adj, int N)
{
    __shared__ int cnt2[256];
    __shared__ int cur2[256];
    __shared__ int wsum[4];
    const int b = blockIdx.x, t = threadIdx.x;
    const int lane = t & 63, wv = t >> 6;
    const int beg = bbase[b], end = bbase[b + 1];
    cnt2[t] = 0;
    __syncthreads();
    for (int i = beg + t; i < end; i += 256)
        atomicAdd(&cnt2[(staged[i] >> 16) & 255], 1);
    __syncthreads();
    int v = cnt2[t];
    int incl = v;
#pragma unroll
    for (int off = 1; off < 64; off <<= 1) {
        int n = __shfl_up(incl, off);
        if (lane >= off) incl += n;
    }
    if (lane == 63) wsum[wv] = incl;
    __syncthreads();
    int wb = 0;
#pragma unroll
    for (int i = 0; i < 4; i++) if (i < wv) wb += wsum[i];
    int excl = beg + wb + incl - v;
    int node = b * 256 + t;
    if (node < N) row_start[node] = excl;
    cur2[t] = excl;
    __syncthreads();
    for (int i = beg + t; i < end; i += 256) {
        unsigned wd = staged[i];
        int pos = atomicAdd(&cur2[(wd >> 16) & 255], 1);
        adj[pos] = (int)(wd & 0xFFFFu);
    }
}

// ---------- fused GAT layer 1: single-pass, half-wave 2-edge accumulate ----------
__global__ __launch_bounds__(256) void gat1_fused(
    const int* __restrict__ row_start, const int* __restrict__ adj,
    const float* __restrict__ as_n, const float* __restrict__ ad_n,
    const unsigned short* __restrict__ xhb, const float* __restrict__ b1,
    unsigned short* __restrict__ outb, int N)
{
    __shared__ unsigned s_ofs[4][64];
    __shared__ float    s_p[4][256];
    const int w = threadIdx.x >> 6;
    const int d = blockIdx.x * 4 + w;
    if (d >= N) return;
    const int lane = threadIdx.x & 63;
    const int li = lane & 31;
    const int half = lane >> 5;
    const int h = li >> 3;
    const int beg = row_start[d];
    const int deg = row_start[d + 1] - beg;
    const float4 adv = ((const float4*)ad_n)[d];
    const char* xbase = (const char*)xhb;

    float l0 = 0.f, l1 = 0.f, l2 = 0.f, l3 = 0.f;
    float a0 = 0.f, a1 = 0.f, a2 = 0.f, a3 = 0.f;
    for (int j0 = 0; j0 < deg; j0 += 64) {
        const int chunk = min(64, deg - j0);
        if (lane < chunk) {
            int s = adj[beg + j0 + lane];
            float4 asv = ((const float4*)as_n)[s];
            float p0 = __expf(leaky(asv.x + adv.x));
            float p1 = __expf(leaky(asv.y + adv.y));
            float p2 = __expf(leaky(asv.z + adv.z));
            float p3 = __expf(leaky(asv.w + adv.w));
            l0 += p0; l1 += p1; l2 += p2; l3 += p3;
            s_ofs[w][lane] = (unsigned)s << 8;
            ((float4*)&s_p[w][lane * 4])[0] = make_float4(p0, p1, p2, p3);
        }
        __threadfence_block();
#pragma unroll 4
        for (int jj = half; jj < chunk; jj += 2) {
            float a = s_p[w][jj * 4 + h];
            unsigned ofs = s_ofs[w][jj] + ((unsigned)li << 3);
            uint2 u = *(const uint2*)(xbase + ofs);
            a0 += a * bflo(u.x); a1 += a * bfhi(u.x);
            a2 += a * bflo(u.y); a3 += a * bfhi(u.y);
        }
        __threadfence_block();
    }
    a0 += __shfl_xor(a0, 32); a1 += __shfl_xor(a1, 32);
    a2 += __shfl_xor(a2, 32); a3 += __shfl_xor(a3, 32);
#pragma unroll
    for (int msk = 32; msk >= 1; msk >>= 1) {
        l0 += __shfl_xor(l0, msk); l1 += __shfl_xor(l1, msk);
        l2 += __shfl_xor(l2, msk); l3 += __shfl_xor(l3, msk);
    }
    if (half == 0) {
        float lh = (h == 0) ? l0 : (h == 1) ? l1 : (h == 2) ? l2 : l3;
        const float inv = 1.0f / (lh + 1e-16f);
        float4 bb = ((const float4*)b1)[li];
        float v0 = a0 * inv + bb.x;
        float v1 = a1 * inv + bb.y;
        float v2 = a2 * inv + bb.z;
        float v3 = a3 * inv + bb.w;
        v0 = (v0 > 0.f) ? v0 : expm1f(v0);
        v1 = (v1 > 0.f) ? v1 : expm1f(v1);
        v2 = (v2 > 0.f) ? v2 : expm1f(v2);
        v3 = (v3 > 0.f) ? v3 : expm1f(v3);
        unsigned pk01 = (unsigned)f2bf(v0) | ((unsigned)f2bf(v1) << 16);
        unsigned pk23 = (unsigned)f2bf(v2) | ((unsigned)f2bf(v3) << 16);
        ((uint2*)((char*)outb + (size_t)d * 256))[li] = make_uint2(pk01, pk23);
    }
}

// ---------- fused GAT layer 2: single-pass + elu + mean-pool, 2-edge ILP ----------
__global__ __launch_bounds__(256) void gat2_fused(
    const int* __restrict__ row_start, const int* __restrict__ adj,
    const float* __restrict__ as_n, const float* __restrict__ ad_n,
    const unsigned short* __restrict__ xhb, const float* __restrict__ b2,
    const int* __restrict__ batch, float* __restrict__ sums, float* __restrict__ cnts,
    int N, int G)
{
    __shared__ unsigned s_ofs[4][64];
    __shared__ float    s_p[4][64];
    __shared__ float    pbuf[4][64];
    __shared__ int      pg[4];
    const int w = threadIdx.x >> 6;
    const int d = blockIdx.x * 4 + w;
    const int lane = threadIdx.x & 63;
    const int li = lane & 31;
    const int half = lane >> 5;
    const bool alive = (d < N);
    int beg = 0, deg = 0; float ad = 0.f; int g = -1;
    if (alive) {
        beg = row_start[d];
        deg = row_start[d + 1] - beg;
        ad = ad_n[d];
        int gb = batch[d];
        if ((unsigned)gb < (unsigned)G) g = gb;
    }
    const char* xbase = (const char*)xhb;
    float l = 0.f, a0 = 0.f, a1 = 0.f;
    for (int j0 = 0; j0 < deg; j0 += 64) {
        const int chunk = min(64, deg - j0);
        if (lane < chunk) {
            int s = adj[beg + j0 + lane];
            float p = __expf(leaky(as_n[s] + ad));
            l += p;
            s_ofs[w][lane] = (unsigned)s << 7;
            s_p[w][lane] = p;
        }
        __threadfence_block();
#pragma unroll 4
        for (int jj = half; jj < chunk; jj += 2) {
            float a = s_p[w][jj];
            unsigned ofs = s_ofs[w][jj] + ((unsigned)li << 2);
            unsigned u = *(const unsigned*)(xbase + ofs);
            a0 += a * bflo(u);
            a1 += a * bfhi(u);
        }
        __threadfence_block();
    }
    a0 += __shfl_xor(a0, 32);
    a1 += __shfl_xor(a1, 32);
#pragma unroll
    for (int msk = 32; msk >= 1; msk >>= 1) l += __shfl_xor(l, msk);

    if (lane == 0) pg[w] = g;
    if (half == 0) {
        const float inv = 1.0f / (l + 1e-16f);
        float2 bb = ((const float2*)b2)[li];
        float v0 = a0 * inv + bb.x;
        float v1 = a1 * inv + bb.y;
        v0 = (v0 > 0.f) ? v0 : expm1f(v0);
        v1 = (v1 > 0.f) ? v1 : expm1f(v1);
        ((float2*)&pbuf[w][2 * li])[0] = make_float2((g >= 0) ? v0 : 0.f,
                                                    (g >= 0) ? v1 : 0.f);
    }
    __syncthreads();
    int g0 = pg[0], g1 = pg[1], g2 = pg[2], g3 = pg[3];
    bool uni = (g0 >= 0) && (g1 == g0) && (g2 == g0) && (g3 == g0);
    if (uni) {
        if (w == 0) {
            float s4 = pbuf[0][lane] + pbuf[1][lane] + pbuf[2][lane] + pbuf[3][lane];
            atomicAdd(&sums[(size_t)g0 * 64 + lane], s4);
            if (lane == 0) atomicAdd(&cnts[g0], 4.0f);
        }
    } else if (g >= 0) {
        atomicAdd(&sums[(size_t)g * 64 + lane], pbuf[w][lane]);
        if (lane == 0) atomicAdd(&cnts[g], 1.0f);
    }
}

// ---------- final MLP + 3 heads, one wave per graph ----------
__global__ __launch_bounds__(64) void mlp_head(
    const float* __restrict__ sums, const float* __restrict__ cnts,
    const float* __restrict__ Wm1, const float* __restrict__ bm1,
    const float* __restrict__ Wm2, const float* __restrict__ bm2,
    const float* __restrict__ Wc, const float* __restrict__ bc,
    const float* __restrict__ Wr, const float* __restrict__ br,
    const float* __restrict__ Wv, const float* __restrict__ bv,
    float* __restrict__ out, int G)
{
    int g = blockIdx.x;
    int t = threadIdx.x;
    __shared__ float hrow[64];
    __shared__ float zrow[64];
    float hv = sums[(size_t)g * 64 + t] / fmaxf(cnts[g], 1.0f);
    hrow[t] = hv;
    __syncthreads();
    float z1 = bm1[t];
#pragma unroll 8
    for (int k = 0; k < 64; k++) z1 += hrow[k] * Wm1[k * 64 + t];
    z1 = fmaxf(z1, 0.f);
    zrow[t] = z1;
    __syncthreads();
    float z2 = bm2[t];
#pragma unroll 8
    for (int k = 0; k < 64; k++) z2 += zrow[k] * Wm2[k * 64 + t];
    z2 = fmaxf(z2, 0.f);
    float pc = z2 * Wc[t], pr = z2 * Wr[t], pv = z2 * Wv[t];
#pragma unroll
    for (int m = 32; m >= 1; m >>= 1) {
        pc += __shfl_xor(pc, m);
        pr += __shfl_xor(pr, m);
        pv += __shfl_xor(pv, m);
    }
    if (t == 0) {
        out[g] = pc + bc[0];
        out[G + g] = pr + br[0];
        float s = pv + bv[0];
        out[2 * G + g] = (s > 20.f) ? s : log1pf(expf(s));
    }
}

extern "C" void kernel_launch(void* const* d_in, const int* in_sizes, int n_in,
                              void* d_out, int out_size, void* d_ws, size_t ws_size,
                              hipStream_t stream)
{
    const float* x     = (const float*)d_in[0];
    const int*   ei    = (const int*)d_in[1];
    const int*   batch = (const int*)d_in[2];
    const float* Wp  = (const float*)d_in[3];
    const float* bp  = (const float*)d_in[4];
    const float* W1  = (const float*)d_in[5];
    const float* as1 = (const float*)d_in[6];
    const float* ad1 = (const float*)d_in[7];
    const float* b1  = (const float*)d_in[8];
    const float* W2  = (const float*)d_in[9];
    const float* as2 = (const float*)d_in[10];
    const float* ad2 = (const float*)d_in[11];
    const float* b2  = (const float*)d_in[12];
    const float* Wm1 = (const float*)d_in[13];
    const float* bm1 = (const float*)d_in[14];
    const float* Wm2 = (const float*)d_in[15];
    const float* bm2 = (const float*)d_in[16];
    const float* Wc  = (const float*)d_in[17];
    const float* bc  = (const float*)d_in[18];
    const float* Wr  = (const float*)d_in[19];
    const float* br  = (const float*)d_in[20];
    const float* Wv  = (const float*)d_in[21];
    const float* bv  = (const float*)d_in[22];

    const int N  = in_sizes[0] / F_IN;
    const int E  = in_sizes[1] / 2;
    const int G  = out_size / 3;
    const int ET = E + N;
    const int B  = (N + 255) >> 8;   // dst buckets of 256 nodes (N <= 65536)

    float* ws = (float*)d_ws;
    size_t o = 0;
    unsigned short* h0b  = (unsigned short*)(ws + o); o += (size_t)N * 32;  // h0 bf16 [N,64]
    unsigned short* h1b  = (unsigned short*)(ws + o); o += (size_t)N * 64;  // h1 bf16 [N,128]
    unsigned short* xhb1 = (unsigned short*)(ws + o); o += (size_t)N * 64;  // xh1 bf16 [N,128]
    unsigned short* xhb2 = (unsigned short*)(ws + o); o += (size_t)N * 32;  // xh2 bf16 [N,64]
    float* as1n = ws + o; o += (size_t)N * 4;
    float* ad1n = ws + o; o += (size_t)N * 4;
    float* as2n = ws + o; o += (size_t)N;
    float* ad2n = ws + o; o += (size_t)N;
    int* row_start = (int*)(ws + o); o += (size_t)N + 1;
    int* adj       = (int*)(ws + o); o += (size_t)ET;
    int* bbase     = (int*)(ws + o); o += 257;
    int* bcur      = (int*)(ws + o); o += 256;
    unsigned* staged = (unsigned*)(ws + o); o += (size_t)ET;
    // contiguous zero-init block:
    float* zstart = ws + o;
    int*   bcnt = (int*)(ws + o); o += 256;
    float* sums = ws + o;         o += (size_t)G * 64;
    float* cnts = ws + o;         o += (size_t)G;
    size_t zlen = (size_t)(ws + o - zstart) * sizeof(float);

    hipMemsetAsync(zstart, 0, zlen, stream);

    const int gN64 = (N + 63) / 64;
    const int gN4  = (N + 3) / 4;
    const int gSC  = (ET + SCHUNK - 1) / SCHUNK;

    // bucketed CSR build
    bucket_hist<<<512, 256, 0, stream>>>(ei, E, ET, N, bcnt);
    bucket_scan<<<1, 256, 0, stream>>>(bcnt, bbase, bcur, row_start, B, N);
    bucket_scatter<<<gSC, 256, 0, stream>>>(ei, E, ET, N, bcur, staged);
    bucket_build<<<B, 256, 0, stream>>>(staged, bbase, row_start, adj, N);

    // node_proj: h0 = relu(x @ Wp + bp) -> bf16
    gemm_mfma<128, 64, true, 0, 0><<<gN64, 256, 0, stream>>>(
        x, nullptr, Wp, bp, h0b, nullptr, nullptr, nullptr, nullptr, N);
    // gat1 transform: xh1 = h0 @ W1 -> bf16, fused 4-head attention dots
    gemm_mfma<64, 128, false, 1, 1><<<gN64, 256, 0, stream>>>(
        nullptr, h0b, W1, nullptr, xhb1, as1, ad1, as1n, ad1n, N);
    // fused single-pass edge softmax + aggregate + bias + elu -> h1 (bf16)
    gat1_fused<<<gN4, 256, 0, stream>>>(row_start, adj, as1n, ad1n, xhb1, b1, h1b, N);
    // gat2 transform: xh2 = h1 @ W2 -> bf16, fused 1-head dots
    gemm_mfma<128, 64, false, 1, 2><<<gN64, 256, 0, stream>>>(
        nullptr, h1b, W2, nullptr, xhb2, as2, ad2, as2n, ad2n, N);
    // fused single-pass edge softmax + aggregate + bias + elu + mean-pool
    gat2_fused<<<gN4, 256, 0, stream>>>(row_start, adj, as2n, ad2n, xhb2, b2,
                                        batch, sums, cnts, N, G);
    // final MLP heads
    mlp_head<<<G, 64, 0, stream>>>(sums, cnts, Wm1, bm1, Wm2, bm2,
                                   Wc, bc, Wr, br, Wv, bv, (float*)d_out, G);
}